// Round 13
// baseline (275.974 us; speedup 1.0000x reference)
//
#include <hip/hip_runtime.h>
#include <stdint.h>
#include <math.h>

#define NN 2048
#define BB 8
#define BN (BB*NN)
#define KK 16
#define EE (BN*KK)
#define HID 128
#define PROJ_D 256
#define QPB 16   // queries (waves) per knn block

typedef unsigned long long u64;
typedef unsigned short ushort_t;
typedef __attribute__((ext_vector_type(8))) short short8;
typedef __attribute__((ext_vector_type(4))) float f32x4;

__device__ __forceinline__ u64 wave_min_u64(u64 v) {
  #pragma unroll
  for (int off = 32; off > 0; off >>= 1) {
    u64 o = __shfl_xor(v, off);
    v = o < v ? o : v;
  }
  return v;
}

// ---------------- kNN + fused degree count (round-5/6 design, unchanged) ----
__global__ __launch_bounds__(1024) void knn_kernel(const float* __restrict__ pos,
                                                   int* __restrict__ nbr,
                                                   int* __restrict__ cnt) {
  __shared__ float4 Ps[NN];
  __shared__ unsigned Hist[QPB * 256];
  const int b  = blockIdx.x >> 7;
  const int qb = blockIdx.x & 127;
  const int wave = threadIdx.x >> 6;
  const int lane = threadIdx.x & 63;
  const int i = qb * QPB + wave;
  const float* P = pos + (size_t)b * NN * 3;

  for (int t = threadIdx.x; t < NN; t += 1024)
    Ps[t] = make_float4(P[t*3], P[t*3+1], P[t*3+2], 0.f);
  __syncthreads();

  const float4 pi = Ps[i];
  const float xi = pi.x, yi = pi.y, zi = pi.z;
  unsigned* H = &Hist[wave * 256];

  float d[32];
  #pragma unroll
  for (int t = 0; t < 32; t++) {
    int j = t * 64 + lane;
    float4 pj = Ps[j];
    float ax = fabsf(xi - pj.x), ay = fabsf(yi - pj.y), az = fabsf(zi - pj.z);
    float dx = fminf(ax, 1.0f - ax);
    float dy = fminf(ay, 1.0f - ay);
    float dz = fminf(az, 1.0f - az);
    float s = __fadd_rn(__fadd_rn(__fadd_rn(__fmul_rn(dx,dx), __fmul_rn(dy,dy)),
                                  __fmul_rn(dz,dz)), 1e-12f);
    d[t] = __fsqrt_rn(s);
  }

  float scale = 1024.0f;
  int bstar = 0; unsigned C = 0;
  for (;;) {
    *(uint4*)&H[lane * 4] = make_uint4(0u, 0u, 0u, 0u);
    #pragma unroll
    for (int t = 0; t < 32; t++) {
      int bin = (int)(d[t] * scale);
      if (bin < 256) atomicAdd(&H[bin], 1u);
    }
    uint4 cv = *(const uint4*)&H[lane * 4];
    unsigned s4 = cv.x + cv.y + cv.z + cv.w;
    unsigned incl = s4;
    #pragma unroll
    for (int off = 1; off < 64; off <<= 1) {
      unsigned v = __shfl_up(incl, off);
      if (lane >= off) incl += v;
    }
    unsigned total = __shfl(incl, 63);
    if (total >= 17u) {
      unsigned base = incl - s4;
      bool has = (incl >= 17u) && (base < 17u);
      u64 hmask = __ballot(has);
      int srcl = __ffsll((unsigned long long)hmask) - 1;
      int bl = 0; unsigned Cl = 0;
      if (has) {
        if (base + cv.x >= 17u)                    { bl = lane*4 + 0; Cl = base; }
        else if (base + cv.x + cv.y >= 17u)        { bl = lane*4 + 1; Cl = base + cv.x; }
        else if (base + cv.x + cv.y + cv.z >= 17u) { bl = lane*4 + 2; Cl = base + cv.x + cv.y; }
        else                                       { bl = lane*4 + 3; Cl = base + cv.x + cv.y + cv.z; }
      }
      bstar = __shfl(bl, srcl);
      C     = __shfl(Cl, srcl);
      break;
    }
    scale *= 0.25f;
  }
  const int m = 17 - (int)C;

  u64 lst[6];
  #pragma unroll
  for (int t = 0; t < 6; t++) lst[t] = ~0ull;
  #pragma unroll
  for (int t = 0; t < 32; t++) {
    int bin = (int)(d[t] * scale);
    u64 key = ((u64)__float_as_uint(d[t]) << 11) | (unsigned)(t * 64 + lane);
    u64 cand = (bin == bstar) ? key : ~0ull;
    if (cand < lst[5]) {
      lst[5] = cand;
      #pragma unroll
      for (int u = 5; u > 0; u--) {
        u64 a = lst[u-1], c2 = lst[u];
        lst[u-1] = a < c2 ? a : c2;
        lst[u]   = a < c2 ? c2 : a;
      }
    }
  }

  u64 kstar = 0;
  #pragma unroll 1
  for (int r = 0; r < m; r++) {
    u64 h0 = lst[0];
    u64 gm = wave_min_u64(h0);
    kstar = gm;
    bool win = (h0 == gm);
    #pragma unroll
    for (int u = 0; u < 5; u++) lst[u] = win ? lst[u+1] : lst[u];
    lst[5] = win ? ~0ull : lst[5];
  }

  int* outp = nbr + ((size_t)b * NN + i) * KK;
  int total = 0;
  #pragma unroll
  for (int t = 0; t < 32; t++) {
    int j = t * 64 + lane;
    u64 key = ((u64)__float_as_uint(d[t]) << 11) | (unsigned)j;
    bool pred = (key <= kstar) && (j != i);
    u64 msk = __ballot(pred);
    if (pred) {
      int ofs = total + __popcll(msk & ((1ull << lane) - 1ull));
      outp[ofs] = b * NN + j;
      atomicAdd(&cnt[b * NN + j], 1);
    }
    total += __popcll(msk);
  }
}

// ---------------- CSR build ----------------
__global__ __launch_bounds__(256) void scan_kernel(const int* __restrict__ cnt,
                                                   int* __restrict__ row_ptr) {
  __shared__ int ps[256];
  int t = threadIdx.x;
  const int4* cv = (const int4*)(cnt + t * 64);
  int4 c[16];
  int s = 0;
  #pragma unroll
  for (int i = 0; i < 16; i++) {
    c[i] = cv[i];
    s += c[i].x + c[i].y + c[i].z + c[i].w;
  }
  ps[t] = s;
  __syncthreads();
  for (int off = 1; off < 256; off <<= 1) {
    int v = 0;
    if (t >= off) v = ps[t - off];
    __syncthreads();
    ps[t] += v;
    __syncthreads();
  }
  int run = t ? ps[t - 1] : 0;
  int4* rp = (int4*)(row_ptr + t * 64);
  #pragma unroll
  for (int i = 0; i < 16; i++) {
    int4 o;
    o.x = run; run += c[i].x;
    o.y = run; run += c[i].y;
    o.z = run; run += c[i].z;
    o.w = run; run += c[i].w;
    rp[i] = o;
  }
  if (t == 255) row_ptr[BN] = run;
}

__global__ __launch_bounds__(256) void fill_kernel(const int* __restrict__ nbr,
                                                   const int* __restrict__ row_ptr,
                                                   int* __restrict__ fill,
                                                   int* __restrict__ col) {
  int e = blockIdx.x * 256 + threadIdx.x;
  int d = nbr[e];
  int srcn = e >> 4;
  int p = row_ptr[d] + atomicAdd(&fill[d], 1);
  col[p] = srcn;
}

// ---------------- encoder layer 0: (BN,5)@(5,128)+relu ----------------
__global__ __launch_bounds__(256) void enc0_kernel(const float* __restrict__ x,
                                                   const float* __restrict__ w0,
                                                   const float* __restrict__ b0,
                                                   float* __restrict__ h) {
  int t = blockIdx.x * 256 + threadIdx.x;
  int m = t >> 5;
  int c = (t & 31) * 4;
  float xv[5];
  #pragma unroll
  for (int d = 0; d < 5; d++) xv[d] = x[m * 5 + d];
  float4 acc = *(const float4*)&b0[c];
  #pragma unroll
  for (int d = 0; d < 5; d++) {
    float4 w = *(const float4*)&w0[d * HID + c];
    acc.x += xv[d] * w.x; acc.y += xv[d] * w.y;
    acc.z += xv[d] * w.z; acc.w += xv[d] * w.w;
  }
  acc.x = fmaxf(acc.x, 0.f); acc.y = fmaxf(acc.y, 0.f);
  acc.z = fmaxf(acc.z, 0.f); acc.w = fmaxf(acc.w, 0.f);
  *(float4*)&h[(size_t)m * HID + c] = acc;
}

// ================= split-bf16 MFMA machinery (round-9, verified) =========
// 3-term split a*b ~= ah*bh + ah*bl + al*bh, rel err ~1e-5.
// Fragment map (pi-consistent A/B): chunk(row,kg) holds k = kg*8..kg*8+7 at
// idx = (((row>>4)*4 + (kg>>2))*64 + ((row&15)|((kg&3)<<4)))*8.
// D layout (HW-verified): col = lane&15, row = (lane>>4)*4 + reg.

__device__ __forceinline__ ushort_t bf16_rne(float x) {
  unsigned u = __float_as_uint(x);
  unsigned r = u + 0x7FFFu + ((u >> 16) & 1u);
  return (ushort_t)(r >> 16);
}
__device__ __forceinline__ float bf16_to_f(ushort_t h) {
  return __uint_as_float(((unsigned)h) << 16);
}

__device__ __forceinline__ void cvt8(const float4 f0, const float4 f1,
                                     short8& hi, short8& lo) {
  float f[8] = {f0.x, f0.y, f0.z, f0.w, f1.x, f1.y, f1.z, f1.w};
  #pragma unroll
  for (int e = 0; e < 8; e++) {
    ushort_t h = bf16_rne(f[e]);
    ushort_t l = bf16_rne(f[e] - bf16_to_f(h));
    hi[e] = (short)h;
    lo[e] = (short)l;
  }
}

// prep: 16 unit-Ws (128x128) -> fragment-ordered bf16 hi/lo (unchanged r9)
__global__ __launch_bounds__(256) void prep_w_kernel(
    const float* __restrict__ enc_w1, const float* __restrict__ msg_w,
    const float* __restrict__ upd_w, const float* __restrict__ proj_w0,
    const float* __restrict__ proj_w1, ushort_t* __restrict__ wfrag) {
  int u = blockIdx.x >> 3;
  int c = (blockIdx.x & 7) * 256 + threadIdx.x;
  const float* src;
  int ldW = HID;
  if (u == 0) src = enc_w1;
  else if (u <= 6)  { int i = (u-1)>>1; int hf = (u-1)&1; src = msg_w + ((size_t)i*256 + hf*128) * HID; }
  else if (u <= 12) { int i = (u-7)>>1; int hf = (u-7)&1; src = upd_w + ((size_t)i*256 + hf*128) * HID; }
  else if (u == 13) src = proj_w0;
  else { src = proj_w1 + (u - 14) * 128; ldW = PROJ_D; }

  int ks = c >> 9, ct = (c >> 6) & 7, lane = c & 63;
  int colc = ct * 16 + (lane & 15);
  int k0 = ks * 32 + ((lane >> 4) << 3);
  float f[8];
  #pragma unroll
  for (int e = 0; e < 8; e++) f[e] = src[(size_t)(k0 + e) * ldW + colc];
  short8 hv, lv;
  cvt8(make_float4(f[0],f[1],f[2],f[3]), make_float4(f[4],f[5],f[6],f[7]), hv, lv);
  *(short8*)&wfrag[(size_t)u * 32768 + (size_t)c * 8] = hv;
  *(short8*)&wfrag[(size_t)u * 32768 + 16384 + (size_t)c * 8] = lv;
}

// convert 64x128 f32 global rows -> fragment hi/lo in LDS (consumer-side)
__device__ __forceinline__ void stage_A_convert(ushort_t* Ahi, ushort_t* Alo,
                                                const float* A, int m0, int tid) {
  #pragma unroll
  for (int i = 0; i < 4; i++) {
    int c = tid + i * 256;
    int row = c >> 4, kg = c & 15;
    const float4* ap = (const float4*)(A + (((size_t)m0 + row) << 7) + (kg << 3));
    short8 hv, lv;
    cvt8(ap[0], ap[1], hv, lv);
    int idx = (((row >> 4) * 4 + (kg >> 2)) * 64 + ((row & 15) | ((kg & 3) << 4))) * 8;
    *(short8*)&Ahi[idx] = hv;
    *(short8*)&Alo[idx] = lv;
  }
}

// ---- full-N unit (8 col-tiles), r9-verified ----
__device__ __forceinline__ void unit_mfma(f32x4 acc[8], const ushort_t* wf,
                                          const ushort_t* Ahi, const ushort_t* Alo,
                                          ushort_t* Bhi, ushort_t* Blo,
                                          int tid, int lane, int wid) {
  #pragma unroll 1
  for (int half = 0; half < 2; half++) {
    __syncthreads();
    const short8* ghi = (const short8*)(wf + half * 8192);
    const short8* glo = (const short8*)(wf + 16384 + half * 8192);
    #pragma unroll
    for (int i = 0; i < 4; i++) {
      ((short8*)Bhi)[tid + i * 256] = ghi[tid + i * 256];
      ((short8*)Blo)[tid + i * 256] = glo[tid + i * 256];
    }
    __syncthreads();
    #pragma unroll
    for (int ks2 = 0; ks2 < 2; ks2++) {
      int ksA = half * 2 + ks2;
      short8 ah = *(const short8*)&Ahi[((wid * 4 + ksA) * 64 + lane) * 8];
      short8 al = *(const short8*)&Alo[((wid * 4 + ksA) * 64 + lane) * 8];
      #pragma unroll
      for (int ct = 0; ct < 8; ct++) {
        short8 bh = *(const short8*)&Bhi[((ks2 * 8 + ct) * 64 + lane) * 8];
        short8 bl = *(const short8*)&Blo[((ks2 * 8 + ct) * 64 + lane) * 8];
        acc[ct] = __builtin_amdgcn_mfma_f32_16x16x32_bf16(ah, bh, acc[ct], 0, 0, 0);
        acc[ct] = __builtin_amdgcn_mfma_f32_16x16x32_bf16(ah, bl, acc[ct], 0, 0, 0);
        acc[ct] = __builtin_amdgcn_mfma_f32_16x16x32_bf16(al, bh, acc[ct], 0, 0, 0);
      }
    }
  }
}

// ---- N-half unit (4 col-tiles, ct0 = 0 or 4) — r11-verified ----
__device__ __forceinline__ void unit_mfma_h(f32x4 acc[4], const ushort_t* wf,
                                            int ct0,
                                            const ushort_t* Ahi, const ushort_t* Alo,
                                            ushort_t* Bhi, ushort_t* Blo,
                                            int tid, int lane, int wid) {
  #pragma unroll 1
  for (int half = 0; half < 2; half++) {
    __syncthreads();
    #pragma unroll
    for (int i = 0; i < 2; i++) {
      int sc = tid + i * 256;             // 0..511
      int ks2 = sc >> 8;
      int cts = (sc >> 6) & 3;
      int ln  = sc & 63;
      int c = half * 1024 + ks2 * 512 + (ct0 + cts) * 64 + ln;
      ((short8*)Bhi)[sc] = *(const short8*)&wf[(size_t)c * 8];
      ((short8*)Blo)[sc] = *(const short8*)&wf[16384 + (size_t)c * 8];
    }
    __syncthreads();
    #pragma unroll
    for (int ks2 = 0; ks2 < 2; ks2++) {
      int ksA = half * 2 + ks2;
      short8 ah = *(const short8*)&Ahi[((wid * 4 + ksA) * 64 + lane) * 8];
      short8 al = *(const short8*)&Alo[((wid * 4 + ksA) * 64 + lane) * 8];
      #pragma unroll
      for (int ct = 0; ct < 4; ct++) {
        short8 bh = *(const short8*)&Bhi[((ks2 * 4 + ct) * 64 + lane) * 8];
        short8 bl = *(const short8*)&Blo[((ks2 * 4 + ct) * 64 + lane) * 8];
        acc[ct] = __builtin_amdgcn_mfma_f32_16x16x32_bf16(ah, bh, acc[ct], 0, 0, 0);
        acc[ct] = __builtin_amdgcn_mfma_f32_16x16x32_bf16(ah, bl, acc[ct], 0, 0, 0);
        acc[ct] = __builtin_amdgcn_mfma_f32_16x16x32_bf16(al, bh, acc[ct], 0, 0, 0);
      }
    }
  }
}

// ---------------- g1 (N-split): out = [relu](A@W + bias), grid (256,2) -----
template<int RELU>
__global__ __launch_bounds__(256, 4) void g1_kernel(
    const float* __restrict__ A, const ushort_t* __restrict__ wf,
    const float* __restrict__ bias, float* __restrict__ out) {
  __shared__ ushort_t Ahi[8192], Alo[8192], Bhi[4096], Blo[4096];
  const int tid = threadIdx.x, lane = tid & 63, wid = tid >> 6;
  const int m0 = blockIdx.x * 64, ct0 = blockIdx.y * 4;
  stage_A_convert(Ahi, Alo, A, m0, tid);
  f32x4 acc[4];
  f32x4 z = {0.f, 0.f, 0.f, 0.f};
  #pragma unroll
  for (int ct = 0; ct < 4; ct++) acc[ct] = z;
  unit_mfma_h(acc, wf, ct0, Ahi, Alo, Bhi, Blo, tid, lane, wid);

  const int rbase = m0 + wid * 16 + ((lane >> 4) << 2);
  const int cb = lane & 15;
  #pragma unroll
  for (int ct = 0; ct < 4; ct++) {
    int n = (ct0 + ct) * 16 + cb;
    float bv = bias ? bias[n] : 0.f;
    #pragma unroll
    for (int r = 0; r < 4; r++) {
      float v = acc[ct][r] + bv;
      if (RELU) v = fmaxf(v, 0.f);
      out[(size_t)(rbase + r) * HID + n] = v;
    }
  }
}

// ---------------- msg pair (full-N, grid (256,2) y=top/bot) — r9 form ------
__global__ __launch_bounds__(256, 4) void msg_kernel(
    const float* __restrict__ h, const ushort_t* __restrict__ wfT,
    const ushort_t* __restrict__ wfB, const float* __restrict__ mb,
    float* __restrict__ bufA, float* __restrict__ bufB) {
  __shared__ ushort_t Ahi[8192], Alo[8192], Bhi[8192], Blo[8192];
  const int tid = threadIdx.x, lane = tid & 63, wid = tid >> 6;
  const int m0 = blockIdx.x * 64;
  const int y = blockIdx.y;
  stage_A_convert(Ahi, Alo, h, m0, tid);
  f32x4 acc[8];
  f32x4 z = {0.f, 0.f, 0.f, 0.f};
  #pragma unroll
  for (int ct = 0; ct < 8; ct++) acc[ct] = z;
  unit_mfma(acc, y ? wfB : wfT, Ahi, Alo, Bhi, Blo, tid, lane, wid);

  float* out = y ? bufB : bufA;
  const float* bias = y ? mb : nullptr;
  const int rbase = m0 + wid * 16 + ((lane >> 4) << 2);
  const int cb = lane & 15;
  #pragma unroll
  for (int ct = 0; ct < 8; ct++) {
    int n = ct * 16 + cb;
    float bv = bias ? bias[n] : 0.f;
    #pragma unroll
    for (int r = 0; r < 4; r++)
      out[(size_t)(rbase + r) * HID + n] = acc[ct][r] + bv;
  }
}

// ---------------- upd_fused: agg (in-kernel gather) + h@Wt + agg@Wb --------
// Round-13: agg for rows [m0,m0+64) only needs bufA (complete after msg
// dispatch) + bufB rows m0..m0+63 -> compute it HERE, into fragment chunks,
// skipping the agg dispatch + bufAgg global roundtrip entirely.
__global__ __launch_bounds__(256, 2) void upd_fused_kernel(
    const float* __restrict__ h, const ushort_t* __restrict__ wuT,
    const ushort_t* __restrict__ wuB, const float* __restrict__ ub,
    const float* __restrict__ bufA, const float* __restrict__ bufB,
    const int* __restrict__ row_ptr, const int* __restrict__ col,
    float* __restrict__ out) {
  __shared__ ushort_t Ahi[8192], Alo[8192], Bhi[8192], Blo[8192];
  const int tid = threadIdx.x, lane = tid & 63, wid = tid >> 6;
  const int m0 = blockIdx.x * 64;

  // ---- phase A: mean-aggregation straight into fragment chunks ----
  // chunk c: node j = m0 + (c>>4), channels (c&15)*8 .. +7
  #pragma unroll 1
  for (int i = 0; i < 4; i++) {
    int c = tid + i * 256;
    int row = c >> 4, kg = c & 15;
    int j = m0 + row;
    const float4* bjp = (const float4*)(bufB + ((size_t)j << 7) + (kg << 3));
    float4 bj0 = bjp[0], bj1 = bjp[1];
    int s = row_ptr[j], e = row_ptr[j + 1];
    float4 a0 = make_float4(0.f, 0.f, 0.f, 0.f);
    float4 a1 = make_float4(0.f, 0.f, 0.f, 0.f);
    int p = s;
    for (; p + 2 <= e; p += 2) {
      int j0 = col[p], j1 = col[p + 1];
      const float4* v0 = (const float4*)(bufA + ((size_t)j0 << 7) + (kg << 3));
      const float4* v1 = (const float4*)(bufA + ((size_t)j1 << 7) + (kg << 3));
      float4 x0 = v0[0], x1 = v0[1], y0 = v1[0], y1 = v1[1];
      a0.x += fmaxf(x0.x + bj0.x, 0.f) + fmaxf(y0.x + bj0.x, 0.f);
      a0.y += fmaxf(x0.y + bj0.y, 0.f) + fmaxf(y0.y + bj0.y, 0.f);
      a0.z += fmaxf(x0.z + bj0.z, 0.f) + fmaxf(y0.z + bj0.z, 0.f);
      a0.w += fmaxf(x0.w + bj0.w, 0.f) + fmaxf(y0.w + bj0.w, 0.f);
      a1.x += fmaxf(x1.x + bj1.x, 0.f) + fmaxf(y1.x + bj1.x, 0.f);
      a1.y += fmaxf(x1.y + bj1.y, 0.f) + fmaxf(y1.y + bj1.y, 0.f);
      a1.z += fmaxf(x1.z + bj1.z, 0.f) + fmaxf(y1.z + bj1.z, 0.f);
      a1.w += fmaxf(x1.w + bj1.w, 0.f) + fmaxf(y1.w + bj1.w, 0.f);
    }
    for (; p < e; p++) {
      int j0 = col[p];
      const float4* v0 = (const float4*)(bufA + ((size_t)j0 << 7) + (kg << 3));
      float4 x0 = v0[0], x1 = v0[1];
      a0.x += fmaxf(x0.x + bj0.x, 0.f);
      a0.y += fmaxf(x0.y + bj0.y, 0.f);
      a0.z += fmaxf(x0.z + bj0.z, 0.f);
      a0.w += fmaxf(x0.w + bj0.w, 0.f);
      a1.x += fmaxf(x1.x + bj1.x, 0.f);
      a1.y += fmaxf(x1.y + bj1.y, 0.f);
      a1.z += fmaxf(x1.z + bj1.z, 0.f);
      a1.w += fmaxf(x1.w + bj1.w, 0.f);
    }
    float inv = 1.0f / fmaxf((float)(e - s), 1.0f);
    a0.x *= inv; a0.y *= inv; a0.z *= inv; a0.w *= inv;
    a1.x *= inv; a1.y *= inv; a1.z *= inv; a1.w *= inv;
    short8 hv, lv;
    cvt8(a0, a1, hv, lv);
    int idx = (((row >> 4) * 4 + (kg >> 2)) * 64 + ((row & 15) | ((kg & 3) << 4))) * 8;
    *(short8*)&Ahi[idx] = hv;
    *(short8*)&Alo[idx] = lv;
  }

  // ---- phase B: agg @ Wb (unit_mfma's leading barrier makes Ahi visible) --
  f32x4 acc[8];
  f32x4 z = {0.f, 0.f, 0.f, 0.f};
  #pragma unroll
  for (int ct = 0; ct < 8; ct++) acc[ct] = z;
  unit_mfma(acc, wuB, Ahi, Alo, Bhi, Blo, tid, lane, wid);

  // ---- phase C: h @ Wt ----
  __syncthreads();                       // phase-B A reads done
  stage_A_convert(Ahi, Alo, h, m0, tid);
  unit_mfma(acc, wuT, Ahi, Alo, Bhi, Blo, tid, lane, wid);

  // ---- epilogue: h' = h + relu(acc + ub) ----
  const int rbase = m0 + wid * 16 + ((lane >> 4) << 2);
  const int cb = lane & 15;
  #pragma unroll
  for (int ct = 0; ct < 8; ct++) {
    int n = ct * 16 + cb;
    float bv = ub[n];
    #pragma unroll
    for (int r = 0; r < 4; r++) {
      float v = fmaxf(acc[ct][r] + bv, 0.f)
              + h[(size_t)(rbase + r) * HID + n];
      out[(size_t)(rbase + r) * HID + n] = v;
    }
  }
}

// ---------------- proj1 (full-N, grid (256,2) y=col-block) — r9 form -------
__global__ __launch_bounds__(256, 4) void proj1_kernel(
    const float* __restrict__ A, const ushort_t* __restrict__ wf01,
    const float* __restrict__ pb1, float* __restrict__ zout) {
  __shared__ ushort_t Ahi[8192], Alo[8192], Bhi[8192], Blo[8192];
  const int tid = threadIdx.x, lane = tid & 63, wid = tid >> 6;
  const int m0 = blockIdx.x * 64;
  const int y = blockIdx.y;
  stage_A_convert(Ahi, Alo, A, m0, tid);
  f32x4 acc[8];
  f32x4 z = {0.f, 0.f, 0.f, 0.f};
  #pragma unroll
  for (int ct = 0; ct < 8; ct++) acc[ct] = z;
  unit_mfma(acc, wf01 + (size_t)y * 32768, Ahi, Alo, Bhi, Blo, tid, lane, wid);

  const int rbase = m0 + wid * 16 + ((lane >> 4) << 2);
  const int cb = lane & 15;
  #pragma unroll
  for (int ct = 0; ct < 8; ct++) {
    int n = y * 128 + ct * 16 + cb;
    float bv = pb1[n];
    #pragma unroll
    for (int r = 0; r < 4; r++)
      zout[(size_t)(rbase + r) * PROJ_D + n] = acc[ct][r] + bv;
  }
}

extern "C" void kernel_launch(void* const* d_in, const int* in_sizes, int n_in,
                              void* d_out, int out_size, void* d_ws, size_t ws_size,
                              hipStream_t stream) {
  (void)in_sizes; (void)n_in; (void)out_size; (void)ws_size;
  const float* x       = (const float*)d_in[0];
  const float* pos     = (const float*)d_in[1];
  const float* enc_w0  = (const float*)d_in[3];
  const float* enc_b0  = (const float*)d_in[4];
  const float* enc_w1  = (const float*)d_in[5];
  const float* enc_b1  = (const float*)d_in[6];
  const float* msg_w   = (const float*)d_in[7];
  const float* msg_b   = (const float*)d_in[8];
  const float* upd_w   = (const float*)d_in[9];
  const float* upd_b   = (const float*)d_in[10];
  const float* proj_w0 = (const float*)d_in[11];
  const float* proj_b0 = (const float*)d_in[12];
  const float* proj_w1 = (const float*)d_in[13];
  const float* proj_b1 = (const float*)d_in[14];

  char* ws = (char*)d_ws;
  size_t off = 0;
  auto alloc = [&](size_t bytes) -> void* {
    void* p = ws + off;
    off += (bytes + 255) & ~(size_t)255;
    return p;
  };
  int*      nbr     = (int*)alloc((size_t)EE * 4);
  int*      cnt     = (int*)alloc((size_t)BN * 4);
  int*      fill    = (int*)alloc((size_t)BN * 4);
  int*      row_ptr = (int*)alloc((size_t)(BN + 1) * 4);
  int*      col     = (int*)alloc((size_t)EE * 4);
  float*    h_a     = (float*)alloc((size_t)BN * HID * 4);
  float*    h_b     = (float*)alloc((size_t)BN * HID * 4);
  float*    bufA    = (float*)alloc((size_t)BN * HID * 4);
  float*    bufB    = (float*)alloc((size_t)BN * HID * 4);
  ushort_t* wfrag   = (ushort_t*)alloc((size_t)16 * 32768 * 2);
  float*    out     = (float*)d_out;
  float*    hOut    = out + (size_t)BN * PROJ_D;

  hipMemsetAsync(cnt, 0, (size_t)BN * 4 * 2, stream);   // cnt + fill

  prep_w_kernel<<<128, 256, 0, stream>>>(enc_w1, msg_w, upd_w, proj_w0, proj_w1, wfrag);
  knn_kernel<<<BN / QPB, 1024, 0, stream>>>(pos, nbr, cnt);
  scan_kernel<<<1, 256, 0, stream>>>(cnt, row_ptr);
  fill_kernel<<<EE / 256, 256, 0, stream>>>(nbr, row_ptr, fill, col);

  enc0_kernel<<<BN * 32 / 256, 256, 0, stream>>>(x, enc_w0, enc_b0, bufA);
  g1_kernel<1><<<dim3(BN / 64, 2), 256, 0, stream>>>(bufA, wfrag + 0 * 32768,
                                                     enc_b1, h_a);

  float* hc = h_a;
  float* hn = h_b;
  for (int i = 0; i < 3; i++) {
    msg_kernel<<<dim3(BN / 64, 2), 256, 0, stream>>>(
        hc, wfrag + (size_t)(1 + 2 * i) * 32768,
        wfrag + (size_t)(2 + 2 * i) * 32768, msg_b + (size_t)i * HID,
        bufA, bufB);
    float* target = (i == 2) ? hOut : hn;
    upd_fused_kernel<<<BN / 64, 256, 0, stream>>>(
        hc, wfrag + (size_t)(7 + 2 * i) * 32768,
        wfrag + (size_t)(8 + 2 * i) * 32768, upd_b + (size_t)i * HID,
        bufA, bufB, row_ptr, col, target);
    hn = hc; hc = target;
  }

  g1_kernel<1><<<dim3(BN / 64, 2), 256, 0, stream>>>(hc, wfrag + 13 * 32768,
                                                     proj_b0, bufA);
  proj1_kernel<<<dim3(BN / 64, 2), 256, 0, stream>>>(
      bufA, wfrag + 14 * 32768, proj_b1, out);
}

// Round 14
// 243.042 us; speedup vs baseline: 1.1355x; 1.1355x over previous
//
#include <hip/hip_runtime.h>
#include <stdint.h>
#include <math.h>

#define NN 2048
#define BB 8
#define BN (BB*NN)
#define KK 16
#define EE (BN*KK)
#define HID 128
#define PROJ_D 256
#define QPB 16   // queries (waves) per knn block

typedef unsigned long long u64;
typedef unsigned short ushort_t;
typedef __attribute__((ext_vector_type(8))) short short8;
typedef __attribute__((ext_vector_type(4))) float f32x4;

__device__ __forceinline__ u64 wave_min_u64(u64 v) {
  #pragma unroll
  for (int off = 32; off > 0; off >>= 1) {
    u64 o = __shfl_xor(v, off);
    v = o < v ? o : v;
  }
  return v;
}

// ---------------- kNN + fused degree count ----------------
// r14: min-image via rndne: t = D - rndne(D) gives |t| = min(|D|,1-|D|)
// bit-exactly (Sterbenz for the 1-|D| branch; tie at 0.5 rounds to 0).
// t*t equals the reference's delta*delta exactly.
__global__ __launch_bounds__(1024) void knn_kernel(const float* __restrict__ pos,
                                                   int* __restrict__ nbr,
                                                   int* __restrict__ cnt) {
  __shared__ float4 Ps[NN];
  __shared__ unsigned Hist[QPB * 256];
  const int b  = blockIdx.x >> 7;
  const int qb = blockIdx.x & 127;
  const int wave = threadIdx.x >> 6;
  const int lane = threadIdx.x & 63;
  const int i = qb * QPB + wave;
  const float* P = pos + (size_t)b * NN * 3;

  for (int t = threadIdx.x; t < NN; t += 1024)
    Ps[t] = make_float4(P[t*3], P[t*3+1], P[t*3+2], 0.f);
  __syncthreads();

  const float4 pi = Ps[i];
  const float xi = pi.x, yi = pi.y, zi = pi.z;
  unsigned* H = &Hist[wave * 256];

  float d[32];
  #pragma unroll
  for (int t = 0; t < 32; t++) {
    int j = t * 64 + lane;
    float4 pj = Ps[j];
    float tx = xi - pj.x, ty = yi - pj.y, tz = zi - pj.z;
    float dx = __fsub_rn(tx, rintf(tx));
    float dy = __fsub_rn(ty, rintf(ty));
    float dz = __fsub_rn(tz, rintf(tz));
    // match numpy fp32 exactly: no FMA contraction, sum order ((x+y)+z)+eps
    float s = __fadd_rn(__fadd_rn(__fadd_rn(__fmul_rn(dx,dx), __fmul_rn(dy,dy)),
                                  __fmul_rn(dz,dz)), 1e-12f);
    d[t] = __fsqrt_rn(s);
  }

  float scale = 1024.0f;
  int bstar = 0; unsigned C = 0;
  for (;;) {
    *(uint4*)&H[lane * 4] = make_uint4(0u, 0u, 0u, 0u);
    #pragma unroll
    for (int t = 0; t < 32; t++) {
      int bin = (int)(d[t] * scale);
      if (bin < 256) atomicAdd(&H[bin], 1u);
    }
    uint4 cv = *(const uint4*)&H[lane * 4];
    unsigned s4 = cv.x + cv.y + cv.z + cv.w;
    unsigned incl = s4;
    #pragma unroll
    for (int off = 1; off < 64; off <<= 1) {
      unsigned v = __shfl_up(incl, off);
      if (lane >= off) incl += v;
    }
    unsigned total = __shfl(incl, 63);
    if (total >= 17u) {
      unsigned base = incl - s4;
      bool has = (incl >= 17u) && (base < 17u);
      u64 hmask = __ballot(has);
      int srcl = __ffsll((unsigned long long)hmask) - 1;
      int bl = 0; unsigned Cl = 0;
      if (has) {
        if (base + cv.x >= 17u)                    { bl = lane*4 + 0; Cl = base; }
        else if (base + cv.x + cv.y >= 17u)        { bl = lane*4 + 1; Cl = base + cv.x; }
        else if (base + cv.x + cv.y + cv.z >= 17u) { bl = lane*4 + 2; Cl = base + cv.x + cv.y; }
        else                                       { bl = lane*4 + 3; Cl = base + cv.x + cv.y + cv.z; }
      }
      bstar = __shfl(bl, srcl);
      C     = __shfl(Cl, srcl);
      break;
    }
    scale *= 0.25f;
  }
  const int m = 17 - (int)C;

  u64 lst[6];
  #pragma unroll
  for (int t = 0; t < 6; t++) lst[t] = ~0ull;
  #pragma unroll
  for (int t = 0; t < 32; t++) {
    int bin = (int)(d[t] * scale);
    u64 key = ((u64)__float_as_uint(d[t]) << 11) | (unsigned)(t * 64 + lane);
    u64 cand = (bin == bstar) ? key : ~0ull;
    if (cand < lst[5]) {
      lst[5] = cand;
      #pragma unroll
      for (int u = 5; u > 0; u--) {
        u64 a = lst[u-1], c2 = lst[u];
        lst[u-1] = a < c2 ? a : c2;
        lst[u]   = a < c2 ? c2 : a;
      }
    }
  }

  u64 kstar = 0;
  #pragma unroll 1
  for (int r = 0; r < m; r++) {
    u64 h0 = lst[0];
    u64 gm = wave_min_u64(h0);
    kstar = gm;
    bool win = (h0 == gm);
    #pragma unroll
    for (int u = 0; u < 5; u++) lst[u] = win ? lst[u+1] : lst[u];
    lst[5] = win ? ~0ull : lst[5];
  }

  int* outp = nbr + ((size_t)b * NN + i) * KK;
  int total = 0;
  #pragma unroll
  for (int t = 0; t < 32; t++) {
    int j = t * 64 + lane;
    u64 key = ((u64)__float_as_uint(d[t]) << 11) | (unsigned)j;
    bool pred = (key <= kstar) && (j != i);
    u64 msk = __ballot(pred);
    if (pred) {
      int ofs = total + __popcll(msk & ((1ull << lane) - 1ull));
      outp[ofs] = b * NN + j;
      atomicAdd(&cnt[b * NN + j], 1);
    }
    total += __popcll(msk);
  }
}

// ---------------- CSR build ----------------
__global__ __launch_bounds__(256) void scan_kernel(const int* __restrict__ cnt,
                                                   int* __restrict__ row_ptr) {
  __shared__ int ps[256];
  int t = threadIdx.x;
  const int4* cv = (const int4*)(cnt + t * 64);
  int4 c[16];
  int s = 0;
  #pragma unroll
  for (int i = 0; i < 16; i++) {
    c[i] = cv[i];
    s += c[i].x + c[i].y + c[i].z + c[i].w;
  }
  ps[t] = s;
  __syncthreads();
  for (int off = 1; off < 256; off <<= 1) {
    int v = 0;
    if (t >= off) v = ps[t - off];
    __syncthreads();
    ps[t] += v;
    __syncthreads();
  }
  int run = t ? ps[t - 1] : 0;
  int4* rp = (int4*)(row_ptr + t * 64);
  #pragma unroll
  for (int i = 0; i < 16; i++) {
    int4 o;
    o.x = run; run += c[i].x;
    o.y = run; run += c[i].y;
    o.z = run; run += c[i].z;
    o.w = run; run += c[i].w;
    rp[i] = o;
  }
  if (t == 255) row_ptr[BN] = run;
}

__global__ __launch_bounds__(256) void fill_kernel(const int* __restrict__ nbr,
                                                   const int* __restrict__ row_ptr,
                                                   int* __restrict__ fill,
                                                   int* __restrict__ col) {
  int e = blockIdx.x * 256 + threadIdx.x;
  int d = nbr[e];
  int srcn = e >> 4;
  int p = row_ptr[d] + atomicAdd(&fill[d], 1);
  col[p] = srcn;
}

// ---------------- encoder layer 0: (BN,5)@(5,128)+relu ----------------
__global__ __launch_bounds__(256) void enc0_kernel(const float* __restrict__ x,
                                                   const float* __restrict__ w0,
                                                   const float* __restrict__ b0,
                                                   float* __restrict__ h) {
  int t = blockIdx.x * 256 + threadIdx.x;
  int m = t >> 5;
  int c = (t & 31) * 4;
  float xv[5];
  #pragma unroll
  for (int d = 0; d < 5; d++) xv[d] = x[m * 5 + d];
  float4 acc = *(const float4*)&b0[c];
  #pragma unroll
  for (int d = 0; d < 5; d++) {
    float4 w = *(const float4*)&w0[d * HID + c];
    acc.x += xv[d] * w.x; acc.y += xv[d] * w.y;
    acc.z += xv[d] * w.z; acc.w += xv[d] * w.w;
  }
  acc.x = fmaxf(acc.x, 0.f); acc.y = fmaxf(acc.y, 0.f);
  acc.z = fmaxf(acc.z, 0.f); acc.w = fmaxf(acc.w, 0.f);
  *(float4*)&h[(size_t)m * HID + c] = acc;
}

// ================= split-bf16 MFMA machinery =========
// 3-term split a*b ~= ah*bh + ah*bl + al*bh, rel err ~1e-5.
// r14: conversion via v_cvt_pk_bf16_f32 (2 f32 -> packed 2xbf16, 1 instr).
// Any within-pair element permutation or rounding-mode difference cancels:
// A and B both pass through cvt8 (pi-consistency), and lo captures the
// residual of whatever hi rounding the HW applies.
__device__ __forceinline__ unsigned cvtpk_bf16(float a, float b) {
  unsigned r;
  asm("v_cvt_pk_bf16_f32 %0, %1, %2" : "=v"(r) : "v"(a), "v"(b));
  return r;
}

__device__ __forceinline__ void cvt8(const float4 f0, const float4 f1,
                                     short8& hi, short8& lo) {
  unsigned h0 = cvtpk_bf16(f0.x, f0.y);
  unsigned h1 = cvtpk_bf16(f0.z, f0.w);
  unsigned h2 = cvtpk_bf16(f1.x, f1.y);
  unsigned h3 = cvtpk_bf16(f1.z, f1.w);
  unsigned l0 = cvtpk_bf16(f0.x - __uint_as_float(h0 << 16),
                           f0.y - __uint_as_float(h0 & 0xffff0000u));
  unsigned l1 = cvtpk_bf16(f0.z - __uint_as_float(h1 << 16),
                           f0.w - __uint_as_float(h1 & 0xffff0000u));
  unsigned l2 = cvtpk_bf16(f1.x - __uint_as_float(h2 << 16),
                           f1.y - __uint_as_float(h2 & 0xffff0000u));
  unsigned l3 = cvtpk_bf16(f1.z - __uint_as_float(h3 << 16),
                           f1.w - __uint_as_float(h3 & 0xffff0000u));
  union { unsigned u[4]; short8 v; } H, L;
  H.u[0] = h0; H.u[1] = h1; H.u[2] = h2; H.u[3] = h3;
  L.u[0] = l0; L.u[1] = l1; L.u[2] = l2; L.u[3] = l3;
  hi = H.v;
  lo = L.v;
}

// prep: 16 unit-Ws (128x128) -> fragment-ordered bf16 hi/lo
__global__ __launch_bounds__(256) void prep_w_kernel(
    const float* __restrict__ enc_w1, const float* __restrict__ msg_w,
    const float* __restrict__ upd_w, const float* __restrict__ proj_w0,
    const float* __restrict__ proj_w1, ushort_t* __restrict__ wfrag) {
  int u = blockIdx.x >> 3;
  int c = (blockIdx.x & 7) * 256 + threadIdx.x;
  const float* src;
  int ldW = HID;
  if (u == 0) src = enc_w1;
  else if (u <= 6)  { int i = (u-1)>>1; int hf = (u-1)&1; src = msg_w + ((size_t)i*256 + hf*128) * HID; }
  else if (u <= 12) { int i = (u-7)>>1; int hf = (u-7)&1; src = upd_w + ((size_t)i*256 + hf*128) * HID; }
  else if (u == 13) src = proj_w0;
  else { src = proj_w1 + (u - 14) * 128; ldW = PROJ_D; }

  int ks = c >> 9, ct = (c >> 6) & 7, lane = c & 63;
  int colc = ct * 16 + (lane & 15);
  int k0 = ks * 32 + ((lane >> 4) << 3);
  float f[8];
  #pragma unroll
  for (int e = 0; e < 8; e++) f[e] = src[(size_t)(k0 + e) * ldW + colc];
  short8 hv, lv;
  cvt8(make_float4(f[0],f[1],f[2],f[3]), make_float4(f[4],f[5],f[6],f[7]), hv, lv);
  *(short8*)&wfrag[(size_t)u * 32768 + (size_t)c * 8] = hv;
  *(short8*)&wfrag[(size_t)u * 32768 + 16384 + (size_t)c * 8] = lv;
}

// convert 64x128 f32 global rows -> fragment hi/lo in LDS (consumer-side)
__device__ __forceinline__ void stage_A_convert(ushort_t* Ahi, ushort_t* Alo,
                                                const float* A, int m0, int tid) {
  #pragma unroll
  for (int i = 0; i < 4; i++) {
    int c = tid + i * 256;
    int row = c >> 4, kg = c & 15;
    const float4* ap = (const float4*)(A + (((size_t)m0 + row) << 7) + (kg << 3));
    short8 hv, lv;
    cvt8(ap[0], ap[1], hv, lv);
    int idx = (((row >> 4) * 4 + (kg >> 2)) * 64 + ((row & 15) | ((kg & 3) << 4))) * 8;
    *(short8*)&Ahi[idx] = hv;
    *(short8*)&Alo[idx] = lv;
  }
}

// ---- full-N unit (8 col-tiles), r9-verified ----
__device__ __forceinline__ void unit_mfma(f32x4 acc[8], const ushort_t* wf,
                                          const ushort_t* Ahi, const ushort_t* Alo,
                                          ushort_t* Bhi, ushort_t* Blo,
                                          int tid, int lane, int wid) {
  #pragma unroll 1
  for (int half = 0; half < 2; half++) {
    __syncthreads();
    const short8* ghi = (const short8*)(wf + half * 8192);
    const short8* glo = (const short8*)(wf + 16384 + half * 8192);
    #pragma unroll
    for (int i = 0; i < 4; i++) {
      ((short8*)Bhi)[tid + i * 256] = ghi[tid + i * 256];
      ((short8*)Blo)[tid + i * 256] = glo[tid + i * 256];
    }
    __syncthreads();
    #pragma unroll
    for (int ks2 = 0; ks2 < 2; ks2++) {
      int ksA = half * 2 + ks2;
      short8 ah = *(const short8*)&Ahi[((wid * 4 + ksA) * 64 + lane) * 8];
      short8 al = *(const short8*)&Alo[((wid * 4 + ksA) * 64 + lane) * 8];
      #pragma unroll
      for (int ct = 0; ct < 8; ct++) {
        short8 bh = *(const short8*)&Bhi[((ks2 * 8 + ct) * 64 + lane) * 8];
        short8 bl = *(const short8*)&Blo[((ks2 * 8 + ct) * 64 + lane) * 8];
        acc[ct] = __builtin_amdgcn_mfma_f32_16x16x32_bf16(ah, bh, acc[ct], 0, 0, 0);
        acc[ct] = __builtin_amdgcn_mfma_f32_16x16x32_bf16(ah, bl, acc[ct], 0, 0, 0);
        acc[ct] = __builtin_amdgcn_mfma_f32_16x16x32_bf16(al, bh, acc[ct], 0, 0, 0);
      }
    }
  }
}

// ---- N-half unit (4 col-tiles, ct0 = 0 or 4) — r11-verified ----
__device__ __forceinline__ void unit_mfma_h(f32x4 acc[4], const ushort_t* wf,
                                            int ct0,
                                            const ushort_t* Ahi, const ushort_t* Alo,
                                            ushort_t* Bhi, ushort_t* Blo,
                                            int tid, int lane, int wid) {
  #pragma unroll 1
  for (int half = 0; half < 2; half++) {
    __syncthreads();
    #pragma unroll
    for (int i = 0; i < 2; i++) {
      int sc = tid + i * 256;             // 0..511
      int ks2 = sc >> 8;
      int cts = (sc >> 6) & 3;
      int ln  = sc & 63;
      int c = half * 1024 + ks2 * 512 + (ct0 + cts) * 64 + ln;
      ((short8*)Bhi)[sc] = *(const short8*)&wf[(size_t)c * 8];
      ((short8*)Blo)[sc] = *(const short8*)&wf[16384 + (size_t)c * 8];
    }
    __syncthreads();
    #pragma unroll
    for (int ks2 = 0; ks2 < 2; ks2++) {
      int ksA = half * 2 + ks2;
      short8 ah = *(const short8*)&Ahi[((wid * 4 + ksA) * 64 + lane) * 8];
      short8 al = *(const short8*)&Alo[((wid * 4 + ksA) * 64 + lane) * 8];
      #pragma unroll
      for (int ct = 0; ct < 4; ct++) {
        short8 bh = *(const short8*)&Bhi[((ks2 * 4 + ct) * 64 + lane) * 8];
        short8 bl = *(const short8*)&Blo[((ks2 * 4 + ct) * 64 + lane) * 8];
        acc[ct] = __builtin_amdgcn_mfma_f32_16x16x32_bf16(ah, bh, acc[ct], 0, 0, 0);
        acc[ct] = __builtin_amdgcn_mfma_f32_16x16x32_bf16(ah, bl, acc[ct], 0, 0, 0);
        acc[ct] = __builtin_amdgcn_mfma_f32_16x16x32_bf16(al, bh, acc[ct], 0, 0, 0);
      }
    }
  }
}

// ---------------- g1 (N-split): out = [relu](A@W + bias), grid (256,2) -----
template<int RELU>
__global__ __launch_bounds__(256, 4) void g1_kernel(
    const float* __restrict__ A, const ushort_t* __restrict__ wf,
    const float* __restrict__ bias, float* __restrict__ out) {
  __shared__ ushort_t Ahi[8192], Alo[8192], Bhi[4096], Blo[4096];
  const int tid = threadIdx.x, lane = tid & 63, wid = tid >> 6;
  const int m0 = blockIdx.x * 64, ct0 = blockIdx.y * 4;
  stage_A_convert(Ahi, Alo, A, m0, tid);
  f32x4 acc[4];
  f32x4 z = {0.f, 0.f, 0.f, 0.f};
  #pragma unroll
  for (int ct = 0; ct < 4; ct++) acc[ct] = z;
  unit_mfma_h(acc, wf, ct0, Ahi, Alo, Bhi, Blo, tid, lane, wid);

  const int rbase = m0 + wid * 16 + ((lane >> 4) << 2);
  const int cb = lane & 15;
  #pragma unroll
  for (int ct = 0; ct < 4; ct++) {
    int n = (ct0 + ct) * 16 + cb;
    float bv = bias ? bias[n] : 0.f;
    #pragma unroll
    for (int r = 0; r < 4; r++) {
      float v = acc[ct][r] + bv;
      if (RELU) v = fmaxf(v, 0.f);
      out[(size_t)(rbase + r) * HID + n] = v;
    }
  }
}

// ---------------- msg pair (full-N, grid (256,2) y=top/bot) ------
__global__ __launch_bounds__(256, 4) void msg_kernel(
    const float* __restrict__ h, const ushort_t* __restrict__ wfT,
    const ushort_t* __restrict__ wfB, const float* __restrict__ mb,
    float* __restrict__ bufA, float* __restrict__ bufB) {
  __shared__ ushort_t Ahi[8192], Alo[8192], Bhi[8192], Blo[8192];
  const int tid = threadIdx.x, lane = tid & 63, wid = tid >> 6;
  const int m0 = blockIdx.x * 64;
  const int y = blockIdx.y;
  stage_A_convert(Ahi, Alo, h, m0, tid);
  f32x4 acc[8];
  f32x4 z = {0.f, 0.f, 0.f, 0.f};
  #pragma unroll
  for (int ct = 0; ct < 8; ct++) acc[ct] = z;
  unit_mfma(acc, y ? wfB : wfT, Ahi, Alo, Bhi, Blo, tid, lane, wid);

  float* out = y ? bufB : bufA;
  const float* bias = y ? mb : nullptr;
  const int rbase = m0 + wid * 16 + ((lane >> 4) << 2);
  const int cb = lane & 15;
  #pragma unroll
  for (int ct = 0; ct < 8; ct++) {
    int n = ct * 16 + cb;
    float bv = bias ? bias[n] : 0.f;
    #pragma unroll
    for (int r = 0; r < 4; r++)
      out[(size_t)(rbase + r) * HID + n] = acc[ct][r] + bv;
  }
}

// ---------------- upd (N-split): h' = h + relu(h@Wt + agg@Wb + ub) ---------
__global__ __launch_bounds__(256, 4) void upd_kernel(
    const float* __restrict__ h, const ushort_t* __restrict__ wuT,
    const float* __restrict__ aggF, const ushort_t* __restrict__ wuB,
    const float* __restrict__ ub, float* __restrict__ out) {
  __shared__ ushort_t Ahi[8192], Alo[8192], Bhi[4096], Blo[4096];
  const int tid = threadIdx.x, lane = tid & 63, wid = tid >> 6;
  const int m0 = blockIdx.x * 64, ct0 = blockIdx.y * 4;
  stage_A_convert(Ahi, Alo, h, m0, tid);
  f32x4 acc[4];
  f32x4 z = {0.f, 0.f, 0.f, 0.f};
  #pragma unroll
  for (int ct = 0; ct < 4; ct++) acc[ct] = z;
  unit_mfma_h(acc, wuT, ct0, Ahi, Alo, Bhi, Blo, tid, lane, wid);
  __syncthreads();                         // phase-1 A reads done
  stage_A_convert(Ahi, Alo, aggF, m0, tid);
  unit_mfma_h(acc, wuB, ct0, Ahi, Alo, Bhi, Blo, tid, lane, wid);

  const int rbase = m0 + wid * 16 + ((lane >> 4) << 2);
  const int cb = lane & 15;
  #pragma unroll
  for (int ct = 0; ct < 4; ct++) {
    int n = (ct0 + ct) * 16 + cb;
    float bv = ub[n];
    #pragma unroll
    for (int r = 0; r < 4; r++) {
      float v = fmaxf(acc[ct][r] + bv, 0.f)
              + h[(size_t)(rbase + r) * HID + n];
      out[(size_t)(rbase + r) * HID + n] = v;
    }
  }
}

// ---------------- proj1 (full-N, grid (256,2) y=col-block) -------
__global__ __launch_bounds__(256, 4) void proj1_kernel(
    const float* __restrict__ A, const ushort_t* __restrict__ wf01,
    const float* __restrict__ pb1, float* __restrict__ zout) {
  __shared__ ushort_t Ahi[8192], Alo[8192], Bhi[8192], Blo[8192];
  const int tid = threadIdx.x, lane = tid & 63, wid = tid >> 6;
  const int m0 = blockIdx.x * 64;
  const int y = blockIdx.y;
  stage_A_convert(Ahi, Alo, A, m0, tid);
  f32x4 acc[8];
  f32x4 z = {0.f, 0.f, 0.f, 0.f};
  #pragma unroll
  for (int ct = 0; ct < 8; ct++) acc[ct] = z;
  unit_mfma(acc, wf01 + (size_t)y * 32768, Ahi, Alo, Bhi, Blo, tid, lane, wid);

  const int rbase = m0 + wid * 16 + ((lane >> 4) << 2);
  const int cb = lane & 15;
  #pragma unroll
  for (int ct = 0; ct < 8; ct++) {
    int n = y * 128 + ct * 16 + cb;
    float bv = pb1[n];
    #pragma unroll
    for (int r = 0; r < 4; r++)
      zout[(size_t)(rbase + r) * PROJ_D + n] = acc[ct][r] + bv;
  }
}

// ---------------- fused message + mean-aggregation (2 nodes/block) --------
__global__ __launch_bounds__(256) void agg_kernel(const float* __restrict__ Abuf,
                                                  const float* __restrict__ Bbuf,
                                                  const int* __restrict__ row_ptr,
                                                  const int* __restrict__ col,
                                                  float* __restrict__ agg) {
  int j = blockIdx.x * 2 + (threadIdx.x >> 7);
  int c = threadIdx.x & 127;
  float bj = Bbuf[(size_t)j * HID + c];
  int s = row_ptr[j], e = row_ptr[j + 1];
  float acc = 0.f;
  int p = s;
  for (; p + 4 <= e; p += 4) {
    int i0 = col[p], i1 = col[p+1], i2 = col[p+2], i3 = col[p+3];
    float v0 = Abuf[(size_t)i0 * HID + c];
    float v1 = Abuf[(size_t)i1 * HID + c];
    float v2 = Abuf[(size_t)i2 * HID + c];
    float v3 = Abuf[(size_t)i3 * HID + c];
    acc += fmaxf(v0 + bj, 0.f) + fmaxf(v1 + bj, 0.f)
         + fmaxf(v2 + bj, 0.f) + fmaxf(v3 + bj, 0.f);
  }
  for (; p < e; p++) {
    int i = col[p];
    acc += fmaxf(Abuf[(size_t)i * HID + c] + bj, 0.f);
  }
  float deg = (float)(e - s);
  float inv = 1.0f / fmaxf(deg, 1.0f);
  agg[(size_t)j * HID + c] = acc * inv;
}

extern "C" void kernel_launch(void* const* d_in, const int* in_sizes, int n_in,
                              void* d_out, int out_size, void* d_ws, size_t ws_size,
                              hipStream_t stream) {
  (void)in_sizes; (void)n_in; (void)out_size; (void)ws_size;
  const float* x       = (const float*)d_in[0];
  const float* pos     = (const float*)d_in[1];
  const float* enc_w0  = (const float*)d_in[3];
  const float* enc_b0  = (const float*)d_in[4];
  const float* enc_w1  = (const float*)d_in[5];
  const float* enc_b1  = (const float*)d_in[6];
  const float* msg_w   = (const float*)d_in[7];
  const float* msg_b   = (const float*)d_in[8];
  const float* upd_w   = (const float*)d_in[9];
  const float* upd_b   = (const float*)d_in[10];
  const float* proj_w0 = (const float*)d_in[11];
  const float* proj_b0 = (const float*)d_in[12];
  const float* proj_w1 = (const float*)d_in[13];
  const float* proj_b1 = (const float*)d_in[14];

  char* ws = (char*)d_ws;
  size_t off = 0;
  auto alloc = [&](size_t bytes) -> void* {
    void* p = ws + off;
    off += (bytes + 255) & ~(size_t)255;
    return p;
  };
  int*      nbr     = (int*)alloc((size_t)EE * 4);
  int*      cnt     = (int*)alloc((size_t)BN * 4);
  int*      fill    = (int*)alloc((size_t)BN * 4);
  int*      row_ptr = (int*)alloc((size_t)(BN + 1) * 4);
  int*      col     = (int*)alloc((size_t)EE * 4);
  float*    h_a     = (float*)alloc((size_t)BN * HID * 4);
  float*    h_b     = (float*)alloc((size_t)BN * HID * 4);
  float*    bufA    = (float*)alloc((size_t)BN * HID * 4);
  float*    bufB    = (float*)alloc((size_t)BN * HID * 4);
  float*    bufAgg  = (float*)alloc((size_t)BN * HID * 4);
  ushort_t* wfrag   = (ushort_t*)alloc((size_t)16 * 32768 * 2);
  float*    out     = (float*)d_out;
  float*    hOut    = out + (size_t)BN * PROJ_D;

  hipMemsetAsync(cnt, 0, (size_t)BN * 4 * 2, stream);   // cnt + fill

  prep_w_kernel<<<128, 256, 0, stream>>>(enc_w1, msg_w, upd_w, proj_w0, proj_w1, wfrag);
  knn_kernel<<<BN / QPB, 1024, 0, stream>>>(pos, nbr, cnt);
  scan_kernel<<<1, 256, 0, stream>>>(cnt, row_ptr);
  fill_kernel<<<EE / 256, 256, 0, stream>>>(nbr, row_ptr, fill, col);

  enc0_kernel<<<BN * 32 / 256, 256, 0, stream>>>(x, enc_w0, enc_b0, bufA);
  g1_kernel<1><<<dim3(BN / 64, 2), 256, 0, stream>>>(bufA, wfrag + 0 * 32768,
                                                     enc_b1, h_a);

  float* hc = h_a;
  float* hn = h_b;
  for (int i = 0; i < 3; i++) {
    msg_kernel<<<dim3(BN / 64, 2), 256, 0, stream>>>(
        hc, wfrag + (size_t)(1 + 2 * i) * 32768,
        wfrag + (size_t)(2 + 2 * i) * 32768, msg_b + (size_t)i * HID,
        bufA, bufB);
    agg_kernel<<<BN / 2, 256, 0, stream>>>(bufA, bufB, row_ptr, col, bufAgg);
    float* target = (i == 2) ? hOut : hn;
    upd_kernel<<<dim3(BN / 64, 2), 256, 0, stream>>>(
        hc, wfrag + (size_t)(7 + 2 * i) * 32768, bufAgg,
        wfrag + (size_t)(8 + 2 * i) * 32768, upd_b + (size_t)i * HID, target);
    hn = hc; hc = target;
  }

  g1_kernel<1><<<dim3(BN / 64, 2), 256, 0, stream>>>(hc, wfrag + 13 * 32768,
                                                     proj_b0, bufA);
  proj1_kernel<<<dim3(BN / 64, 2), 256, 0, stream>>>(
      bufA, wfrag + 14 * 32768, proj_b1, out);
}

// Round 15
// 228.975 us; speedup vs baseline: 1.2053x; 1.0614x over previous
//
#include <hip/hip_runtime.h>
#include <stdint.h>
#include <math.h>

#define NN 2048
#define BB 8
#define BN (BB*NN)
#define KK 16
#define EE (BN*KK)
#define HID 128
#define PROJ_D 256
#define QPB 16    // queries (waves) per knn block
#define CDIM 6
#define NCELL (CDIM*CDIM*CDIM)
#define CAP 768   // per-wave candidate list capacity

typedef unsigned long long u64;
typedef unsigned short ushort_t;
typedef __attribute__((ext_vector_type(8))) short short8;
typedef __attribute__((ext_vector_type(4))) float f32x4;

__device__ __forceinline__ u64 wave_min_u64(u64 v) {
  #pragma unroll
  for (int off = 32; off > 0; off >>= 1) {
    u64 o = __shfl_xor(v, off);
    v = o < v ? o : v;
  }
  return v;
}

// ---------------- per-batch counting sort by 6^3 cell ----------------
__global__ __launch_bounds__(256) void cellsort_kernel(
    const float* __restrict__ pos, float4* __restrict__ spos,
    int* __restrict__ cptr) {
  __shared__ int hist[NCELL];
  __shared__ int base[NCELL];
  const int b = blockIdx.x, tid = threadIdx.x;
  if (tid < NCELL) hist[tid] = 0;
  __syncthreads();
  int cellv[8];
  float4 pv[8];
  #pragma unroll
  for (int k = 0; k < 8; k++) {
    int j = tid * 8 + k;
    const float* pp = pos + ((size_t)b * NN + j) * 3;
    float x = pp[0], y = pp[1], z = pp[2];
    int cx = (int)(x * 6.0f); cx = cx > 5 ? 5 : cx;
    int cy = (int)(y * 6.0f); cy = cy > 5 ? 5 : cy;
    int cz = (int)(z * 6.0f); cz = cz > 5 ? 5 : cz;
    int cell = (cx * 6 + cy) * 6 + cz;
    cellv[k] = cell;
    pv[k] = make_float4(x, y, z, __int_as_float(j));
    atomicAdd(&hist[cell], 1);
  }
  __syncthreads();
  if (tid == 0) {
    int run = 0;
    for (int c = 0; c < NCELL; c++) {
      cptr[b * (NCELL + 1) + c] = run;
      base[c] = run;
      run += hist[c];
    }
    cptr[b * (NCELL + 1) + NCELL] = run;   // = NN
  }
  __syncthreads();
  if (tid < NCELL) hist[tid] = 0;          // reuse as fill counters
  __syncthreads();
  #pragma unroll
  for (int k = 0; k < 8; k++) {
    int slot = base[cellv[k]] + atomicAdd(&hist[cellv[k]], 1);
    spos[(size_t)b * NN + slot] = pv[k];
  }
}

// ---------------- kNN via exact cell-pruned histogram selection ----------
// Fast mode: 27-cell neighborhood (~256 cands), hist bins d*1536 < 254.
// Excluded points have d >= 1/6 = 0.1667 > 254/1536 + margin -> if >=17
// candidates bin, top-17 is globally exact (same keys/tie-break as ref).
// Fallback (ovf or <17 binned, P~1e-4): full 2048 scan, scale 256 (exact).
__global__ __launch_bounds__(1024) void knn_kernel(
    const float4* __restrict__ spos, const int* __restrict__ cptr,
    int* __restrict__ nbr, int* __restrict__ cnt) {
  __shared__ float4 Ps[NN];             // 32 KB (sorted; .w = orig idx bits)
  __shared__ unsigned Hist[QPB * 256];  // 16 KB
  __shared__ ushort_t Cand[QPB * CAP];  // 24 KB
  __shared__ int Cp[NCELL + 1];         // 868 B
  const int b  = blockIdx.x >> 7;
  const int qb = blockIdx.x & 127;
  const int wave = threadIdx.x >> 6;
  const int lane = threadIdx.x & 63;
  const int s_q = qb * QPB + wave;      // sorted query slot

  for (int t = threadIdx.x; t < NN; t += 1024)
    Ps[t] = spos[(size_t)b * NN + t];
  if (threadIdx.x <= NCELL)
    Cp[threadIdx.x] = cptr[b * (NCELL + 1) + threadIdx.x];
  __syncthreads();

  const float4 q = Ps[s_q];
  const float xi = q.x, yi = q.y, zi = q.z;
  const int orig_i = __float_as_int(q.w);
  unsigned* H = &Hist[wave * 256];
  ushort_t* CL = &Cand[wave * CAP];

  int cx = (int)(xi * 6.0f); cx = cx > 5 ? 5 : cx;
  int cy = (int)(yi * 6.0f); cy = cy > 5 ? 5 : cy;
  int cz = (int)(zi * 6.0f); cz = cz > 5 ? 5 : cz;

  // build candidate list: 9 columns x (3-z-cell run, <=2 segments w/ wrap)
  int T = 0;
  bool ovf = false;
  #pragma unroll 1
  for (int dxy = 0; dxy < 9; dxy++) {
    int dx = dxy / 3 - 1, dy = dxy - (dxy / 3) * 3 - 1;
    int ncx = cx + dx; ncx += (ncx < 0) ? 6 : 0; ncx -= (ncx >= 6) ? 6 : 0;
    int ncy = cy + dy; ncy += (ncy < 0) ? 6 : 0; ncy -= (ncy >= 6) ? 6 : 0;
    int cbse = (ncx * 6 + ncy) * 6;
    int s0, l0, s1 = 0, l1 = 0;
    if (cz == 0) {
      s0 = Cp[cbse + 5]; l0 = Cp[cbse + 6] - s0;
      s1 = Cp[cbse];     l1 = Cp[cbse + 2] - s1;
    } else if (cz == 5) {
      s0 = Cp[cbse + 4]; l0 = Cp[cbse + 6] - s0;
      s1 = Cp[cbse];     l1 = Cp[cbse + 1] - s1;
    } else {
      s0 = Cp[cbse + cz - 1]; l0 = Cp[cbse + cz + 2] - s0;
    }
    if (T + l0 + l1 > CAP) { ovf = true; break; }
    for (int t = lane; t < l0; t += 64) CL[T + t] = (ushort_t)(s0 + t);
    T += l0;
    for (int t = lane; t < l1; t += 64) CL[T + t] = (ushort_t)(s1 + t);
    T += l1;
  }

  int mode = ovf ? 1 : 0;
  float scale = 1536.0f;
  int T2 = T, binmax = 254;
  int bstar = 0; unsigned C = 0;
  for (;;) {
    scale = mode ? 256.0f : 1536.0f;
    T2 = mode ? NN : T;
    binmax = mode ? 256 : 254;
    *(uint4*)&H[lane * 4] = make_uint4(0u, 0u, 0u, 0u);
    for (int t = lane; t < T2; t += 64) {
      int p = mode ? t : (int)CL[t];
      float4 pj = Ps[p];
      float tx = xi - pj.x, ty = yi - pj.y, tz = zi - pj.z;
      float ddx = __fsub_rn(tx, rintf(tx));
      float ddy = __fsub_rn(ty, rintf(ty));
      float ddz = __fsub_rn(tz, rintf(tz));
      float s = __fadd_rn(__fadd_rn(__fadd_rn(__fmul_rn(ddx,ddx), __fmul_rn(ddy,ddy)),
                                    __fmul_rn(ddz,ddz)), 1e-12f);
      float d = __fsqrt_rn(s);
      int bin = (int)(d * scale);
      if (bin < binmax) atomicAdd(&H[bin], 1u);
    }
    uint4 cv = *(const uint4*)&H[lane * 4];
    unsigned s4 = cv.x + cv.y + cv.z + cv.w;
    unsigned incl = s4;
    #pragma unroll
    for (int off = 1; off < 64; off <<= 1) {
      unsigned v = __shfl_up(incl, off);
      if (lane >= off) incl += v;
    }
    unsigned total = __shfl(incl, 63);
    if (total >= 17u) {
      unsigned base = incl - s4;
      bool has = (incl >= 17u) && (base < 17u);
      u64 hmask = __ballot(has);
      int srcl = __ffsll((unsigned long long)hmask) - 1;
      int bl = 0; unsigned Cl = 0;
      if (has) {
        if (base + cv.x >= 17u)                    { bl = lane*4 + 0; Cl = base; }
        else if (base + cv.x + cv.y >= 17u)        { bl = lane*4 + 1; Cl = base + cv.x; }
        else if (base + cv.x + cv.y + cv.z >= 17u) { bl = lane*4 + 2; Cl = base + cv.x + cv.y; }
        else                                       { bl = lane*4 + 3; Cl = base + cv.x + cv.y + cv.z; }
      }
      bstar = __shfl(bl, srcl);
      C     = __shfl(Cl, srcl);
      break;
    }
    mode = 1;   // fallback: full scan, all bins covered -> total = NN >= 17
  }
  const int m = 17 - (int)C;

  // per-lane sorted members of bin bstar
  u64 lst[6];
  #pragma unroll
  for (int t = 0; t < 6; t++) lst[t] = ~0ull;
  for (int t = lane; t < T2; t += 64) {
    int p = mode ? t : (int)CL[t];
    float4 pj = Ps[p];
    float tx = xi - pj.x, ty = yi - pj.y, tz = zi - pj.z;
    float ddx = __fsub_rn(tx, rintf(tx));
    float ddy = __fsub_rn(ty, rintf(ty));
    float ddz = __fsub_rn(tz, rintf(tz));
    float s = __fadd_rn(__fadd_rn(__fadd_rn(__fmul_rn(ddx,ddx), __fmul_rn(ddy,ddy)),
                                  __fmul_rn(ddz,ddz)), 1e-12f);
    float d = __fsqrt_rn(s);
    int bin = (int)(d * scale);
    if (bin == bstar) {
      u64 key = ((u64)__float_as_uint(d) << 11) | (unsigned)__float_as_int(pj.w);
      if (key < lst[5]) {
        lst[5] = key;
        #pragma unroll
        for (int u = 5; u > 0; u--) {
          u64 a = lst[u-1], c2 = lst[u];
          lst[u-1] = a < c2 ? a : c2;
          lst[u]   = a < c2 ? c2 : a;
        }
      }
    }
  }

  u64 kstar = 0;
  #pragma unroll 1
  for (int r = 0; r < m; r++) {
    u64 h0 = lst[0];
    u64 gm = wave_min_u64(h0);
    kstar = gm;
    bool win = (h0 == gm);
    #pragma unroll
    for (int u = 0; u < 5; u++) lst[u] = win ? lst[u+1] : lst[u];
    lst[5] = win ? ~0ull : lst[5];
  }

  // emission (uniform trip count for ballot)
  int* outp = nbr + ((size_t)b * NN + orig_i) * KK;
  int total_e = 0;
  for (int t0 = 0; t0 < T2; t0 += 64) {
    int t = t0 + lane;
    bool pred = false;
    int oj = 0;
    if (t < T2) {
      int p = mode ? t : (int)CL[t];
      float4 pj = Ps[p];
      float tx = xi - pj.x, ty = yi - pj.y, tz = zi - pj.z;
      float ddx = __fsub_rn(tx, rintf(tx));
      float ddy = __fsub_rn(ty, rintf(ty));
      float ddz = __fsub_rn(tz, rintf(tz));
      float s = __fadd_rn(__fadd_rn(__fadd_rn(__fmul_rn(ddx,ddx), __fmul_rn(ddy,ddy)),
                                    __fmul_rn(ddz,ddz)), 1e-12f);
      float d = __fsqrt_rn(s);
      oj = __float_as_int(pj.w);
      u64 key = ((u64)__float_as_uint(d) << 11) | (unsigned)oj;
      pred = (key <= kstar) && (oj != orig_i);
    }
    u64 msk = __ballot(pred);
    if (pred) {
      int ofs = total_e + __popcll(msk & ((1ull << lane) - 1ull));
      outp[ofs] = b * NN + oj;
      atomicAdd(&cnt[b * NN + oj], 1);
    }
    total_e += __popcll(msk);
  }
}

// ---------------- CSR build ----------------
__global__ __launch_bounds__(256) void scan_kernel(const int* __restrict__ cnt,
                                                   int* __restrict__ row_ptr) {
  __shared__ int ps[256];
  int t = threadIdx.x;
  const int4* cv = (const int4*)(cnt + t * 64);
  int4 c[16];
  int s = 0;
  #pragma unroll
  for (int i = 0; i < 16; i++) {
    c[i] = cv[i];
    s += c[i].x + c[i].y + c[i].z + c[i].w;
  }
  ps[t] = s;
  __syncthreads();
  for (int off = 1; off < 256; off <<= 1) {
    int v = 0;
    if (t >= off) v = ps[t - off];
    __syncthreads();
    ps[t] += v;
    __syncthreads();
  }
  int run = t ? ps[t - 1] : 0;
  int4* rp = (int4*)(row_ptr + t * 64);
  #pragma unroll
  for (int i = 0; i < 16; i++) {
    int4 o;
    o.x = run; run += c[i].x;
    o.y = run; run += c[i].y;
    o.z = run; run += c[i].z;
    o.w = run; run += c[i].w;
    rp[i] = o;
  }
  if (t == 255) row_ptr[BN] = run;
}

__global__ __launch_bounds__(256) void fill_kernel(const int* __restrict__ nbr,
                                                   const int* __restrict__ row_ptr,
                                                   int* __restrict__ fill,
                                                   int* __restrict__ col) {
  int e = blockIdx.x * 256 + threadIdx.x;
  int d = nbr[e];
  int srcn = e >> 4;
  int p = row_ptr[d] + atomicAdd(&fill[d], 1);
  col[p] = srcn;
}

// ---------------- encoder layer 0: (BN,5)@(5,128)+relu ----------------
__global__ __launch_bounds__(256) void enc0_kernel(const float* __restrict__ x,
                                                   const float* __restrict__ w0,
                                                   const float* __restrict__ b0,
                                                   float* __restrict__ h) {
  int t = blockIdx.x * 256 + threadIdx.x;
  int m = t >> 5;
  int c = (t & 31) * 4;
  float xv[5];
  #pragma unroll
  for (int d = 0; d < 5; d++) xv[d] = x[m * 5 + d];
  float4 acc = *(const float4*)&b0[c];
  #pragma unroll
  for (int d = 0; d < 5; d++) {
    float4 w = *(const float4*)&w0[d * HID + c];
    acc.x += xv[d] * w.x; acc.y += xv[d] * w.y;
    acc.z += xv[d] * w.z; acc.w += xv[d] * w.w;
  }
  acc.x = fmaxf(acc.x, 0.f); acc.y = fmaxf(acc.y, 0.f);
  acc.z = fmaxf(acc.z, 0.f); acc.w = fmaxf(acc.w, 0.f);
  *(float4*)&h[(size_t)m * HID + c] = acc;
}

// ================= split-bf16 MFMA machinery (r9-r14, verified) =========
__device__ __forceinline__ unsigned cvtpk_bf16(float a, float b) {
  unsigned r;
  asm("v_cvt_pk_bf16_f32 %0, %1, %2" : "=v"(r) : "v"(a), "v"(b));
  return r;
}

__device__ __forceinline__ void cvt8(const float4 f0, const float4 f1,
                                     short8& hi, short8& lo) {
  unsigned h0 = cvtpk_bf16(f0.x, f0.y);
  unsigned h1 = cvtpk_bf16(f0.z, f0.w);
  unsigned h2 = cvtpk_bf16(f1.x, f1.y);
  unsigned h3 = cvtpk_bf16(f1.z, f1.w);
  unsigned l0 = cvtpk_bf16(f0.x - __uint_as_float(h0 << 16),
                           f0.y - __uint_as_float(h0 & 0xffff0000u));
  unsigned l1 = cvtpk_bf16(f0.z - __uint_as_float(h1 << 16),
                           f0.w - __uint_as_float(h1 & 0xffff0000u));
  unsigned l2 = cvtpk_bf16(f1.x - __uint_as_float(h2 << 16),
                           f1.y - __uint_as_float(h2 & 0xffff0000u));
  unsigned l3 = cvtpk_bf16(f1.z - __uint_as_float(h3 << 16),
                           f1.w - __uint_as_float(h3 & 0xffff0000u));
  union { unsigned u[4]; short8 v; } H, L;
  H.u[0] = h0; H.u[1] = h1; H.u[2] = h2; H.u[3] = h3;
  L.u[0] = l0; L.u[1] = l1; L.u[2] = l2; L.u[3] = l3;
  hi = H.v;
  lo = L.v;
}

// prep: 16 unit-Ws (128x128) -> fragment-ordered bf16 hi/lo
__global__ __launch_bounds__(256) void prep_w_kernel(
    const float* __restrict__ enc_w1, const float* __restrict__ msg_w,
    const float* __restrict__ upd_w, const float* __restrict__ proj_w0,
    const float* __restrict__ proj_w1, ushort_t* __restrict__ wfrag) {
  int u = blockIdx.x >> 3;
  int c = (blockIdx.x & 7) * 256 + threadIdx.x;
  const float* src;
  int ldW = HID;
  if (u == 0) src = enc_w1;
  else if (u <= 6)  { int i = (u-1)>>1; int hf = (u-1)&1; src = msg_w + ((size_t)i*256 + hf*128) * HID; }
  else if (u <= 12) { int i = (u-7)>>1; int hf = (u-7)&1; src = upd_w + ((size_t)i*256 + hf*128) * HID; }
  else if (u == 13) src = proj_w0;
  else { src = proj_w1 + (u - 14) * 128; ldW = PROJ_D; }

  int ks = c >> 9, ct = (c >> 6) & 7, lane = c & 63;
  int colc = ct * 16 + (lane & 15);
  int k0 = ks * 32 + ((lane >> 4) << 3);
  float f[8];
  #pragma unroll
  for (int e = 0; e < 8; e++) f[e] = src[(size_t)(k0 + e) * ldW + colc];
  short8 hv, lv;
  cvt8(make_float4(f[0],f[1],f[2],f[3]), make_float4(f[4],f[5],f[6],f[7]), hv, lv);
  *(short8*)&wfrag[(size_t)u * 32768 + (size_t)c * 8] = hv;
  *(short8*)&wfrag[(size_t)u * 32768 + 16384 + (size_t)c * 8] = lv;
}

// convert 64x128 f32 global rows -> fragment hi/lo in LDS (consumer-side)
__device__ __forceinline__ void stage_A_convert(ushort_t* Ahi, ushort_t* Alo,
                                                const float* A, int m0, int tid) {
  #pragma unroll
  for (int i = 0; i < 4; i++) {
    int c = tid + i * 256;
    int row = c >> 4, kg = c & 15;
    const float4* ap = (const float4*)(A + (((size_t)m0 + row) << 7) + (kg << 3));
    short8 hv, lv;
    cvt8(ap[0], ap[1], hv, lv);
    int idx = (((row >> 4) * 4 + (kg >> 2)) * 64 + ((row & 15) | ((kg & 3) << 4))) * 8;
    *(short8*)&Ahi[idx] = hv;
    *(short8*)&Alo[idx] = lv;
  }
}

// ---- full-N unit (8 col-tiles) ----
__device__ __forceinline__ void unit_mfma(f32x4 acc[8], const ushort_t* wf,
                                          const ushort_t* Ahi, const ushort_t* Alo,
                                          ushort_t* Bhi, ushort_t* Blo,
                                          int tid, int lane, int wid) {
  #pragma unroll 1
  for (int half = 0; half < 2; half++) {
    __syncthreads();
    const short8* ghi = (const short8*)(wf + half * 8192);
    const short8* glo = (const short8*)(wf + 16384 + half * 8192);
    #pragma unroll
    for (int i = 0; i < 4; i++) {
      ((short8*)Bhi)[tid + i * 256] = ghi[tid + i * 256];
      ((short8*)Blo)[tid + i * 256] = glo[tid + i * 256];
    }
    __syncthreads();
    #pragma unroll
    for (int ks2 = 0; ks2 < 2; ks2++) {
      int ksA = half * 2 + ks2;
      short8 ah = *(const short8*)&Ahi[((wid * 4 + ksA) * 64 + lane) * 8];
      short8 al = *(const short8*)&Alo[((wid * 4 + ksA) * 64 + lane) * 8];
      #pragma unroll
      for (int ct = 0; ct < 8; ct++) {
        short8 bh = *(const short8*)&Bhi[((ks2 * 8 + ct) * 64 + lane) * 8];
        short8 bl = *(const short8*)&Blo[((ks2 * 8 + ct) * 64 + lane) * 8];
        acc[ct] = __builtin_amdgcn_mfma_f32_16x16x32_bf16(ah, bh, acc[ct], 0, 0, 0);
        acc[ct] = __builtin_amdgcn_mfma_f32_16x16x32_bf16(ah, bl, acc[ct], 0, 0, 0);
        acc[ct] = __builtin_amdgcn_mfma_f32_16x16x32_bf16(al, bh, acc[ct], 0, 0, 0);
      }
    }
  }
}

// ---- N-half unit (4 col-tiles, ct0 = 0 or 4) ----
__device__ __forceinline__ void unit_mfma_h(f32x4 acc[4], const ushort_t* wf,
                                            int ct0,
                                            const ushort_t* Ahi, const ushort_t* Alo,
                                            ushort_t* Bhi, ushort_t* Blo,
                                            int tid, int lane, int wid) {
  #pragma unroll 1
  for (int half = 0; half < 2; half++) {
    __syncthreads();
    #pragma unroll
    for (int i = 0; i < 2; i++) {
      int sc = tid + i * 256;             // 0..511
      int ks2 = sc >> 8;
      int cts = (sc >> 6) & 3;
      int ln  = sc & 63;
      int c = half * 1024 + ks2 * 512 + (ct0 + cts) * 64 + ln;
      ((short8*)Bhi)[sc] = *(const short8*)&wf[(size_t)c * 8];
      ((short8*)Blo)[sc] = *(const short8*)&wf[16384 + (size_t)c * 8];
    }
    __syncthreads();
    #pragma unroll
    for (int ks2 = 0; ks2 < 2; ks2++) {
      int ksA = half * 2 + ks2;
      short8 ah = *(const short8*)&Ahi[((wid * 4 + ksA) * 64 + lane) * 8];
      short8 al = *(const short8*)&Alo[((wid * 4 + ksA) * 64 + lane) * 8];
      #pragma unroll
      for (int ct = 0; ct < 4; ct++) {
        short8 bh = *(const short8*)&Bhi[((ks2 * 4 + ct) * 64 + lane) * 8];
        short8 bl = *(const short8*)&Blo[((ks2 * 4 + ct) * 64 + lane) * 8];
        acc[ct] = __builtin_amdgcn_mfma_f32_16x16x32_bf16(ah, bh, acc[ct], 0, 0, 0);
        acc[ct] = __builtin_amdgcn_mfma_f32_16x16x32_bf16(ah, bl, acc[ct], 0, 0, 0);
        acc[ct] = __builtin_amdgcn_mfma_f32_16x16x32_bf16(al, bh, acc[ct], 0, 0, 0);
      }
    }
  }
}

// ---------------- g1 (N-split): out = [relu](A@W + bias), grid (256,2) -----
template<int RELU>
__global__ __launch_bounds__(256, 4) void g1_kernel(
    const float* __restrict__ A, const ushort_t* __restrict__ wf,
    const float* __restrict__ bias, float* __restrict__ out) {
  __shared__ ushort_t Ahi[8192], Alo[8192], Bhi[4096], Blo[4096];
  const int tid = threadIdx.x, lane = tid & 63, wid = tid >> 6;
  const int m0 = blockIdx.x * 64, ct0 = blockIdx.y * 4;
  stage_A_convert(Ahi, Alo, A, m0, tid);
  f32x4 acc[4];
  f32x4 z = {0.f, 0.f, 0.f, 0.f};
  #pragma unroll
  for (int ct = 0; ct < 4; ct++) acc[ct] = z;
  unit_mfma_h(acc, wf, ct0, Ahi, Alo, Bhi, Blo, tid, lane, wid);

  const int rbase = m0 + wid * 16 + ((lane >> 4) << 2);
  const int cb = lane & 15;
  #pragma unroll
  for (int ct = 0; ct < 4; ct++) {
    int n = (ct0 + ct) * 16 + cb;
    float bv = bias ? bias[n] : 0.f;
    #pragma unroll
    for (int r = 0; r < 4; r++) {
      float v = acc[ct][r] + bv;
      if (RELU) v = fmaxf(v, 0.f);
      out[(size_t)(rbase + r) * HID + n] = v;
    }
  }
}

// ---------------- msg pair (full-N, grid (256,2) y=top/bot) ------
__global__ __launch_bounds__(256, 4) void msg_kernel(
    const float* __restrict__ h, const ushort_t* __restrict__ wfT,
    const ushort_t* __restrict__ wfB, const float* __restrict__ mb,
    float* __restrict__ bufA, float* __restrict__ bufB) {
  __shared__ ushort_t Ahi[8192], Alo[8192], Bhi[8192], Blo[8192];
  const int tid = threadIdx.x, lane = tid & 63, wid = tid >> 6;
  const int m0 = blockIdx.x * 64;
  const int y = blockIdx.y;
  stage_A_convert(Ahi, Alo, h, m0, tid);
  f32x4 acc[8];
  f32x4 z = {0.f, 0.f, 0.f, 0.f};
  #pragma unroll
  for (int ct = 0; ct < 8; ct++) acc[ct] = z;
  unit_mfma(acc, y ? wfB : wfT, Ahi, Alo, Bhi, Blo, tid, lane, wid);

  float* out = y ? bufB : bufA;
  const float* bias = y ? mb : nullptr;
  const int rbase = m0 + wid * 16 + ((lane >> 4) << 2);
  const int cb = lane & 15;
  #pragma unroll
  for (int ct = 0; ct < 8; ct++) {
    int n = ct * 16 + cb;
    float bv = bias ? bias[n] : 0.f;
    #pragma unroll
    for (int r = 0; r < 4; r++)
      out[(size_t)(rbase + r) * HID + n] = acc[ct][r] + bv;
  }
}

// ---------------- upd (N-split): h' = h + relu(h@Wt + agg@Wb + ub) ---------
__global__ __launch_bounds__(256, 4) void upd_kernel(
    const float* __restrict__ h, const ushort_t* __restrict__ wuT,
    const float* __restrict__ aggF, const ushort_t* __restrict__ wuB,
    const float* __restrict__ ub, float* __restrict__ out) {
  __shared__ ushort_t Ahi[8192], Alo[8192], Bhi[4096], Blo[4096];
  const int tid = threadIdx.x, lane = tid & 63, wid = tid >> 6;
  const int m0 = blockIdx.x * 64, ct0 = blockIdx.y * 4;
  stage_A_convert(Ahi, Alo, h, m0, tid);
  f32x4 acc[4];
  f32x4 z = {0.f, 0.f, 0.f, 0.f};
  #pragma unroll
  for (int ct = 0; ct < 4; ct++) acc[ct] = z;
  unit_mfma_h(acc, wuT, ct0, Ahi, Alo, Bhi, Blo, tid, lane, wid);
  __syncthreads();                         // phase-1 A reads done
  stage_A_convert(Ahi, Alo, aggF, m0, tid);
  unit_mfma_h(acc, wuB, ct0, Ahi, Alo, Bhi, Blo, tid, lane, wid);

  const int rbase = m0 + wid * 16 + ((lane >> 4) << 2);
  const int cb = lane & 15;
  #pragma unroll
  for (int ct = 0; ct < 4; ct++) {
    int n = (ct0 + ct) * 16 + cb;
    float bv = ub[n];
    #pragma unroll
    for (int r = 0; r < 4; r++) {
      float v = fmaxf(acc[ct][r] + bv, 0.f)
              + h[(size_t)(rbase + r) * HID + n];
      out[(size_t)(rbase + r) * HID + n] = v;
    }
  }
}

// ---------------- proj1 (full-N, grid (256,2) y=col-block) -------
__global__ __launch_bounds__(256, 4) void proj1_kernel(
    const float* __restrict__ A, const ushort_t* __restrict__ wf01,
    const float* __restrict__ pb1, float* __restrict__ zout) {
  __shared__ ushort_t Ahi[8192], Alo[8192], Bhi[8192], Blo[8192];
  const int tid = threadIdx.x, lane = tid & 63, wid = tid >> 6;
  const int m0 = blockIdx.x * 64;
  const int y = blockIdx.y;
  stage_A_convert(Ahi, Alo, A, m0, tid);
  f32x4 acc[8];
  f32x4 z = {0.f, 0.f, 0.f, 0.f};
  #pragma unroll
  for (int ct = 0; ct < 8; ct++) acc[ct] = z;
  unit_mfma(acc, wf01 + (size_t)y * 32768, Ahi, Alo, Bhi, Blo, tid, lane, wid);

  const int rbase = m0 + wid * 16 + ((lane >> 4) << 2);
  const int cb = lane & 15;
  #pragma unroll
  for (int ct = 0; ct < 8; ct++) {
    int n = y * 128 + ct * 16 + cb;
    float bv = pb1[n];
    #pragma unroll
    for (int r = 0; r < 4; r++)
      zout[(size_t)(rbase + r) * PROJ_D + n] = acc[ct][r] + bv;
  }
}

// ---------------- fused message + mean-aggregation (2 nodes/block) --------
__global__ __launch_bounds__(256) void agg_kernel(const float* __restrict__ Abuf,
                                                  const float* __restrict__ Bbuf,
                                                  const int* __restrict__ row_ptr,
                                                  const int* __restrict__ col,
                                                  float* __restrict__ agg) {
  int j = blockIdx.x * 2 + (threadIdx.x >> 7);
  int c = threadIdx.x & 127;
  float bj = Bbuf[(size_t)j * HID + c];
  int s = row_ptr[j], e = row_ptr[j + 1];
  float acc = 0.f;
  int p = s;
  for (; p + 4 <= e; p += 4) {
    int i0 = col[p], i1 = col[p+1], i2 = col[p+2], i3 = col[p+3];
    float v0 = Abuf[(size_t)i0 * HID + c];
    float v1 = Abuf[(size_t)i1 * HID + c];
    float v2 = Abuf[(size_t)i2 * HID + c];
    float v3 = Abuf[(size_t)i3 * HID + c];
    acc += fmaxf(v0 + bj, 0.f) + fmaxf(v1 + bj, 0.f)
         + fmaxf(v2 + bj, 0.f) + fmaxf(v3 + bj, 0.f);
  }
  for (; p < e; p++) {
    int i = col[p];
    acc += fmaxf(Abuf[(size_t)i * HID + c] + bj, 0.f);
  }
  float deg = (float)(e - s);
  float inv = 1.0f / fmaxf(deg, 1.0f);
  agg[(size_t)j * HID + c] = acc * inv;
}

extern "C" void kernel_launch(void* const* d_in, const int* in_sizes, int n_in,
                              void* d_out, int out_size, void* d_ws, size_t ws_size,
                              hipStream_t stream) {
  (void)in_sizes; (void)n_in; (void)out_size; (void)ws_size;
  const float* x       = (const float*)d_in[0];
  const float* pos     = (const float*)d_in[1];
  const float* enc_w0  = (const float*)d_in[3];
  const float* enc_b0  = (const float*)d_in[4];
  const float* enc_w1  = (const float*)d_in[5];
  const float* enc_b1  = (const float*)d_in[6];
  const float* msg_w   = (const float*)d_in[7];
  const float* msg_b   = (const float*)d_in[8];
  const float* upd_w   = (const float*)d_in[9];
  const float* upd_b   = (const float*)d_in[10];
  const float* proj_w0 = (const float*)d_in[11];
  const float* proj_b0 = (const float*)d_in[12];
  const float* proj_w1 = (const float*)d_in[13];
  const float* proj_b1 = (const float*)d_in[14];

  char* ws = (char*)d_ws;
  size_t off = 0;
  auto alloc = [&](size_t bytes) -> void* {
    void* p = ws + off;
    off += (bytes + 255) & ~(size_t)255;
    return p;
  };
  int*      nbr     = (int*)alloc((size_t)EE * 4);
  int*      cnt     = (int*)alloc((size_t)BN * 4);
  int*      fill    = (int*)alloc((size_t)BN * 4);
  int*      row_ptr = (int*)alloc((size_t)(BN + 1) * 4);
  int*      col     = (int*)alloc((size_t)EE * 4);
  float*    h_a     = (float*)alloc((size_t)BN * HID * 4);
  float*    h_b     = (float*)alloc((size_t)BN * HID * 4);
  float*    bufA    = (float*)alloc((size_t)BN * HID * 4);
  float*    bufB    = (float*)alloc((size_t)BN * HID * 4);
  float*    bufAgg  = (float*)alloc((size_t)BN * HID * 4);
  ushort_t* wfrag   = (ushort_t*)alloc((size_t)16 * 32768 * 2);
  float4*   spos    = (float4*)alloc((size_t)BN * 16);
  int*      cptr    = (int*)alloc((size_t)BB * (NCELL + 1) * 4);
  float*    out     = (float*)d_out;
  float*    hOut    = out + (size_t)BN * PROJ_D;

  hipMemsetAsync(cnt, 0, (size_t)BN * 4 * 2, stream);   // cnt + fill

  cellsort_kernel<<<BB, 256, 0, stream>>>(pos, spos, cptr);
  prep_w_kernel<<<128, 256, 0, stream>>>(enc_w1, msg_w, upd_w, proj_w0, proj_w1, wfrag);
  knn_kernel<<<BN / QPB, 1024, 0, stream>>>(spos, cptr, nbr, cnt);
  scan_kernel<<<1, 256, 0, stream>>>(cnt, row_ptr);
  fill_kernel<<<EE / 256, 256, 0, stream>>>(nbr, row_ptr, fill, col);

  enc0_kernel<<<BN * 32 / 256, 256, 0, stream>>>(x, enc_w0, enc_b0, bufA);
  g1_kernel<1><<<dim3(BN / 64, 2), 256, 0, stream>>>(bufA, wfrag + 0 * 32768,
                                                     enc_b1, h_a);

  float* hc = h_a;
  float* hn = h_b;
  for (int i = 0; i < 3; i++) {
    msg_kernel<<<dim3(BN / 64, 2), 256, 0, stream>>>(
        hc, wfrag + (size_t)(1 + 2 * i) * 32768,
        wfrag + (size_t)(2 + 2 * i) * 32768, msg_b + (size_t)i * HID,
        bufA, bufB);
    agg_kernel<<<BN / 2, 256, 0, stream>>>(bufA, bufB, row_ptr, col, bufAgg);
    float* target = (i == 2) ? hOut : hn;
    upd_kernel<<<dim3(BN / 64, 2), 256, 0, stream>>>(
        hc, wfrag + (size_t)(7 + 2 * i) * 32768, bufAgg,
        wfrag + (size_t)(8 + 2 * i) * 32768, upd_b + (size_t)i * HID, target);
    hn = hc; hc = target;
  }

  g1_kernel<1><<<dim3(BN / 64, 2), 256, 0, stream>>>(hc, wfrag + 13 * 32768,
                                                     proj_b0, bufA);
  proj1_kernel<<<dim3(BN / 64, 2), 256, 0, stream>>>(
      bufA, wfrag + 14 * 32768, proj_b1, out);
}

// Round 16
// 228.600 us; speedup vs baseline: 1.2072x; 1.0016x over previous
//
#include <hip/hip_runtime.h>
#include <stdint.h>
#include <math.h>

#define NN 2048
#define BB 8
#define BN (BB*NN)
#define KK 16
#define EE (BN*KK)
#define HID 128
#define PROJ_D 256
#define QPB 16    // queries (waves) per knn block
#define CDIM 6
#define NCELL (CDIM*CDIM*CDIM)
#define CAP 768   // per-wave candidate list capacity

typedef unsigned long long u64;
typedef unsigned short ushort_t;
typedef __attribute__((ext_vector_type(8))) short short8;
typedef __attribute__((ext_vector_type(4))) float f32x4;

__device__ __forceinline__ u64 wave_min_u64(u64 v) {
  #pragma unroll
  for (int off = 32; off > 0; off >>= 1) {
    u64 o = __shfl_xor(v, off);
    v = o < v ? o : v;
  }
  return v;
}

// ---------------- zero scratch (cnt+fill): 256 KB in one parallel sweep ----
// r16: hipMemsetAsync dispatched __amd_rocclr_fillBufferAligned at ~43us
// (3.5 GB/s, 8.5% occupancy) -- 19% of total runtime. This does it in ~2us.
__global__ __launch_bounds__(256) void zero_kernel(int4* __restrict__ p) {
  p[blockIdx.x * 256 + threadIdx.x] = make_int4(0, 0, 0, 0);
}

// ---------------- per-batch counting sort by 6^3 cell ----------------
__global__ __launch_bounds__(256) void cellsort_kernel(
    const float* __restrict__ pos, float4* __restrict__ spos,
    int* __restrict__ cptr) {
  __shared__ int hist[NCELL];
  __shared__ int base[NCELL];
  const int b = blockIdx.x, tid = threadIdx.x;
  if (tid < NCELL) hist[tid] = 0;
  __syncthreads();
  int cellv[8];
  float4 pv[8];
  #pragma unroll
  for (int k = 0; k < 8; k++) {
    int j = tid * 8 + k;
    const float* pp = pos + ((size_t)b * NN + j) * 3;
    float x = pp[0], y = pp[1], z = pp[2];
    int cx = (int)(x * 6.0f); cx = cx > 5 ? 5 : cx;
    int cy = (int)(y * 6.0f); cy = cy > 5 ? 5 : cy;
    int cz = (int)(z * 6.0f); cz = cz > 5 ? 5 : cz;
    int cell = (cx * 6 + cy) * 6 + cz;
    cellv[k] = cell;
    pv[k] = make_float4(x, y, z, __int_as_float(j));
    atomicAdd(&hist[cell], 1);
  }
  __syncthreads();
  if (tid == 0) {
    int run = 0;
    for (int c = 0; c < NCELL; c++) {
      cptr[b * (NCELL + 1) + c] = run;
      base[c] = run;
      run += hist[c];
    }
    cptr[b * (NCELL + 1) + NCELL] = run;   // = NN
  }
  __syncthreads();
  if (tid < NCELL) hist[tid] = 0;          // reuse as fill counters
  __syncthreads();
  #pragma unroll
  for (int k = 0; k < 8; k++) {
    int slot = base[cellv[k]] + atomicAdd(&hist[cellv[k]], 1);
    spos[(size_t)b * NN + slot] = pv[k];
  }
}

// ---------------- kNN via exact cell-pruned histogram selection ----------
// Fast mode: 27-cell neighborhood (~256 cands), hist bins d*1536 < 254.
// Excluded points have d >= 1/6 -> if >=17 candidates bin, top-17 is
// globally exact (same keys/tie-break as ref). Fallback: full scan.
__global__ __launch_bounds__(1024) void knn_kernel(
    const float4* __restrict__ spos, const int* __restrict__ cptr,
    int* __restrict__ nbr, int* __restrict__ cnt) {
  __shared__ float4 Ps[NN];             // 32 KB (sorted; .w = orig idx bits)
  __shared__ unsigned Hist[QPB * 256];  // 16 KB
  __shared__ ushort_t Cand[QPB * CAP];  // 24 KB
  __shared__ int Cp[NCELL + 1];
  const int b  = blockIdx.x >> 7;
  const int qb = blockIdx.x & 127;
  const int wave = threadIdx.x >> 6;
  const int lane = threadIdx.x & 63;
  const int s_q = qb * QPB + wave;      // sorted query slot

  for (int t = threadIdx.x; t < NN; t += 1024)
    Ps[t] = spos[(size_t)b * NN + t];
  if (threadIdx.x <= NCELL)
    Cp[threadIdx.x] = cptr[b * (NCELL + 1) + threadIdx.x];
  __syncthreads();

  const float4 q = Ps[s_q];
  const float xi = q.x, yi = q.y, zi = q.z;
  const int orig_i = __float_as_int(q.w);
  unsigned* H = &Hist[wave * 256];
  ushort_t* CL = &Cand[wave * CAP];

  int cx = (int)(xi * 6.0f); cx = cx > 5 ? 5 : cx;
  int cy = (int)(yi * 6.0f); cy = cy > 5 ? 5 : cy;
  int cz = (int)(zi * 6.0f); cz = cz > 5 ? 5 : cz;

  // build candidate list: 9 columns x (3-z-cell run, <=2 segments w/ wrap)
  int T = 0;
  bool ovf = false;
  #pragma unroll 1
  for (int dxy = 0; dxy < 9; dxy++) {
    int dx = dxy / 3 - 1, dy = dxy - (dxy / 3) * 3 - 1;
    int ncx = cx + dx; ncx += (ncx < 0) ? 6 : 0; ncx -= (ncx >= 6) ? 6 : 0;
    int ncy = cy + dy; ncy += (ncy < 0) ? 6 : 0; ncy -= (ncy >= 6) ? 6 : 0;
    int cbse = (ncx * 6 + ncy) * 6;
    int s0, l0, s1 = 0, l1 = 0;
    if (cz == 0) {
      s0 = Cp[cbse + 5]; l0 = Cp[cbse + 6] - s0;
      s1 = Cp[cbse];     l1 = Cp[cbse + 2] - s1;
    } else if (cz == 5) {
      s0 = Cp[cbse + 4]; l0 = Cp[cbse + 6] - s0;
      s1 = Cp[cbse];     l1 = Cp[cbse + 1] - s1;
    } else {
      s0 = Cp[cbse + cz - 1]; l0 = Cp[cbse + cz + 2] - s0;
    }
    if (T + l0 + l1 > CAP) { ovf = true; break; }
    for (int t = lane; t < l0; t += 64) CL[T + t] = (ushort_t)(s0 + t);
    T += l0;
    for (int t = lane; t < l1; t += 64) CL[T + t] = (ushort_t)(s1 + t);
    T += l1;
  }

  int mode = ovf ? 1 : 0;
  float scale = 1536.0f;
  int T2 = T, binmax = 254;
  int bstar = 0; unsigned C = 0;
  for (;;) {
    scale = mode ? 256.0f : 1536.0f;
    T2 = mode ? NN : T;
    binmax = mode ? 256 : 254;
    *(uint4*)&H[lane * 4] = make_uint4(0u, 0u, 0u, 0u);
    for (int t = lane; t < T2; t += 64) {
      int p = mode ? t : (int)CL[t];
      float4 pj = Ps[p];
      float tx = xi - pj.x, ty = yi - pj.y, tz = zi - pj.z;
      float ddx = __fsub_rn(tx, rintf(tx));
      float ddy = __fsub_rn(ty, rintf(ty));
      float ddz = __fsub_rn(tz, rintf(tz));
      float s = __fadd_rn(__fadd_rn(__fadd_rn(__fmul_rn(ddx,ddx), __fmul_rn(ddy,ddy)),
                                    __fmul_rn(ddz,ddz)), 1e-12f);
      float d = __fsqrt_rn(s);
      int bin = (int)(d * scale);
      if (bin < binmax) atomicAdd(&H[bin], 1u);
    }
    uint4 cv = *(const uint4*)&H[lane * 4];
    unsigned s4 = cv.x + cv.y + cv.z + cv.w;
    unsigned incl = s4;
    #pragma unroll
    for (int off = 1; off < 64; off <<= 1) {
      unsigned v = __shfl_up(incl, off);
      if (lane >= off) incl += v;
    }
    unsigned total = __shfl(incl, 63);
    if (total >= 17u) {
      unsigned base = incl - s4;
      bool has = (incl >= 17u) && (base < 17u);
      u64 hmask = __ballot(has);
      int srcl = __ffsll((unsigned long long)hmask) - 1;
      int bl = 0; unsigned Cl = 0;
      if (has) {
        if (base + cv.x >= 17u)                    { bl = lane*4 + 0; Cl = base; }
        else if (base + cv.x + cv.y >= 17u)        { bl = lane*4 + 1; Cl = base + cv.x; }
        else if (base + cv.x + cv.y + cv.z >= 17u) { bl = lane*4 + 2; Cl = base + cv.x + cv.y; }
        else                                       { bl = lane*4 + 3; Cl = base + cv.x + cv.y + cv.z; }
      }
      bstar = __shfl(bl, srcl);
      C     = __shfl(Cl, srcl);
      break;
    }
    mode = 1;   // fallback: full scan, all bins covered -> total = NN >= 17
  }
  const int m = 17 - (int)C;

  // per-lane sorted members of bin bstar
  u64 lst[6];
  #pragma unroll
  for (int t = 0; t < 6; t++) lst[t] = ~0ull;
  for (int t = lane; t < T2; t += 64) {
    int p = mode ? t : (int)CL[t];
    float4 pj = Ps[p];
    float tx = xi - pj.x, ty = yi - pj.y, tz = zi - pj.z;
    float ddx = __fsub_rn(tx, rintf(tx));
    float ddy = __fsub_rn(ty, rintf(ty));
    float ddz = __fsub_rn(tz, rintf(tz));
    float s = __fadd_rn(__fadd_rn(__fadd_rn(__fmul_rn(ddx,ddx), __fmul_rn(ddy,ddy)),
                                  __fmul_rn(ddz,ddz)), 1e-12f);
    float d = __fsqrt_rn(s);
    int bin = (int)(d * scale);
    if (bin == bstar) {
      u64 key = ((u64)__float_as_uint(d) << 11) | (unsigned)__float_as_int(pj.w);
      if (key < lst[5]) {
        lst[5] = key;
        #pragma unroll
        for (int u = 5; u > 0; u--) {
          u64 a = lst[u-1], c2 = lst[u];
          lst[u-1] = a < c2 ? a : c2;
          lst[u]   = a < c2 ? c2 : a;
        }
      }
    }
  }

  u64 kstar = 0;
  #pragma unroll 1
  for (int r = 0; r < m; r++) {
    u64 h0 = lst[0];
    u64 gm = wave_min_u64(h0);
    kstar = gm;
    bool win = (h0 == gm);
    #pragma unroll
    for (int u = 0; u < 5; u++) lst[u] = win ? lst[u+1] : lst[u];
    lst[5] = win ? ~0ull : lst[5];
  }

  // emission (uniform trip count for ballot)
  int* outp = nbr + ((size_t)b * NN + orig_i) * KK;
  int total_e = 0;
  for (int t0 = 0; t0 < T2; t0 += 64) {
    int t = t0 + lane;
    bool pred = false;
    int oj = 0;
    if (t < T2) {
      int p = mode ? t : (int)CL[t];
      float4 pj = Ps[p];
      float tx = xi - pj.x, ty = yi - pj.y, tz = zi - pj.z;
      float ddx = __fsub_rn(tx, rintf(tx));
      float ddy = __fsub_rn(ty, rintf(ty));
      float ddz = __fsub_rn(tz, rintf(tz));
      float s = __fadd_rn(__fadd_rn(__fadd_rn(__fmul_rn(ddx,ddx), __fmul_rn(ddy,ddy)),
                                    __fmul_rn(ddz,ddz)), 1e-12f);
      float d = __fsqrt_rn(s);
      oj = __float_as_int(pj.w);
      u64 key = ((u64)__float_as_uint(d) << 11) | (unsigned)oj;
      pred = (key <= kstar) && (oj != orig_i);
    }
    u64 msk = __ballot(pred);
    if (pred) {
      int ofs = total_e + __popcll(msk & ((1ull << lane) - 1ull));
      outp[ofs] = b * NN + oj;
      atomicAdd(&cnt[b * NN + oj], 1);
    }
    total_e += __popcll(msk);
  }
}

// ---------------- CSR build ----------------
__global__ __launch_bounds__(256) void scan_kernel(const int* __restrict__ cnt,
                                                   int* __restrict__ row_ptr) {
  __shared__ int ps[256];
  int t = threadIdx.x;
  const int4* cv = (const int4*)(cnt + t * 64);
  int4 c[16];
  int s = 0;
  #pragma unroll
  for (int i = 0; i < 16; i++) {
    c[i] = cv[i];
    s += c[i].x + c[i].y + c[i].z + c[i].w;
  }
  ps[t] = s;
  __syncthreads();
  for (int off = 1; off < 256; off <<= 1) {
    int v = 0;
    if (t >= off) v = ps[t - off];
    __syncthreads();
    ps[t] += v;
    __syncthreads();
  }
  int run = t ? ps[t - 1] : 0;
  int4* rp = (int4*)(row_ptr + t * 64);
  #pragma unroll
  for (int i = 0; i < 16; i++) {
    int4 o;
    o.x = run; run += c[i].x;
    o.y = run; run += c[i].y;
    o.z = run; run += c[i].z;
    o.w = run; run += c[i].w;
    rp[i] = o;
  }
  if (t == 255) row_ptr[BN] = run;
}

__global__ __launch_bounds__(256) void fill_kernel(const int* __restrict__ nbr,
                                                   const int* __restrict__ row_ptr,
                                                   int* __restrict__ fill,
                                                   int* __restrict__ col) {
  int e = blockIdx.x * 256 + threadIdx.x;
  int d = nbr[e];
  int srcn = e >> 4;
  int p = row_ptr[d] + atomicAdd(&fill[d], 1);
  col[p] = srcn;
}

// ---------------- encoder layer 0: (BN,5)@(5,128)+relu ----------------
__global__ __launch_bounds__(256) void enc0_kernel(const float* __restrict__ x,
                                                   const float* __restrict__ w0,
                                                   const float* __restrict__ b0,
                                                   float* __restrict__ h) {
  int t = blockIdx.x * 256 + threadIdx.x;
  int m = t >> 5;
  int c = (t & 31) * 4;
  float xv[5];
  #pragma unroll
  for (int d = 0; d < 5; d++) xv[d] = x[m * 5 + d];
  float4 acc = *(const float4*)&b0[c];
  #pragma unroll
  for (int d = 0; d < 5; d++) {
    float4 w = *(const float4*)&w0[d * HID + c];
    acc.x += xv[d] * w.x; acc.y += xv[d] * w.y;
    acc.z += xv[d] * w.z; acc.w += xv[d] * w.w;
  }
  acc.x = fmaxf(acc.x, 0.f); acc.y = fmaxf(acc.y, 0.f);
  acc.z = fmaxf(acc.z, 0.f); acc.w = fmaxf(acc.w, 0.f);
  *(float4*)&h[(size_t)m * HID + c] = acc;
}

// ================= split-bf16 MFMA machinery (r9-r14, verified) =========
__device__ __forceinline__ unsigned cvtpk_bf16(float a, float b) {
  unsigned r;
  asm("v_cvt_pk_bf16_f32 %0, %1, %2" : "=v"(r) : "v"(a), "v"(b));
  return r;
}

__device__ __forceinline__ void cvt8(const float4 f0, const float4 f1,
                                     short8& hi, short8& lo) {
  unsigned h0 = cvtpk_bf16(f0.x, f0.y);
  unsigned h1 = cvtpk_bf16(f0.z, f0.w);
  unsigned h2 = cvtpk_bf16(f1.x, f1.y);
  unsigned h3 = cvtpk_bf16(f1.z, f1.w);
  unsigned l0 = cvtpk_bf16(f0.x - __uint_as_float(h0 << 16),
                           f0.y - __uint_as_float(h0 & 0xffff0000u));
  unsigned l1 = cvtpk_bf16(f0.z - __uint_as_float(h1 << 16),
                           f0.w - __uint_as_float(h1 & 0xffff0000u));
  unsigned l2 = cvtpk_bf16(f1.x - __uint_as_float(h2 << 16),
                           f1.y - __uint_as_float(h2 & 0xffff0000u));
  unsigned l3 = cvtpk_bf16(f1.z - __uint_as_float(h3 << 16),
                           f1.w - __uint_as_float(h3 & 0xffff0000u));
  union { unsigned u[4]; short8 v; } H, L;
  H.u[0] = h0; H.u[1] = h1; H.u[2] = h2; H.u[3] = h3;
  L.u[0] = l0; L.u[1] = l1; L.u[2] = l2; L.u[3] = l3;
  hi = H.v;
  lo = L.v;
}

// prep: 16 unit-Ws (128x128) -> fragment-ordered bf16 hi/lo
__global__ __launch_bounds__(256) void prep_w_kernel(
    const float* __restrict__ enc_w1, const float* __restrict__ msg_w,
    const float* __restrict__ upd_w, const float* __restrict__ proj_w0,
    const float* __restrict__ proj_w1, ushort_t* __restrict__ wfrag) {
  int u = blockIdx.x >> 3;
  int c = (blockIdx.x & 7) * 256 + threadIdx.x;
  const float* src;
  int ldW = HID;
  if (u == 0) src = enc_w1;
  else if (u <= 6)  { int i = (u-1)>>1; int hf = (u-1)&1; src = msg_w + ((size_t)i*256 + hf*128) * HID; }
  else if (u <= 12) { int i = (u-7)>>1; int hf = (u-7)&1; src = upd_w + ((size_t)i*256 + hf*128) * HID; }
  else if (u == 13) src = proj_w0;
  else { src = proj_w1 + (u - 14) * 128; ldW = PROJ_D; }

  int ks = c >> 9, ct = (c >> 6) & 7, lane = c & 63;
  int colc = ct * 16 + (lane & 15);
  int k0 = ks * 32 + ((lane >> 4) << 3);
  float f[8];
  #pragma unroll
  for (int e = 0; e < 8; e++) f[e] = src[(size_t)(k0 + e) * ldW + colc];
  short8 hv, lv;
  cvt8(make_float4(f[0],f[1],f[2],f[3]), make_float4(f[4],f[5],f[6],f[7]), hv, lv);
  *(short8*)&wfrag[(size_t)u * 32768 + (size_t)c * 8] = hv;
  *(short8*)&wfrag[(size_t)u * 32768 + 16384 + (size_t)c * 8] = lv;
}

// convert 64x128 f32 global rows -> fragment hi/lo in LDS (consumer-side)
__device__ __forceinline__ void stage_A_convert(ushort_t* Ahi, ushort_t* Alo,
                                                const float* A, int m0, int tid) {
  #pragma unroll
  for (int i = 0; i < 4; i++) {
    int c = tid + i * 256;
    int row = c >> 4, kg = c & 15;
    const float4* ap = (const float4*)(A + (((size_t)m0 + row) << 7) + (kg << 3));
    short8 hv, lv;
    cvt8(ap[0], ap[1], hv, lv);
    int idx = (((row >> 4) * 4 + (kg >> 2)) * 64 + ((row & 15) | ((kg & 3) << 4))) * 8;
    *(short8*)&Ahi[idx] = hv;
    *(short8*)&Alo[idx] = lv;
  }
}

// ---- full-N unit (8 col-tiles) ----
__device__ __forceinline__ void unit_mfma(f32x4 acc[8], const ushort_t* wf,
                                          const ushort_t* Ahi, const ushort_t* Alo,
                                          ushort_t* Bhi, ushort_t* Blo,
                                          int tid, int lane, int wid) {
  #pragma unroll 1
  for (int half = 0; half < 2; half++) {
    __syncthreads();
    const short8* ghi = (const short8*)(wf + half * 8192);
    const short8* glo = (const short8*)(wf + 16384 + half * 8192);
    #pragma unroll
    for (int i = 0; i < 4; i++) {
      ((short8*)Bhi)[tid + i * 256] = ghi[tid + i * 256];
      ((short8*)Blo)[tid + i * 256] = glo[tid + i * 256];
    }
    __syncthreads();
    #pragma unroll
    for (int ks2 = 0; ks2 < 2; ks2++) {
      int ksA = half * 2 + ks2;
      short8 ah = *(const short8*)&Ahi[((wid * 4 + ksA) * 64 + lane) * 8];
      short8 al = *(const short8*)&Alo[((wid * 4 + ksA) * 64 + lane) * 8];
      #pragma unroll
      for (int ct = 0; ct < 8; ct++) {
        short8 bh = *(const short8*)&Bhi[((ks2 * 8 + ct) * 64 + lane) * 8];
        short8 bl = *(const short8*)&Blo[((ks2 * 8 + ct) * 64 + lane) * 8];
        acc[ct] = __builtin_amdgcn_mfma_f32_16x16x32_bf16(ah, bh, acc[ct], 0, 0, 0);
        acc[ct] = __builtin_amdgcn_mfma_f32_16x16x32_bf16(ah, bl, acc[ct], 0, 0, 0);
        acc[ct] = __builtin_amdgcn_mfma_f32_16x16x32_bf16(al, bh, acc[ct], 0, 0, 0);
      }
    }
  }
}

// ---- N-half unit (4 col-tiles, ct0 = 0 or 4) ----
__device__ __forceinline__ void unit_mfma_h(f32x4 acc[4], const ushort_t* wf,
                                            int ct0,
                                            const ushort_t* Ahi, const ushort_t* Alo,
                                            ushort_t* Bhi, ushort_t* Blo,
                                            int tid, int lane, int wid) {
  #pragma unroll 1
  for (int half = 0; half < 2; half++) {
    __syncthreads();
    #pragma unroll
    for (int i = 0; i < 2; i++) {
      int sc = tid + i * 256;             // 0..511
      int ks2 = sc >> 8;
      int cts = (sc >> 6) & 3;
      int ln  = sc & 63;
      int c = half * 1024 + ks2 * 512 + (ct0 + cts) * 64 + ln;
      ((short8*)Bhi)[sc] = *(const short8*)&wf[(size_t)c * 8];
      ((short8*)Blo)[sc] = *(const short8*)&wf[16384 + (size_t)c * 8];
    }
    __syncthreads();
    #pragma unroll
    for (int ks2 = 0; ks2 < 2; ks2++) {
      int ksA = half * 2 + ks2;
      short8 ah = *(const short8*)&Ahi[((wid * 4 + ksA) * 64 + lane) * 8];
      short8 al = *(const short8*)&Alo[((wid * 4 + ksA) * 64 + lane) * 8];
      #pragma unroll
      for (int ct = 0; ct < 4; ct++) {
        short8 bh = *(const short8*)&Bhi[((ks2 * 4 + ct) * 64 + lane) * 8];
        short8 bl = *(const short8*)&Blo[((ks2 * 4 + ct) * 64 + lane) * 8];
        acc[ct] = __builtin_amdgcn_mfma_f32_16x16x32_bf16(ah, bh, acc[ct], 0, 0, 0);
        acc[ct] = __builtin_amdgcn_mfma_f32_16x16x32_bf16(ah, bl, acc[ct], 0, 0, 0);
        acc[ct] = __builtin_amdgcn_mfma_f32_16x16x32_bf16(al, bh, acc[ct], 0, 0, 0);
      }
    }
  }
}

// ---------------- g1 (N-split): out = [relu](A@W + bias), grid (256,2) -----
template<int RELU>
__global__ __launch_bounds__(256, 4) void g1_kernel(
    const float* __restrict__ A, const ushort_t* __restrict__ wf,
    const float* __restrict__ bias, float* __restrict__ out) {
  __shared__ ushort_t Ahi[8192], Alo[8192], Bhi[4096], Blo[4096];
  const int tid = threadIdx.x, lane = tid & 63, wid = tid >> 6;
  const int m0 = blockIdx.x * 64, ct0 = blockIdx.y * 4;
  stage_A_convert(Ahi, Alo, A, m0, tid);
  f32x4 acc[4];
  f32x4 z = {0.f, 0.f, 0.f, 0.f};
  #pragma unroll
  for (int ct = 0; ct < 4; ct++) acc[ct] = z;
  unit_mfma_h(acc, wf, ct0, Ahi, Alo, Bhi, Blo, tid, lane, wid);

  const int rbase = m0 + wid * 16 + ((lane >> 4) << 2);
  const int cb = lane & 15;
  #pragma unroll
  for (int ct = 0; ct < 4; ct++) {
    int n = (ct0 + ct) * 16 + cb;
    float bv = bias ? bias[n] : 0.f;
    #pragma unroll
    for (int r = 0; r < 4; r++) {
      float v = acc[ct][r] + bv;
      if (RELU) v = fmaxf(v, 0.f);
      out[(size_t)(rbase + r) * HID + n] = v;
    }
  }
}

// ---------------- msg pair (full-N, grid (256,2) y=top/bot) ------
__global__ __launch_bounds__(256, 4) void msg_kernel(
    const float* __restrict__ h, const ushort_t* __restrict__ wfT,
    const ushort_t* __restrict__ wfB, const float* __restrict__ mb,
    float* __restrict__ bufA, float* __restrict__ bufB) {
  __shared__ ushort_t Ahi[8192], Alo[8192], Bhi[8192], Blo[8192];
  const int tid = threadIdx.x, lane = tid & 63, wid = tid >> 6;
  const int m0 = blockIdx.x * 64;
  const int y = blockIdx.y;
  stage_A_convert(Ahi, Alo, h, m0, tid);
  f32x4 acc[8];
  f32x4 z = {0.f, 0.f, 0.f, 0.f};
  #pragma unroll
  for (int ct = 0; ct < 8; ct++) acc[ct] = z;
  unit_mfma(acc, y ? wfB : wfT, Ahi, Alo, Bhi, Blo, tid, lane, wid);

  float* out = y ? bufB : bufA;
  const float* bias = y ? mb : nullptr;
  const int rbase = m0 + wid * 16 + ((lane >> 4) << 2);
  const int cb = lane & 15;
  #pragma unroll
  for (int ct = 0; ct < 8; ct++) {
    int n = ct * 16 + cb;
    float bv = bias ? bias[n] : 0.f;
    #pragma unroll
    for (int r = 0; r < 4; r++)
      out[(size_t)(rbase + r) * HID + n] = acc[ct][r] + bv;
  }
}

// ---------------- upd (N-split): h' = h + relu(h@Wt + agg@Wb + ub) ---------
__global__ __launch_bounds__(256, 4) void upd_kernel(
    const float* __restrict__ h, const ushort_t* __restrict__ wuT,
    const float* __restrict__ aggF, const ushort_t* __restrict__ wuB,
    const float* __restrict__ ub, float* __restrict__ out) {
  __shared__ ushort_t Ahi[8192], Alo[8192], Bhi[4096], Blo[4096];
  const int tid = threadIdx.x, lane = tid & 63, wid = tid >> 6;
  const int m0 = blockIdx.x * 64, ct0 = blockIdx.y * 4;
  stage_A_convert(Ahi, Alo, h, m0, tid);
  f32x4 acc[4];
  f32x4 z = {0.f, 0.f, 0.f, 0.f};
  #pragma unroll
  for (int ct = 0; ct < 4; ct++) acc[ct] = z;
  unit_mfma_h(acc, wuT, ct0, Ahi, Alo, Bhi, Blo, tid, lane, wid);
  __syncthreads();                         // phase-1 A reads done
  stage_A_convert(Ahi, Alo, aggF, m0, tid);
  unit_mfma_h(acc, wuB, ct0, Ahi, Alo, Bhi, Blo, tid, lane, wid);

  const int rbase = m0 + wid * 16 + ((lane >> 4) << 2);
  const int cb = lane & 15;
  #pragma unroll
  for (int ct = 0; ct < 4; ct++) {
    int n = (ct0 + ct) * 16 + cb;
    float bv = ub[n];
    #pragma unroll
    for (int r = 0; r < 4; r++) {
      float v = fmaxf(acc[ct][r] + bv, 0.f)
              + h[(size_t)(rbase + r) * HID + n];
      out[(size_t)(rbase + r) * HID + n] = v;
    }
  }
}

// ---------------- proj1 (full-N, grid (256,2) y=col-block) -------
__global__ __launch_bounds__(256, 4) void proj1_kernel(
    const float* __restrict__ A, const ushort_t* __restrict__ wf01,
    const float* __restrict__ pb1, float* __restrict__ zout) {
  __shared__ ushort_t Ahi[8192], Alo[8192], Bhi[8192], Blo[8192];
  const int tid = threadIdx.x, lane = tid & 63, wid = tid >> 6;
  const int m0 = blockIdx.x * 64;
  const int y = blockIdx.y;
  stage_A_convert(Ahi, Alo, A, m0, tid);
  f32x4 acc[8];
  f32x4 z = {0.f, 0.f, 0.f, 0.f};
  #pragma unroll
  for (int ct = 0; ct < 8; ct++) acc[ct] = z;
  unit_mfma(acc, wf01 + (size_t)y * 32768, Ahi, Alo, Bhi, Blo, tid, lane, wid);

  const int rbase = m0 + wid * 16 + ((lane >> 4) << 2);
  const int cb = lane & 15;
  #pragma unroll
  for (int ct = 0; ct < 8; ct++) {
    int n = y * 128 + ct * 16 + cb;
    float bv = pb1[n];
    #pragma unroll
    for (int r = 0; r < 4; r++)
      zout[(size_t)(rbase + r) * PROJ_D + n] = acc[ct][r] + bv;
  }
}

// ---------------- fused message + mean-aggregation (2 nodes/block) --------
__global__ __launch_bounds__(256) void agg_kernel(const float* __restrict__ Abuf,
                                                  const float* __restrict__ Bbuf,
                                                  const int* __restrict__ row_ptr,
                                                  const int* __restrict__ col,
                                                  float* __restrict__ agg) {
  int j = blockIdx.x * 2 + (threadIdx.x >> 7);
  int c = threadIdx.x & 127;
  float bj = Bbuf[(size_t)j * HID + c];
  int s = row_ptr[j], e = row_ptr[j + 1];
  float acc = 0.f;
  int p = s;
  for (; p + 4 <= e; p += 4) {
    int i0 = col[p], i1 = col[p+1], i2 = col[p+2], i3 = col[p+3];
    float v0 = Abuf[(size_t)i0 * HID + c];
    float v1 = Abuf[(size_t)i1 * HID + c];
    float v2 = Abuf[(size_t)i2 * HID + c];
    float v3 = Abuf[(size_t)i3 * HID + c];
    acc += fmaxf(v0 + bj, 0.f) + fmaxf(v1 + bj, 0.f)
         + fmaxf(v2 + bj, 0.f) + fmaxf(v3 + bj, 0.f);
  }
  for (; p < e; p++) {
    int i = col[p];
    acc += fmaxf(Abuf[(size_t)i * HID + c] + bj, 0.f);
  }
  float deg = (float)(e - s);
  float inv = 1.0f / fmaxf(deg, 1.0f);
  agg[(size_t)j * HID + c] = acc * inv;
}

extern "C" void kernel_launch(void* const* d_in, const int* in_sizes, int n_in,
                              void* d_out, int out_size, void* d_ws, size_t ws_size,
                              hipStream_t stream) {
  (void)in_sizes; (void)n_in; (void)out_size; (void)ws_size;
  const float* x       = (const float*)d_in[0];
  const float* pos     = (const float*)d_in[1];
  const float* enc_w0  = (const float*)d_in[3];
  const float* enc_b0  = (const float*)d_in[4];
  const float* enc_w1  = (const float*)d_in[5];
  const float* enc_b1  = (const float*)d_in[6];
  const float* msg_w   = (const float*)d_in[7];
  const float* msg_b   = (const float*)d_in[8];
  const float* upd_w   = (const float*)d_in[9];
  const float* upd_b   = (const float*)d_in[10];
  const float* proj_w0 = (const float*)d_in[11];
  const float* proj_b0 = (const float*)d_in[12];
  const float* proj_w1 = (const float*)d_in[13];
  const float* proj_b1 = (const float*)d_in[14];

  char* ws = (char*)d_ws;
  size_t off = 0;
  auto alloc = [&](size_t bytes) -> void* {
    void* p = ws + off;
    off += (bytes + 255) & ~(size_t)255;
    return p;
  };
  int*      nbr     = (int*)alloc((size_t)EE * 4);
  int*      cnt     = (int*)alloc((size_t)BN * 4);
  int*      fill    = (int*)alloc((size_t)BN * 4);
  int*      row_ptr = (int*)alloc((size_t)(BN + 1) * 4);
  int*      col     = (int*)alloc((size_t)EE * 4);
  float*    h_a     = (float*)alloc((size_t)BN * HID * 4);
  float*    h_b     = (float*)alloc((size_t)BN * HID * 4);
  float*    bufA    = (float*)alloc((size_t)BN * HID * 4);
  float*    bufB    = (float*)alloc((size_t)BN * HID * 4);
  float*    bufAgg  = (float*)alloc((size_t)BN * HID * 4);
  ushort_t* wfrag   = (ushort_t*)alloc((size_t)16 * 32768 * 2);
  float4*   spos    = (float4*)alloc((size_t)BN * 16);
  int*      cptr    = (int*)alloc((size_t)BB * (NCELL + 1) * 4);
  float*    out     = (float*)d_out;
  float*    hOut    = out + (size_t)BN * PROJ_D;

  // zero cnt+fill (contiguous 256 KB) with a parallel kernel, not memset
  zero_kernel<<<32, 256, 0, stream>>>((int4*)cnt);

  cellsort_kernel<<<BB, 256, 0, stream>>>(pos, spos, cptr);
  prep_w_kernel<<<128, 256, 0, stream>>>(enc_w1, msg_w, upd_w, proj_w0, proj_w1, wfrag);
  knn_kernel<<<BN / QPB, 1024, 0, stream>>>(spos, cptr, nbr, cnt);
  scan_kernel<<<1, 256, 0, stream>>>(cnt, row_ptr);
  fill_kernel<<<EE / 256, 256, 0, stream>>>(nbr, row_ptr, fill, col);

  enc0_kernel<<<BN * 32 / 256, 256, 0, stream>>>(x, enc_w0, enc_b0, bufA);
  g1_kernel<1><<<dim3(BN / 64, 2), 256, 0, stream>>>(bufA, wfrag + 0 * 32768,
                                                     enc_b1, h_a);

  float* hc = h_a;
  float* hn = h_b;
  for (int i = 0; i < 3; i++) {
    msg_kernel<<<dim3(BN / 64, 2), 256, 0, stream>>>(
        hc, wfrag + (size_t)(1 + 2 * i) * 32768,
        wfrag + (size_t)(2 + 2 * i) * 32768, msg_b + (size_t)i * HID,
        bufA, bufB);
    agg_kernel<<<BN / 2, 256, 0, stream>>>(bufA, bufB, row_ptr, col, bufAgg);
    float* target = (i == 2) ? hOut : hn;
    upd_kernel<<<dim3(BN / 64, 2), 256, 0, stream>>>(
        hc, wfrag + (size_t)(7 + 2 * i) * 32768, bufAgg,
        wfrag + (size_t)(8 + 2 * i) * 32768, upd_b + (size_t)i * HID, target);
    hn = hc; hc = target;
  }

  g1_kernel<1><<<dim3(BN / 64, 2), 256, 0, stream>>>(hc, wfrag + 13 * 32768,
                                                     proj_b0, bufA);
  proj1_kernel<<<dim3(BN / 64, 2), 256, 0, stream>>>(
      bufA, wfrag + 14 * 32768, proj_b1, out);
}

// Round 17
// 214.065 us; speedup vs baseline: 1.2892x; 1.0679x over previous
//
#include <hip/hip_runtime.h>
#include <stdint.h>
#include <math.h>

#define NN 2048
#define BB 8
#define BN (BB*NN)
#define KK 16
#define EE (BN*KK)
#define HID 128
#define PROJ_D 256
#define QPB 16    // queries (waves) per knn block
#define CDIM 6
#define NCELL (CDIM*CDIM*CDIM)
#define CAP 768   // per-wave candidate list capacity

typedef unsigned long long u64;
typedef unsigned short ushort_t;
typedef __attribute__((ext_vector_type(8))) short short8;
typedef __attribute__((ext_vector_type(4))) float f32x4;

__device__ __forceinline__ u64 wave_min_u64(u64 v) {
  #pragma unroll
  for (int off = 32; off > 0; off >>= 1) {
    u64 o = __shfl_xor(v, off);
    v = o < v ? o : v;
  }
  return v;
}

// ---------------- per-batch counting sort by 6^3 cell (+ zero cnt/fill) ----
__global__ __launch_bounds__(256) void cellsort_kernel(
    const float* __restrict__ pos, float4* __restrict__ spos,
    int* __restrict__ cptr, int4* __restrict__ cntz) {
  __shared__ int hist[NCELL];
  __shared__ int base[NCELL];
  const int b = blockIdx.x, tid = threadIdx.x;
  // r17: zero cnt+fill (8192 int4 over 8x256 threads) here; knn runs later
  #pragma unroll
  for (int k = 0; k < 4; k++)
    cntz[(b * 256 + tid) + k * 2048] = make_int4(0, 0, 0, 0);
  if (tid < NCELL) hist[tid] = 0;
  __syncthreads();
  int cellv[8];
  float4 pv[8];
  #pragma unroll
  for (int k = 0; k < 8; k++) {
    int j = tid * 8 + k;
    const float* pp = pos + ((size_t)b * NN + j) * 3;
    float x = pp[0], y = pp[1], z = pp[2];
    int cx = (int)(x * 6.0f); cx = cx > 5 ? 5 : cx;
    int cy = (int)(y * 6.0f); cy = cy > 5 ? 5 : cy;
    int cz = (int)(z * 6.0f); cz = cz > 5 ? 5 : cz;
    int cell = (cx * 6 + cy) * 6 + cz;
    cellv[k] = cell;
    pv[k] = make_float4(x, y, z, __int_as_float(j));
    atomicAdd(&hist[cell], 1);
  }
  __syncthreads();
  if (tid == 0) {
    int run = 0;
    for (int c = 0; c < NCELL; c++) {
      cptr[b * (NCELL + 1) + c] = run;
      base[c] = run;
      run += hist[c];
    }
    cptr[b * (NCELL + 1) + NCELL] = run;   // = NN
  }
  __syncthreads();
  if (tid < NCELL) hist[tid] = 0;          // reuse as fill counters
  __syncthreads();
  #pragma unroll
  for (int k = 0; k < 8; k++) {
    int slot = base[cellv[k]] + atomicAdd(&hist[cellv[k]], 1);
    spos[(size_t)b * NN + slot] = pv[k];
  }
}

// ---------------- kNN via exact cell-pruned histogram selection ----------
__global__ __launch_bounds__(1024) void knn_kernel(
    const float4* __restrict__ spos, const int* __restrict__ cptr,
    int* __restrict__ nbr, int* __restrict__ cnt) {
  __shared__ float4 Ps[NN];             // 32 KB (sorted; .w = orig idx bits)
  __shared__ unsigned Hist[QPB * 256];  // 16 KB
  __shared__ ushort_t Cand[QPB * CAP];  // 24 KB
  __shared__ int Cp[NCELL + 1];
  const int b  = blockIdx.x >> 7;
  const int qb = blockIdx.x & 127;
  const int wave = threadIdx.x >> 6;
  const int lane = threadIdx.x & 63;
  const int s_q = qb * QPB + wave;      // sorted query slot

  for (int t = threadIdx.x; t < NN; t += 1024)
    Ps[t] = spos[(size_t)b * NN + t];
  if (threadIdx.x <= NCELL)
    Cp[threadIdx.x] = cptr[b * (NCELL + 1) + threadIdx.x];
  __syncthreads();

  const float4 q = Ps[s_q];
  const float xi = q.x, yi = q.y, zi = q.z;
  const int orig_i = __float_as_int(q.w);
  unsigned* H = &Hist[wave * 256];
  ushort_t* CL = &Cand[wave * CAP];

  int cx = (int)(xi * 6.0f); cx = cx > 5 ? 5 : cx;
  int cy = (int)(yi * 6.0f); cy = cy > 5 ? 5 : cy;
  int cz = (int)(zi * 6.0f); cz = cz > 5 ? 5 : cz;

  int T = 0;
  bool ovf = false;
  #pragma unroll 1
  for (int dxy = 0; dxy < 9; dxy++) {
    int dx = dxy / 3 - 1, dy = dxy - (dxy / 3) * 3 - 1;
    int ncx = cx + dx; ncx += (ncx < 0) ? 6 : 0; ncx -= (ncx >= 6) ? 6 : 0;
    int ncy = cy + dy; ncy += (ncy < 0) ? 6 : 0; ncy -= (ncy >= 6) ? 6 : 0;
    int cbse = (ncx * 6 + ncy) * 6;
    int s0, l0, s1 = 0, l1 = 0;
    if (cz == 0) {
      s0 = Cp[cbse + 5]; l0 = Cp[cbse + 6] - s0;
      s1 = Cp[cbse];     l1 = Cp[cbse + 2] - s1;
    } else if (cz == 5) {
      s0 = Cp[cbse + 4]; l0 = Cp[cbse + 6] - s0;
      s1 = Cp[cbse];     l1 = Cp[cbse + 1] - s1;
    } else {
      s0 = Cp[cbse + cz - 1]; l0 = Cp[cbse + cz + 2] - s0;
    }
    if (T + l0 + l1 > CAP) { ovf = true; break; }
    for (int t = lane; t < l0; t += 64) CL[T + t] = (ushort_t)(s0 + t);
    T += l0;
    for (int t = lane; t < l1; t += 64) CL[T + t] = (ushort_t)(s1 + t);
    T += l1;
  }

  int mode = ovf ? 1 : 0;
  float scale = 1536.0f;
  int T2 = T, binmax = 254;
  int bstar = 0; unsigned C = 0;
  for (;;) {
    scale = mode ? 256.0f : 1536.0f;
    T2 = mode ? NN : T;
    binmax = mode ? 256 : 254;
    *(uint4*)&H[lane * 4] = make_uint4(0u, 0u, 0u, 0u);
    for (int t = lane; t < T2; t += 64) {
      int p = mode ? t : (int)CL[t];
      float4 pj = Ps[p];
      float tx = xi - pj.x, ty = yi - pj.y, tz = zi - pj.z;
      float ddx = __fsub_rn(tx, rintf(tx));
      float ddy = __fsub_rn(ty, rintf(ty));
      float ddz = __fsub_rn(tz, rintf(tz));
      float s = __fadd_rn(__fadd_rn(__fadd_rn(__fmul_rn(ddx,ddx), __fmul_rn(ddy,ddy)),
                                    __fmul_rn(ddz,ddz)), 1e-12f);
      float d = __fsqrt_rn(s);
      int bin = (int)(d * scale);
      if (bin < binmax) atomicAdd(&H[bin], 1u);
    }
    uint4 cv = *(const uint4*)&H[lane * 4];
    unsigned s4 = cv.x + cv.y + cv.z + cv.w;
    unsigned incl = s4;
    #pragma unroll
    for (int off = 1; off < 64; off <<= 1) {
      unsigned v = __shfl_up(incl, off);
      if (lane >= off) incl += v;
    }
    unsigned total = __shfl(incl, 63);
    if (total >= 17u) {
      unsigned base = incl - s4;
      bool has = (incl >= 17u) && (base < 17u);
      u64 hmask = __ballot(has);
      int srcl = __ffsll((unsigned long long)hmask) - 1;
      int bl = 0; unsigned Cl = 0;
      if (has) {
        if (base + cv.x >= 17u)                    { bl = lane*4 + 0; Cl = base; }
        else if (base + cv.x + cv.y >= 17u)        { bl = lane*4 + 1; Cl = base + cv.x; }
        else if (base + cv.x + cv.y + cv.z >= 17u) { bl = lane*4 + 2; Cl = base + cv.x + cv.y; }
        else                                       { bl = lane*4 + 3; Cl = base + cv.x + cv.y + cv.z; }
      }
      bstar = __shfl(bl, srcl);
      C     = __shfl(Cl, srcl);
      break;
    }
    mode = 1;   // fallback: full scan (exact)
  }
  const int m = 17 - (int)C;

  u64 lst[6];
  #pragma unroll
  for (int t = 0; t < 6; t++) lst[t] = ~0ull;
  for (int t = lane; t < T2; t += 64) {
    int p = mode ? t : (int)CL[t];
    float4 pj = Ps[p];
    float tx = xi - pj.x, ty = yi - pj.y, tz = zi - pj.z;
    float ddx = __fsub_rn(tx, rintf(tx));
    float ddy = __fsub_rn(ty, rintf(ty));
    float ddz = __fsub_rn(tz, rintf(tz));
    float s = __fadd_rn(__fadd_rn(__fadd_rn(__fmul_rn(ddx,ddx), __fmul_rn(ddy,ddy)),
                                  __fmul_rn(ddz,ddz)), 1e-12f);
    float d = __fsqrt_rn(s);
    int bin = (int)(d * scale);
    if (bin == bstar) {
      u64 key = ((u64)__float_as_uint(d) << 11) | (unsigned)__float_as_int(pj.w);
      if (key < lst[5]) {
        lst[5] = key;
        #pragma unroll
        for (int u = 5; u > 0; u--) {
          u64 a = lst[u-1], c2 = lst[u];
          lst[u-1] = a < c2 ? a : c2;
          lst[u]   = a < c2 ? c2 : a;
        }
      }
    }
  }

  u64 kstar = 0;
  #pragma unroll 1
  for (int r = 0; r < m; r++) {
    u64 h0 = lst[0];
    u64 gm = wave_min_u64(h0);
    kstar = gm;
    bool win = (h0 == gm);
    #pragma unroll
    for (int u = 0; u < 5; u++) lst[u] = win ? lst[u+1] : lst[u];
    lst[5] = win ? ~0ull : lst[5];
  }

  int* outp = nbr + ((size_t)b * NN + orig_i) * KK;
  int total_e = 0;
  for (int t0 = 0; t0 < T2; t0 += 64) {
    int t = t0 + lane;
    bool pred = false;
    int oj = 0;
    if (t < T2) {
      int p = mode ? t : (int)CL[t];
      float4 pj = Ps[p];
      float tx = xi - pj.x, ty = yi - pj.y, tz = zi - pj.z;
      float ddx = __fsub_rn(tx, rintf(tx));
      float ddy = __fsub_rn(ty, rintf(ty));
      float ddz = __fsub_rn(tz, rintf(tz));
      float s = __fadd_rn(__fadd_rn(__fadd_rn(__fmul_rn(ddx,ddx), __fmul_rn(ddy,ddy)),
                                    __fmul_rn(ddz,ddz)), 1e-12f);
      float d = __fsqrt_rn(s);
      oj = __float_as_int(pj.w);
      u64 key = ((u64)__float_as_uint(d) << 11) | (unsigned)oj;
      pred = (key <= kstar) && (oj != orig_i);
    }
    u64 msk = __ballot(pred);
    if (pred) {
      int ofs = total_e + __popcll(msk & ((1ull << lane) - 1ull));
      outp[ofs] = b * NN + oj;
      atomicAdd(&cnt[b * NN + oj], 1);
    }
    total_e += __popcll(msk);
  }
}

// ---------------- CSR build ----------------
__global__ __launch_bounds__(256) void scan_kernel(const int* __restrict__ cnt,
                                                   int* __restrict__ row_ptr) {
  __shared__ int ps[256];
  int t = threadIdx.x;
  const int4* cv = (const int4*)(cnt + t * 64);
  int4 c[16];
  int s = 0;
  #pragma unroll
  for (int i = 0; i < 16; i++) {
    c[i] = cv[i];
    s += c[i].x + c[i].y + c[i].z + c[i].w;
  }
  ps[t] = s;
  __syncthreads();
  for (int off = 1; off < 256; off <<= 1) {
    int v = 0;
    if (t >= off) v = ps[t - off];
    __syncthreads();
    ps[t] += v;
    __syncthreads();
  }
  int run = t ? ps[t - 1] : 0;
  int4* rp = (int4*)(row_ptr + t * 64);
  #pragma unroll
  for (int i = 0; i < 16; i++) {
    int4 o;
    o.x = run; run += c[i].x;
    o.y = run; run += c[i].y;
    o.z = run; run += c[i].z;
    o.w = run; run += c[i].w;
    rp[i] = o;
  }
  if (t == 255) row_ptr[BN] = run;
}

__global__ __launch_bounds__(256) void fill_kernel(const int* __restrict__ nbr,
                                                   const int* __restrict__ row_ptr,
                                                   int* __restrict__ fill,
                                                   int* __restrict__ col) {
  int e = blockIdx.x * 256 + threadIdx.x;
  int d = nbr[e];
  int srcn = e >> 4;
  int p = row_ptr[d] + atomicAdd(&fill[d], 1);
  col[p] = srcn;
}

// ================= split-bf16 MFMA machinery (r9-r16, verified) =========
__device__ __forceinline__ ushort_t bf16_rne(float x) {
  unsigned u = __float_as_uint(x);
  unsigned r = u + 0x7FFFu + ((u >> 16) & 1u);
  return (ushort_t)(r >> 16);
}
__device__ __forceinline__ float bf16_to_f(ushort_t h) {
  return __uint_as_float(((unsigned)h) << 16);
}
__device__ __forceinline__ unsigned cvtpk_bf16(float a, float b) {
  unsigned r;
  asm("v_cvt_pk_bf16_f32 %0, %1, %2" : "=v"(r) : "v"(a), "v"(b));
  return r;
}

__device__ __forceinline__ void cvt8(const float4 f0, const float4 f1,
                                     short8& hi, short8& lo) {
  unsigned h0 = cvtpk_bf16(f0.x, f0.y);
  unsigned h1 = cvtpk_bf16(f0.z, f0.w);
  unsigned h2 = cvtpk_bf16(f1.x, f1.y);
  unsigned h3 = cvtpk_bf16(f1.z, f1.w);
  unsigned l0 = cvtpk_bf16(f0.x - __uint_as_float(h0 << 16),
                           f0.y - __uint_as_float(h0 & 0xffff0000u));
  unsigned l1 = cvtpk_bf16(f0.z - __uint_as_float(h1 << 16),
                           f0.w - __uint_as_float(h1 & 0xffff0000u));
  unsigned l2 = cvtpk_bf16(f1.x - __uint_as_float(h2 << 16),
                           f1.y - __uint_as_float(h2 & 0xffff0000u));
  unsigned l3 = cvtpk_bf16(f1.z - __uint_as_float(h3 << 16),
                           f1.w - __uint_as_float(h3 & 0xffff0000u));
  union { unsigned u[4]; short8 v; } H, L;
  H.u[0] = h0; H.u[1] = h1; H.u[2] = h2; H.u[3] = h3;
  L.u[0] = l0; L.u[1] = l1; L.u[2] = l2; L.u[3] = l3;
  hi = H.v;
  lo = L.v;
}

// prep: 16 unit-Ws (128x128) -> fragment-ordered bf16 hi/lo
__global__ __launch_bounds__(256) void prep_w_kernel(
    const float* __restrict__ enc_w1, const float* __restrict__ msg_w,
    const float* __restrict__ upd_w, const float* __restrict__ proj_w0,
    const float* __restrict__ proj_w1, ushort_t* __restrict__ wfrag) {
  int u = blockIdx.x >> 3;
  int c = (blockIdx.x & 7) * 256 + threadIdx.x;
  const float* src;
  int ldW = HID;
  if (u == 0) src = enc_w1;
  else if (u <= 6)  { int i = (u-1)>>1; int hf = (u-1)&1; src = msg_w + ((size_t)i*256 + hf*128) * HID; }
  else if (u <= 12) { int i = (u-7)>>1; int hf = (u-7)&1; src = upd_w + ((size_t)i*256 + hf*128) * HID; }
  else if (u == 13) src = proj_w0;
  else { src = proj_w1 + (u - 14) * 128; ldW = PROJ_D; }

  int ks = c >> 9, ct = (c >> 6) & 7, lane = c & 63;
  int colc = ct * 16 + (lane & 15);
  int k0 = ks * 32 + ((lane >> 4) << 3);
  float f[8];
  #pragma unroll
  for (int e = 0; e < 8; e++) f[e] = src[(size_t)(k0 + e) * ldW + colc];
  short8 hv, lv;
  cvt8(make_float4(f[0],f[1],f[2],f[3]), make_float4(f[4],f[5],f[6],f[7]), hv, lv);
  *(short8*)&wfrag[(size_t)u * 32768 + (size_t)c * 8] = hv;
  *(short8*)&wfrag[(size_t)u * 32768 + 16384 + (size_t)c * 8] = lv;
}

// convert 64x128 f32 global rows -> fragment hi/lo in LDS (consumer-side)
__device__ __forceinline__ void stage_A_convert(ushort_t* Ahi, ushort_t* Alo,
                                                const float* A, int m0, int tid) {
  #pragma unroll
  for (int i = 0; i < 4; i++) {
    int c = tid + i * 256;
    int row = c >> 4, kg = c & 15;
    const float4* ap = (const float4*)(A + (((size_t)m0 + row) << 7) + (kg << 3));
    short8 hv, lv;
    cvt8(ap[0], ap[1], hv, lv);
    int idx = (((row >> 4) * 4 + (kg >> 2)) * 64 + ((row & 15) | ((kg & 3) << 4))) * 8;
    *(short8*)&Ahi[idx] = hv;
    *(short8*)&Alo[idx] = lv;
  }
}

// ---- full-N unit (8 col-tiles) ----
__device__ __forceinline__ void unit_mfma(f32x4 acc[8], const ushort_t* wf,
                                          const ushort_t* Ahi, const ushort_t* Alo,
                                          ushort_t* Bhi, ushort_t* Blo,
                                          int tid, int lane, int wid) {
  #pragma unroll 1
  for (int half = 0; half < 2; half++) {
    __syncthreads();
    const short8* ghi = (const short8*)(wf + half * 8192);
    const short8* glo = (const short8*)(wf + 16384 + half * 8192);
    #pragma unroll
    for (int i = 0; i < 4; i++) {
      ((short8*)Bhi)[tid + i * 256] = ghi[tid + i * 256];
      ((short8*)Blo)[tid + i * 256] = glo[tid + i * 256];
    }
    __syncthreads();
    #pragma unroll
    for (int ks2 = 0; ks2 < 2; ks2++) {
      int ksA = half * 2 + ks2;
      short8 ah = *(const short8*)&Ahi[((wid * 4 + ksA) * 64 + lane) * 8];
      short8 al = *(const short8*)&Alo[((wid * 4 + ksA) * 64 + lane) * 8];
      #pragma unroll
      for (int ct = 0; ct < 8; ct++) {
        short8 bh = *(const short8*)&Bhi[((ks2 * 8 + ct) * 64 + lane) * 8];
        short8 bl = *(const short8*)&Blo[((ks2 * 8 + ct) * 64 + lane) * 8];
        acc[ct] = __builtin_amdgcn_mfma_f32_16x16x32_bf16(ah, bh, acc[ct], 0, 0, 0);
        acc[ct] = __builtin_amdgcn_mfma_f32_16x16x32_bf16(ah, bl, acc[ct], 0, 0, 0);
        acc[ct] = __builtin_amdgcn_mfma_f32_16x16x32_bf16(al, bh, acc[ct], 0, 0, 0);
      }
    }
  }
}

// ---- N-half unit (4 col-tiles, ct0 = 0 or 4) ----
__device__ __forceinline__ void unit_mfma_h(f32x4 acc[4], const ushort_t* wf,
                                            int ct0,
                                            const ushort_t* Ahi, const ushort_t* Alo,
                                            ushort_t* Bhi, ushort_t* Blo,
                                            int tid, int lane, int wid) {
  #pragma unroll 1
  for (int half = 0; half < 2; half++) {
    __syncthreads();
    #pragma unroll
    for (int i = 0; i < 2; i++) {
      int sc = tid + i * 256;             // 0..511
      int ks2 = sc >> 8;
      int cts = (sc >> 6) & 3;
      int ln  = sc & 63;
      int c = half * 1024 + ks2 * 512 + (ct0 + cts) * 64 + ln;
      ((short8*)Bhi)[sc] = *(const short8*)&wf[(size_t)c * 8];
      ((short8*)Blo)[sc] = *(const short8*)&wf[16384 + (size_t)c * 8];
    }
    __syncthreads();
    #pragma unroll
    for (int ks2 = 0; ks2 < 2; ks2++) {
      int ksA = half * 2 + ks2;
      short8 ah = *(const short8*)&Ahi[((wid * 4 + ksA) * 64 + lane) * 8];
      short8 al = *(const short8*)&Alo[((wid * 4 + ksA) * 64 + lane) * 8];
      #pragma unroll
      for (int ct = 0; ct < 4; ct++) {
        short8 bh = *(const short8*)&Bhi[((ks2 * 4 + ct) * 64 + lane) * 8];
        short8 bl = *(const short8*)&Blo[((ks2 * 4 + ct) * 64 + lane) * 8];
        acc[ct] = __builtin_amdgcn_mfma_f32_16x16x32_bf16(ah, bh, acc[ct], 0, 0, 0);
        acc[ct] = __builtin_amdgcn_mfma_f32_16x16x32_bf16(ah, bl, acc[ct], 0, 0, 0);
        acc[ct] = __builtin_amdgcn_mfma_f32_16x16x32_bf16(al, bh, acc[ct], 0, 0, 0);
      }
    }
  }
}

// ---------------- encg1: enc0 fused + enc1 N-split, grid (256,2) -----------
__global__ __launch_bounds__(256, 4) void encg1_kernel(
    const float* __restrict__ x, const float* __restrict__ ew0,
    const float* __restrict__ eb0, const ushort_t* __restrict__ wf,
    const float* __restrict__ eb1, float* __restrict__ hOut) {
  __shared__ ushort_t Ahi[8192], Alo[8192], Bhi[4096], Blo[4096];
  __shared__ float XW[1088];   // x[320] | w0[640] @320 | b0[128] @960
  const int tid = threadIdx.x, lane = tid & 63, wid = tid >> 6;
  const int m0 = blockIdx.x * 64, ct0 = blockIdx.y * 4;

  if (tid < 80) ((float4*)XW)[tid] = ((const float4*)(x + (size_t)m0 * 5))[tid];
  else if (tid < 240) ((float4*)XW)[tid] = ((const float4*)ew0)[tid - 80];
  else {
    int k = tid - 240;
    ((float4*)XW)[240 + k] = ((const float4*)eb0)[k];
    ((float4*)XW)[256 + k] = ((const float4*)eb0)[16 + k];
  }
  __syncthreads();

  // enc0 (5->128, relu) computed straight into fragment chunks
  #pragma unroll
  for (int i = 0; i < 4; i++) {
    int c = tid + i * 256;
    int row = c >> 4, kg = c & 15;
    float xr[5];
    #pragma unroll
    for (int d = 0; d < 5; d++) xr[d] = XW[row * 5 + d];
    float v[8];
    #pragma unroll
    for (int e = 0; e < 8; e++) {
      int col = kg * 8 + e;
      float a = XW[960 + col];
      #pragma unroll
      for (int d = 0; d < 5; d++) a += xr[d] * XW[320 + d * 128 + col];
      v[e] = fmaxf(a, 0.f);
    }
    short8 hv, lv;
    cvt8(make_float4(v[0],v[1],v[2],v[3]), make_float4(v[4],v[5],v[6],v[7]), hv, lv);
    int idx = (((row >> 4) * 4 + (kg >> 2)) * 64 + ((row & 15) | ((kg & 3) << 4))) * 8;
    *(short8*)&Ahi[idx] = hv;
    *(short8*)&Alo[idx] = lv;
  }

  f32x4 acc[4];
  f32x4 z = {0.f, 0.f, 0.f, 0.f};
  #pragma unroll
  for (int ct = 0; ct < 4; ct++) acc[ct] = z;
  unit_mfma_h(acc, wf, ct0, Ahi, Alo, Bhi, Blo, tid, lane, wid);

  const int rbase = m0 + wid * 16 + ((lane >> 4) << 2);
  const int cb = lane & 15;
  #pragma unroll
  for (int ct = 0; ct < 4; ct++) {
    int n = (ct0 + ct) * 16 + cb;
    float bv = eb1[n];
    #pragma unroll
    for (int r = 0; r < 4; r++)
      hOut[(size_t)(rbase + r) * HID + n] = fmaxf(acc[ct][r] + bv, 0.f);
  }
}

// ---------------- g1 (N-split): out = [relu](A@W + bias), grid (256,2) -----
template<int RELU>
__global__ __launch_bounds__(256, 4) void g1_kernel(
    const float* __restrict__ A, const ushort_t* __restrict__ wf,
    const float* __restrict__ bias, float* __restrict__ out) {
  __shared__ ushort_t Ahi[8192], Alo[8192], Bhi[4096], Blo[4096];
  const int tid = threadIdx.x, lane = tid & 63, wid = tid >> 6;
  const int m0 = blockIdx.x * 64, ct0 = blockIdx.y * 4;
  stage_A_convert(Ahi, Alo, A, m0, tid);
  f32x4 acc[4];
  f32x4 z = {0.f, 0.f, 0.f, 0.f};
  #pragma unroll
  for (int ct = 0; ct < 4; ct++) acc[ct] = z;
  unit_mfma_h(acc, wf, ct0, Ahi, Alo, Bhi, Blo, tid, lane, wid);

  const int rbase = m0 + wid * 16 + ((lane >> 4) << 2);
  const int cb = lane & 15;
  #pragma unroll
  for (int ct = 0; ct < 4; ct++) {
    int n = (ct0 + ct) * 16 + cb;
    float bv = bias ? bias[n] : 0.f;
    #pragma unroll
    for (int r = 0; r < 4; r++) {
      float v = acc[ct][r] + bv;
      if (RELU) v = fmaxf(v, 0.f);
      out[(size_t)(rbase + r) * HID + n] = v;
    }
  }
}

// ---------------- msg pair (full-N, grid (256,2) y=top/bot), bf16 out ------
__global__ __launch_bounds__(256, 4) void msg_kernel(
    const float* __restrict__ h, const ushort_t* __restrict__ wfT,
    const ushort_t* __restrict__ wfB, const float* __restrict__ mb,
    ushort_t* __restrict__ bufA, ushort_t* __restrict__ bufB) {
  __shared__ ushort_t Ahi[8192], Alo[8192], Bhi[8192], Blo[8192];
  const int tid = threadIdx.x, lane = tid & 63, wid = tid >> 6;
  const int m0 = blockIdx.x * 64;
  const int y = blockIdx.y;
  stage_A_convert(Ahi, Alo, h, m0, tid);
  f32x4 acc[8];
  f32x4 z = {0.f, 0.f, 0.f, 0.f};
  #pragma unroll
  for (int ct = 0; ct < 8; ct++) acc[ct] = z;
  unit_mfma(acc, y ? wfB : wfT, Ahi, Alo, Bhi, Blo, tid, lane, wid);

  ushort_t* out = y ? bufB : bufA;
  const float* bias = y ? mb : nullptr;
  const int rbase = m0 + wid * 16 + ((lane >> 4) << 2);
  const int cb = lane & 15;
  #pragma unroll
  for (int ct = 0; ct < 8; ct++) {
    int n = ct * 16 + cb;
    float bv = bias ? bias[n] : 0.f;
    #pragma unroll
    for (int r = 0; r < 4; r++)
      out[(size_t)(rbase + r) * HID + n] = bf16_rne(acc[ct][r] + bv);
  }
}

// ---------------- upd (N-split): h' = h + relu(h@Wt + agg@Wb + ub) ---------
__global__ __launch_bounds__(256, 4) void upd_kernel(
    const float* __restrict__ h, const ushort_t* __restrict__ wuT,
    const float* __restrict__ aggF, const ushort_t* __restrict__ wuB,
    const float* __restrict__ ub, float* __restrict__ out) {
  __shared__ ushort_t Ahi[8192], Alo[8192], Bhi[4096], Blo[4096];
  const int tid = threadIdx.x, lane = tid & 63, wid = tid >> 6;
  const int m0 = blockIdx.x * 64, ct0 = blockIdx.y * 4;
  stage_A_convert(Ahi, Alo, h, m0, tid);
  f32x4 acc[4];
  f32x4 z = {0.f, 0.f, 0.f, 0.f};
  #pragma unroll
  for (int ct = 0; ct < 4; ct++) acc[ct] = z;
  unit_mfma_h(acc, wuT, ct0, Ahi, Alo, Bhi, Blo, tid, lane, wid);
  __syncthreads();                         // phase-1 A reads done
  stage_A_convert(Ahi, Alo, aggF, m0, tid);
  unit_mfma_h(acc, wuB, ct0, Ahi, Alo, Bhi, Blo, tid, lane, wid);

  const int rbase = m0 + wid * 16 + ((lane >> 4) << 2);
  const int cb = lane & 15;
  #pragma unroll
  for (int ct = 0; ct < 4; ct++) {
    int n = (ct0 + ct) * 16 + cb;
    float bv = ub[n];
    #pragma unroll
    for (int r = 0; r < 4; r++) {
      float v = fmaxf(acc[ct][r] + bv, 0.f)
              + h[(size_t)(rbase + r) * HID + n];
      out[(size_t)(rbase + r) * HID + n] = v;
    }
  }
}

// ---------------- proj1 (full-N, grid (256,2) y=col-block) -------
__global__ __launch_bounds__(256, 4) void proj1_kernel(
    const float* __restrict__ A, const ushort_t* __restrict__ wf01,
    const float* __restrict__ pb1, float* __restrict__ zout) {
  __shared__ ushort_t Ahi[8192], Alo[8192], Bhi[8192], Blo[8192];
  const int tid = threadIdx.x, lane = tid & 63, wid = tid >> 6;
  const int m0 = blockIdx.x * 64;
  const int y = blockIdx.y;
  stage_A_convert(Ahi, Alo, A, m0, tid);
  f32x4 acc[8];
  f32x4 z = {0.f, 0.f, 0.f, 0.f};
  #pragma unroll
  for (int ct = 0; ct < 8; ct++) acc[ct] = z;
  unit_mfma(acc, wf01 + (size_t)y * 32768, Ahi, Alo, Bhi, Blo, tid, lane, wid);

  const int rbase = m0 + wid * 16 + ((lane >> 4) << 2);
  const int cb = lane & 15;
  #pragma unroll
  for (int ct = 0; ct < 8; ct++) {
    int n = y * 128 + ct * 16 + cb;
    float bv = pb1[n];
    #pragma unroll
    for (int r = 0; r < 4; r++)
      zout[(size_t)(rbase + r) * PROJ_D + n] = acc[ct][r] + bv;
  }
}

// ---------------- mean-aggregation over bf16 messages (2 nodes/block) -----
__global__ __launch_bounds__(256) void agg_kernel(const ushort_t* __restrict__ Abuf,
                                                  const ushort_t* __restrict__ Bbuf,
                                                  const int* __restrict__ row_ptr,
                                                  const int* __restrict__ col,
                                                  float* __restrict__ agg) {
  int j = blockIdx.x * 2 + (threadIdx.x >> 7);
  int c = threadIdx.x & 127;
  float bj = bf16_to_f(Bbuf[(size_t)j * HID + c]);
  int s = row_ptr[j], e = row_ptr[j + 1];
  float acc = 0.f;
  int p = s;
  for (; p + 4 <= e; p += 4) {
    int i0 = col[p], i1 = col[p+1], i2 = col[p+2], i3 = col[p+3];
    float v0 = bf16_to_f(Abuf[(size_t)i0 * HID + c]);
    float v1 = bf16_to_f(Abuf[(size_t)i1 * HID + c]);
    float v2 = bf16_to_f(Abuf[(size_t)i2 * HID + c]);
    float v3 = bf16_to_f(Abuf[(size_t)i3 * HID + c]);
    acc += fmaxf(v0 + bj, 0.f) + fmaxf(v1 + bj, 0.f)
         + fmaxf(v2 + bj, 0.f) + fmaxf(v3 + bj, 0.f);
  }
  for (; p < e; p++) {
    int i = col[p];
    acc += fmaxf(bf16_to_f(Abuf[(size_t)i * HID + c]) + bj, 0.f);
  }
  float deg = (float)(e - s);
  float inv = 1.0f / fmaxf(deg, 1.0f);
  agg[(size_t)j * HID + c] = acc * inv;
}

extern "C" void kernel_launch(void* const* d_in, const int* in_sizes, int n_in,
                              void* d_out, int out_size, void* d_ws, size_t ws_size,
                              hipStream_t stream) {
  (void)in_sizes; (void)n_in; (void)out_size; (void)ws_size;
  const float* x       = (const float*)d_in[0];
  const float* pos     = (const float*)d_in[1];
  const float* enc_w0  = (const float*)d_in[3];
  const float* enc_b0  = (const float*)d_in[4];
  const float* enc_w1  = (const float*)d_in[5];
  const float* enc_b1  = (const float*)d_in[6];
  const float* msg_w   = (const float*)d_in[7];
  const float* msg_b   = (const float*)d_in[8];
  const float* upd_w   = (const float*)d_in[9];
  const float* upd_b   = (const float*)d_in[10];
  const float* proj_w0 = (const float*)d_in[11];
  const float* proj_b0 = (const float*)d_in[12];
  const float* proj_w1 = (const float*)d_in[13];
  const float* proj_b1 = (const float*)d_in[14];

  char* ws = (char*)d_ws;
  size_t off = 0;
  auto alloc = [&](size_t bytes) -> void* {
    void* p = ws + off;
    off += (bytes + 255) & ~(size_t)255;
    return p;
  };
  int*      nbr     = (int*)alloc((size_t)EE * 4);
  int*      cnt     = (int*)alloc((size_t)BN * 4);
  int*      fill    = (int*)alloc((size_t)BN * 4);
  int*      row_ptr = (int*)alloc((size_t)(BN + 1) * 4);
  int*      col     = (int*)alloc((size_t)EE * 4);
  float*    h_a     = (float*)alloc((size_t)BN * HID * 4);
  float*    h_b     = (float*)alloc((size_t)BN * HID * 4);
  ushort_t* bufA    = (ushort_t*)alloc((size_t)BN * HID * 2);
  ushort_t* bufB    = (ushort_t*)alloc((size_t)BN * HID * 2);
  float*    bufAgg  = (float*)alloc((size_t)BN * HID * 4);
  ushort_t* wfrag   = (ushort_t*)alloc((size_t)16 * 32768 * 2);
  float4*   spos    = (float4*)alloc((size_t)BN * 16);
  int*      cptr    = (int*)alloc((size_t)BB * (NCELL + 1) * 4);
  float*    out     = (float*)d_out;
  float*    hOut    = out + (size_t)BN * PROJ_D;

  // cellsort also zeroes cnt+fill (contiguous int4 region)
  cellsort_kernel<<<BB, 256, 0, stream>>>(pos, spos, cptr, (int4*)cnt);
  prep_w_kernel<<<128, 256, 0, stream>>>(enc_w1, msg_w, upd_w, proj_w0, proj_w1, wfrag);
  knn_kernel<<<BN / QPB, 1024, 0, stream>>>(spos, cptr, nbr, cnt);
  scan_kernel<<<1, 256, 0, stream>>>(cnt, row_ptr);
  fill_kernel<<<EE / 256, 256, 0, stream>>>(nbr, row_ptr, fill, col);

  encg1_kernel<<<dim3(BN / 64, 2), 256, 0, stream>>>(
      x, enc_w0, enc_b0, wfrag + 0 * 32768, enc_b1, h_a);

  float* hc = h_a;
  float* hn = h_b;
  for (int i = 0; i < 3; i++) {
    msg_kernel<<<dim3(BN / 64, 2), 256, 0, stream>>>(
        hc, wfrag + (size_t)(1 + 2 * i) * 32768,
        wfrag + (size_t)(2 + 2 * i) * 32768, msg_b + (size_t)i * HID,
        bufA, bufB);
    agg_kernel<<<BN / 2, 256, 0, stream>>>(bufA, bufB, row_ptr, col, bufAgg);
    float* target = (i == 2) ? hOut : hn;
    upd_kernel<<<dim3(BN / 64, 2), 256, 0, stream>>>(
        hc, wfrag + (size_t)(7 + 2 * i) * 32768, bufAgg,
        wfrag + (size_t)(8 + 2 * i) * 32768, upd_b + (size_t)i * HID, target);
    hn = hc; hc = target;
  }

  // proj0 -> h_b (free after MP loop), proj1 -> out
  g1_kernel<1><<<dim3(BN / 64, 2), 256, 0, stream>>>(hc, wfrag + 13 * 32768,
                                                     proj_b0, h_b);
  proj1_kernel<<<dim3(BN / 64, 2), 256, 0, stream>>>(
      h_b, wfrag + 14 * 32768, proj_b1, out);
}

// Round 18
// 208.917 us; speedup vs baseline: 1.3210x; 1.0246x over previous
//
#include <hip/hip_runtime.h>
#include <stdint.h>
#include <math.h>

#define NN 2048
#define BB 8
#define BN (BB*NN)
#define KK 16
#define EE (BN*KK)
#define HID 128
#define PROJ_D 256
#define QPB 16    // queries (waves) per knn block
#define CDIM 6
#define NCELL (CDIM*CDIM*CDIM)
#define CAP 512   // per-wave candidate capacity (8 reg slots/lane); ovf->fallback

typedef unsigned long long u64;
typedef unsigned short ushort_t;
typedef __attribute__((ext_vector_type(8))) short short8;
typedef __attribute__((ext_vector_type(4))) float f32x4;

__device__ __forceinline__ u64 wave_min_u64(u64 v) {
  #pragma unroll
  for (int off = 32; off > 0; off >>= 1) {
    u64 o = __shfl_xor(v, off);
    v = o < v ? o : v;
  }
  return v;
}

// ================= split-bf16 MFMA helpers =================
__device__ __forceinline__ ushort_t bf16_rne(float x) {
  unsigned u = __float_as_uint(x);
  unsigned r = u + 0x7FFFu + ((u >> 16) & 1u);
  return (ushort_t)(r >> 16);
}
__device__ __forceinline__ float bf16_to_f(ushort_t h) {
  return __uint_as_float(((unsigned)h) << 16);
}
__device__ __forceinline__ unsigned cvtpk_bf16(float a, float b) {
  unsigned r;
  asm("v_cvt_pk_bf16_f32 %0, %1, %2" : "=v"(r) : "v"(a), "v"(b));
  return r;
}

__device__ __forceinline__ void cvt8(const float4 f0, const float4 f1,
                                     short8& hi, short8& lo) {
  unsigned h0 = cvtpk_bf16(f0.x, f0.y);
  unsigned h1 = cvtpk_bf16(f0.z, f0.w);
  unsigned h2 = cvtpk_bf16(f1.x, f1.y);
  unsigned h3 = cvtpk_bf16(f1.z, f1.w);
  unsigned l0 = cvtpk_bf16(f0.x - __uint_as_float(h0 << 16),
                           f0.y - __uint_as_float(h0 & 0xffff0000u));
  unsigned l1 = cvtpk_bf16(f0.z - __uint_as_float(h1 << 16),
                           f0.w - __uint_as_float(h1 & 0xffff0000u));
  unsigned l2 = cvtpk_bf16(f1.x - __uint_as_float(h2 << 16),
                           f1.y - __uint_as_float(h2 & 0xffff0000u));
  unsigned l3 = cvtpk_bf16(f1.z - __uint_as_float(h3 << 16),
                           f1.w - __uint_as_float(h3 & 0xffff0000u));
  union { unsigned u[4]; short8 v; } H, L;
  H.u[0] = h0; H.u[1] = h1; H.u[2] = h2; H.u[3] = h3;
  L.u[0] = l0; L.u[1] = l1; L.u[2] = l2; L.u[3] = l3;
  hi = H.v;
  lo = L.v;
}

// ---------------- setup: blocks 0-7 cellsort(+zero cnt/fill), 8-135 prep_w --
__global__ __launch_bounds__(256) void setup_kernel(
    const float* __restrict__ pos, float4* __restrict__ spos,
    int* __restrict__ cptr, int4* __restrict__ cntz,
    const float* __restrict__ enc_w1, const float* __restrict__ msg_w,
    const float* __restrict__ upd_w, const float* __restrict__ proj_w0,
    const float* __restrict__ proj_w1, ushort_t* __restrict__ wfrag) {
  __shared__ int hist[NCELL];
  __shared__ int base[NCELL];
  const int tid = threadIdx.x;
  if (blockIdx.x < 8) {
    const int b = blockIdx.x;
    #pragma unroll
    for (int k = 0; k < 4; k++)
      cntz[(b * 256 + tid) + k * 2048] = make_int4(0, 0, 0, 0);
    if (tid < NCELL) hist[tid] = 0;
    __syncthreads();
    int cellv[8];
    float4 pv[8];
    #pragma unroll
    for (int k = 0; k < 8; k++) {
      int j = tid * 8 + k;
      const float* pp = pos + ((size_t)b * NN + j) * 3;
      float x = pp[0], y = pp[1], z = pp[2];
      int cx = (int)(x * 6.0f); cx = cx > 5 ? 5 : cx;
      int cy = (int)(y * 6.0f); cy = cy > 5 ? 5 : cy;
      int cz = (int)(z * 6.0f); cz = cz > 5 ? 5 : cz;
      int cell = (cx * 6 + cy) * 6 + cz;
      cellv[k] = cell;
      pv[k] = make_float4(x, y, z, __int_as_float(j));
      atomicAdd(&hist[cell], 1);
    }
    __syncthreads();
    if (tid == 0) {
      int run = 0;
      for (int c = 0; c < NCELL; c++) {
        cptr[b * (NCELL + 1) + c] = run;
        base[c] = run;
        run += hist[c];
      }
      cptr[b * (NCELL + 1) + NCELL] = run;
    }
    __syncthreads();
    if (tid < NCELL) hist[tid] = 0;
    __syncthreads();
    #pragma unroll
    for (int k = 0; k < 8; k++) {
      int slot = base[cellv[k]] + atomicAdd(&hist[cellv[k]], 1);
      spos[(size_t)b * NN + slot] = pv[k];
    }
  } else {
    int ub = blockIdx.x - 8;
    int u = ub >> 3;
    int c = (ub & 7) * 256 + tid;
    const float* src;
    int ldW = HID;
    if (u == 0) src = enc_w1;
    else if (u <= 6)  { int i = (u-1)>>1; int hf = (u-1)&1; src = msg_w + ((size_t)i*256 + hf*128) * HID; }
    else if (u <= 12) { int i = (u-7)>>1; int hf = (u-7)&1; src = upd_w + ((size_t)i*256 + hf*128) * HID; }
    else if (u == 13) src = proj_w0;
    else { src = proj_w1 + (u - 14) * 128; ldW = PROJ_D; }
    int ks = c >> 9, ct = (c >> 6) & 7, lane = c & 63;
    int colc = ct * 16 + (lane & 15);
    int k0 = ks * 32 + ((lane >> 4) << 3);
    float f[8];
    #pragma unroll
    for (int e = 0; e < 8; e++) f[e] = src[(size_t)(k0 + e) * ldW + colc];
    short8 hv, lv;
    cvt8(make_float4(f[0],f[1],f[2],f[3]), make_float4(f[4],f[5],f[6],f[7]), hv, lv);
    *(short8*)&wfrag[(size_t)u * 32768 + (size_t)c * 8] = hv;
    *(short8*)&wfrag[(size_t)u * 32768 + 16384 + (size_t)c * 8] = lv;
  }
}

// ---------------- kNN: cell-pruned + register-cached distances -------------
// r18: fast mode caches (d, orig_j) for each lane's <=8 candidates in VGPRs
// (static-index unroll), so bin-member and emission passes are register math.
// Fallback (ovf or <17 binned) recomputes over all 2048 -- exact either way.
__global__ __launch_bounds__(1024) void knn_kernel(
    const float4* __restrict__ spos, const int* __restrict__ cptr,
    int* __restrict__ nbr, int* __restrict__ cnt) {
  __shared__ float4 Ps[NN];             // 32 KB (sorted; .w = orig idx bits)
  __shared__ unsigned Hist[QPB * 256];  // 16 KB
  __shared__ ushort_t Cand[QPB * CAP];  // 16 KB
  __shared__ int Cp[NCELL + 1];
  const int b  = blockIdx.x >> 7;
  const int qb = blockIdx.x & 127;
  const int wave = threadIdx.x >> 6;
  const int lane = threadIdx.x & 63;
  const int s_q = qb * QPB + wave;

  for (int t = threadIdx.x; t < NN; t += 1024)
    Ps[t] = spos[(size_t)b * NN + t];
  if (threadIdx.x <= NCELL)
    Cp[threadIdx.x] = cptr[b * (NCELL + 1) + threadIdx.x];
  __syncthreads();

  const float4 q = Ps[s_q];
  const float xi = q.x, yi = q.y, zi = q.z;
  const int orig_i = __float_as_int(q.w);
  unsigned* H = &Hist[wave * 256];
  ushort_t* CL = &Cand[wave * CAP];

  int cx = (int)(xi * 6.0f); cx = cx > 5 ? 5 : cx;
  int cy = (int)(yi * 6.0f); cy = cy > 5 ? 5 : cy;
  int cz = (int)(zi * 6.0f); cz = cz > 5 ? 5 : cz;

  int T = 0;
  bool ovf = false;
  #pragma unroll 1
  for (int dxy = 0; dxy < 9; dxy++) {
    int dx = dxy / 3 - 1, dy = dxy - (dxy / 3) * 3 - 1;
    int ncx = cx + dx; ncx += (ncx < 0) ? 6 : 0; ncx -= (ncx >= 6) ? 6 : 0;
    int ncy = cy + dy; ncy += (ncy < 0) ? 6 : 0; ncy -= (ncy >= 6) ? 6 : 0;
    int cbse = (ncx * 6 + ncy) * 6;
    int s0, l0, s1 = 0, l1 = 0;
    if (cz == 0) {
      s0 = Cp[cbse + 5]; l0 = Cp[cbse + 6] - s0;
      s1 = Cp[cbse];     l1 = Cp[cbse + 2] - s1;
    } else if (cz == 5) {
      s0 = Cp[cbse + 4]; l0 = Cp[cbse + 6] - s0;
      s1 = Cp[cbse];     l1 = Cp[cbse + 1] - s1;
    } else {
      s0 = Cp[cbse + cz - 1]; l0 = Cp[cbse + cz + 2] - s0;
    }
    if (T + l0 + l1 > CAP) { ovf = true; break; }
    for (int t = lane; t < l0; t += 64) CL[T + t] = (ushort_t)(s0 + t);
    T += l0;
    for (int t = lane; t < l1; t += 64) CL[T + t] = (ushort_t)(s1 + t);
    T += l1;
  }

  int mode = ovf ? 1 : 0;

  // ---- pass 1 (fast): compute + cache distances, 8 static slots/lane ----
  float dreg[8];
  int ojreg[8];
  if (!mode) {
    #pragma unroll
    for (int it = 0; it < 8; it++) {
      int t = it * 64 + lane;
      float d = 1e30f;
      int oj = 0;
      if (t < T) {
        float4 pj = Ps[(int)CL[t]];
        float tx = xi - pj.x, ty = yi - pj.y, tz = zi - pj.z;
        float ddx = __fsub_rn(tx, rintf(tx));
        float ddy = __fsub_rn(ty, rintf(ty));
        float ddz = __fsub_rn(tz, rintf(tz));
        float s = __fadd_rn(__fadd_rn(__fadd_rn(__fmul_rn(ddx,ddx), __fmul_rn(ddy,ddy)),
                                      __fmul_rn(ddz,ddz)), 1e-12f);
        d = __fsqrt_rn(s);
        oj = __float_as_int(pj.w);
      }
      dreg[it] = d;
      ojreg[it] = oj;
    }
  }

  float scale = 1536.0f;
  int bstar = 0; unsigned C = 0;
  for (;;) {
    scale = mode ? 256.0f : 1536.0f;
    int binmax = mode ? 256 : 254;
    *(uint4*)&H[lane * 4] = make_uint4(0u, 0u, 0u, 0u);
    if (!mode) {
      #pragma unroll
      for (int it = 0; it < 8; it++) {
        int bin = (int)(dreg[it] * 1536.0f);   // d=1e30 -> huge bin, skipped
        if (bin < binmax) atomicAdd(&H[bin], 1u);
      }
    } else {
      for (int t = lane; t < NN; t += 64) {
        float4 pj = Ps[t];
        float tx = xi - pj.x, ty = yi - pj.y, tz = zi - pj.z;
        float ddx = __fsub_rn(tx, rintf(tx));
        float ddy = __fsub_rn(ty, rintf(ty));
        float ddz = __fsub_rn(tz, rintf(tz));
        float s = __fadd_rn(__fadd_rn(__fadd_rn(__fmul_rn(ddx,ddx), __fmul_rn(ddy,ddy)),
                                      __fmul_rn(ddz,ddz)), 1e-12f);
        float d = __fsqrt_rn(s);
        int bin = (int)(d * 256.0f);
        if (bin < 256) atomicAdd(&H[bin], 1u);
      }
    }
    uint4 cv = *(const uint4*)&H[lane * 4];
    unsigned s4 = cv.x + cv.y + cv.z + cv.w;
    unsigned incl = s4;
    #pragma unroll
    for (int off = 1; off < 64; off <<= 1) {
      unsigned v = __shfl_up(incl, off);
      if (lane >= off) incl += v;
    }
    unsigned total = __shfl(incl, 63);
    if (total >= 17u) {
      unsigned base = incl - s4;
      bool has = (incl >= 17u) && (base < 17u);
      u64 hmask = __ballot(has);
      int srcl = __ffsll((unsigned long long)hmask) - 1;
      int bl = 0; unsigned Cl = 0;
      if (has) {
        if (base + cv.x >= 17u)                    { bl = lane*4 + 0; Cl = base; }
        else if (base + cv.x + cv.y >= 17u)        { bl = lane*4 + 1; Cl = base + cv.x; }
        else if (base + cv.x + cv.y + cv.z >= 17u) { bl = lane*4 + 2; Cl = base + cv.x + cv.y; }
        else                                       { bl = lane*4 + 3; Cl = base + cv.x + cv.y + cv.z; }
      }
      bstar = __shfl(bl, srcl);
      C     = __shfl(Cl, srcl);
      break;
    }
    mode = 1;   // fallback: full scan (exact; all bins covered)
  }
  const int m = 17 - (int)C;

  // ---- pass 2: per-lane sorted members of bin bstar ----
  u64 lst[6];
  #pragma unroll
  for (int t = 0; t < 6; t++) lst[t] = ~0ull;
  if (!mode) {
    #pragma unroll
    for (int it = 0; it < 8; it++) {
      int bin = (int)(dreg[it] * 1536.0f);
      if (bin == bstar) {
        u64 key = ((u64)__float_as_uint(dreg[it]) << 11) | (unsigned)ojreg[it];
        if (key < lst[5]) {
          lst[5] = key;
          #pragma unroll
          for (int u = 5; u > 0; u--) {
            u64 a = lst[u-1], c2 = lst[u];
            lst[u-1] = a < c2 ? a : c2;
            lst[u]   = a < c2 ? c2 : a;
          }
        }
      }
    }
  } else {
    for (int t = lane; t < NN; t += 64) {
      float4 pj = Ps[t];
      float tx = xi - pj.x, ty = yi - pj.y, tz = zi - pj.z;
      float ddx = __fsub_rn(tx, rintf(tx));
      float ddy = __fsub_rn(ty, rintf(ty));
      float ddz = __fsub_rn(tz, rintf(tz));
      float s = __fadd_rn(__fadd_rn(__fadd_rn(__fmul_rn(ddx,ddx), __fmul_rn(ddy,ddy)),
                                    __fmul_rn(ddz,ddz)), 1e-12f);
      float d = __fsqrt_rn(s);
      int bin = (int)(d * 256.0f);
      if (bin == bstar) {
        u64 key = ((u64)__float_as_uint(d) << 11) | (unsigned)__float_as_int(pj.w);
        if (key < lst[5]) {
          lst[5] = key;
          #pragma unroll
          for (int u = 5; u > 0; u--) {
            u64 a = lst[u-1], c2 = lst[u];
            lst[u-1] = a < c2 ? a : c2;
            lst[u]   = a < c2 ? c2 : a;
          }
        }
      }
    }
  }

  u64 kstar = 0;
  #pragma unroll 1
  for (int r = 0; r < m; r++) {
    u64 h0 = lst[0];
    u64 gm = wave_min_u64(h0);
    kstar = gm;
    bool win = (h0 == gm);
    #pragma unroll
    for (int u = 0; u < 5; u++) lst[u] = win ? lst[u+1] : lst[u];
    lst[5] = win ? ~0ull : lst[5];
  }

  // ---- pass 3: emission (register math in fast mode) ----
  int* outp = nbr + ((size_t)b * NN + orig_i) * KK;
  int total_e = 0;
  if (!mode) {
    #pragma unroll
    for (int it = 0; it < 8; it++) {
      int t = it * 64 + lane;
      int oj = ojreg[it];
      bool pred = false;
      if (t < T) {
        u64 key = ((u64)__float_as_uint(dreg[it]) << 11) | (unsigned)oj;
        pred = (key <= kstar) && (oj != orig_i);
      }
      u64 msk = __ballot(pred);
      if (pred) {
        int ofs = total_e + __popcll(msk & ((1ull << lane) - 1ull));
        outp[ofs] = b * NN + oj;
        atomicAdd(&cnt[b * NN + oj], 1);
      }
      total_e += __popcll(msk);
    }
  } else {
    for (int t0 = 0; t0 < NN; t0 += 64) {
      int t = t0 + lane;
      float4 pj = Ps[t];
      float tx = xi - pj.x, ty = yi - pj.y, tz = zi - pj.z;
      float ddx = __fsub_rn(tx, rintf(tx));
      float ddy = __fsub_rn(ty, rintf(ty));
      float ddz = __fsub_rn(tz, rintf(tz));
      float s = __fadd_rn(__fadd_rn(__fadd_rn(__fmul_rn(ddx,ddx), __fmul_rn(ddy,ddy)),
                                    __fmul_rn(ddz,ddz)), 1e-12f);
      float d = __fsqrt_rn(s);
      int oj = __float_as_int(pj.w);
      u64 key = ((u64)__float_as_uint(d) << 11) | (unsigned)oj;
      bool pred = (key <= kstar) && (oj != orig_i);
      u64 msk = __ballot(pred);
      if (pred) {
        int ofs = total_e + __popcll(msk & ((1ull << lane) - 1ull));
        outp[ofs] = b * NN + oj;
        atomicAdd(&cnt[b * NN + oj], 1);
      }
      total_e += __popcll(msk);
    }
  }
}

// ---------------- CSR build ----------------
__global__ __launch_bounds__(256) void scan_kernel(const int* __restrict__ cnt,
                                                   int* __restrict__ row_ptr) {
  __shared__ int ps[256];
  int t = threadIdx.x;
  const int4* cv = (const int4*)(cnt + t * 64);
  int4 c[16];
  int s = 0;
  #pragma unroll
  for (int i = 0; i < 16; i++) {
    c[i] = cv[i];
    s += c[i].x + c[i].y + c[i].z + c[i].w;
  }
  ps[t] = s;
  __syncthreads();
  for (int off = 1; off < 256; off <<= 1) {
    int v = 0;
    if (t >= off) v = ps[t - off];
    __syncthreads();
    ps[t] += v;
    __syncthreads();
  }
  int run = t ? ps[t - 1] : 0;
  int4* rp = (int4*)(row_ptr + t * 64);
  #pragma unroll
  for (int i = 0; i < 16; i++) {
    int4 o;
    o.x = run; run += c[i].x;
    o.y = run; run += c[i].y;
    o.z = run; run += c[i].z;
    o.w = run; run += c[i].w;
    rp[i] = o;
  }
  if (t == 255) row_ptr[BN] = run;
}

__global__ __launch_bounds__(256) void fill_kernel(const int* __restrict__ nbr,
                                                   const int* __restrict__ row_ptr,
                                                   int* __restrict__ fill,
                                                   int* __restrict__ col) {
  int e = blockIdx.x * 256 + threadIdx.x;
  int d = nbr[e];
  int srcn = e >> 4;
  int p = row_ptr[d] + atomicAdd(&fill[d], 1);
  col[p] = srcn;
}

// convert 64x128 f32 global rows -> fragment hi/lo in LDS (consumer-side)
__device__ __forceinline__ void stage_A_convert(ushort_t* Ahi, ushort_t* Alo,
                                                const float* A, int m0, int tid) {
  #pragma unroll
  for (int i = 0; i < 4; i++) {
    int c = tid + i * 256;
    int row = c >> 4, kg = c & 15;
    const float4* ap = (const float4*)(A + (((size_t)m0 + row) << 7) + (kg << 3));
    short8 hv, lv;
    cvt8(ap[0], ap[1], hv, lv);
    int idx = (((row >> 4) * 4 + (kg >> 2)) * 64 + ((row & 15) | ((kg & 3) << 4))) * 8;
    *(short8*)&Ahi[idx] = hv;
    *(short8*)&Alo[idx] = lv;
  }
}

// ---- full-N unit (8 col-tiles) ----
__device__ __forceinline__ void unit_mfma(f32x4 acc[8], const ushort_t* wf,
                                          const ushort_t* Ahi, const ushort_t* Alo,
                                          ushort_t* Bhi, ushort_t* Blo,
                                          int tid, int lane, int wid) {
  #pragma unroll 1
  for (int half = 0; half < 2; half++) {
    __syncthreads();
    const short8* ghi = (const short8*)(wf + half * 8192);
    const short8* glo = (const short8*)(wf + 16384 + half * 8192);
    #pragma unroll
    for (int i = 0; i < 4; i++) {
      ((short8*)Bhi)[tid + i * 256] = ghi[tid + i * 256];
      ((short8*)Blo)[tid + i * 256] = glo[tid + i * 256];
    }
    __syncthreads();
    #pragma unroll
    for (int ks2 = 0; ks2 < 2; ks2++) {
      int ksA = half * 2 + ks2;
      short8 ah = *(const short8*)&Ahi[((wid * 4 + ksA) * 64 + lane) * 8];
      short8 al = *(const short8*)&Alo[((wid * 4 + ksA) * 64 + lane) * 8];
      #pragma unroll
      for (int ct = 0; ct < 8; ct++) {
        short8 bh = *(const short8*)&Bhi[((ks2 * 8 + ct) * 64 + lane) * 8];
        short8 bl = *(const short8*)&Blo[((ks2 * 8 + ct) * 64 + lane) * 8];
        acc[ct] = __builtin_amdgcn_mfma_f32_16x16x32_bf16(ah, bh, acc[ct], 0, 0, 0);
        acc[ct] = __builtin_amdgcn_mfma_f32_16x16x32_bf16(ah, bl, acc[ct], 0, 0, 0);
        acc[ct] = __builtin_amdgcn_mfma_f32_16x16x32_bf16(al, bh, acc[ct], 0, 0, 0);
      }
    }
  }
}

// ---- N-half unit (4 col-tiles, ct0 = 0 or 4) ----
__device__ __forceinline__ void unit_mfma_h(f32x4 acc[4], const ushort_t* wf,
                                            int ct0,
                                            const ushort_t* Ahi, const ushort_t* Alo,
                                            ushort_t* Bhi, ushort_t* Blo,
                                            int tid, int lane, int wid) {
  #pragma unroll 1
  for (int half = 0; half < 2; half++) {
    __syncthreads();
    #pragma unroll
    for (int i = 0; i < 2; i++) {
      int sc = tid + i * 256;             // 0..511
      int ks2 = sc >> 8;
      int cts = (sc >> 6) & 3;
      int ln  = sc & 63;
      int c = half * 1024 + ks2 * 512 + (ct0 + cts) * 64 + ln;
      ((short8*)Bhi)[sc] = *(const short8*)&wf[(size_t)c * 8];
      ((short8*)Blo)[sc] = *(const short8*)&wf[16384 + (size_t)c * 8];
    }
    __syncthreads();
    #pragma unroll
    for (int ks2 = 0; ks2 < 2; ks2++) {
      int ksA = half * 2 + ks2;
      short8 ah = *(const short8*)&Ahi[((wid * 4 + ksA) * 64 + lane) * 8];
      short8 al = *(const short8*)&Alo[((wid * 4 + ksA) * 64 + lane) * 8];
      #pragma unroll
      for (int ct = 0; ct < 4; ct++) {
        short8 bh = *(const short8*)&Bhi[((ks2 * 4 + ct) * 64 + lane) * 8];
        short8 bl = *(const short8*)&Blo[((ks2 * 4 + ct) * 64 + lane) * 8];
        acc[ct] = __builtin_amdgcn_mfma_f32_16x16x32_bf16(ah, bh, acc[ct], 0, 0, 0);
        acc[ct] = __builtin_amdgcn_mfma_f32_16x16x32_bf16(ah, bl, acc[ct], 0, 0, 0);
        acc[ct] = __builtin_amdgcn_mfma_f32_16x16x32_bf16(al, bh, acc[ct], 0, 0, 0);
      }
    }
  }
}

// ---------------- encg1: enc0 fused + enc1 N-split, grid (256,2) -----------
__global__ __launch_bounds__(256, 4) void encg1_kernel(
    const float* __restrict__ x, const float* __restrict__ ew0,
    const float* __restrict__ eb0, const ushort_t* __restrict__ wf,
    const float* __restrict__ eb1, float* __restrict__ hOut) {
  __shared__ ushort_t Ahi[8192], Alo[8192], Bhi[4096], Blo[4096];
  __shared__ float XW[1088];   // x[320] | w0[640] @320 | b0[128] @960
  const int tid = threadIdx.x, lane = tid & 63, wid = tid >> 6;
  const int m0 = blockIdx.x * 64, ct0 = blockIdx.y * 4;

  if (tid < 80) ((float4*)XW)[tid] = ((const float4*)(x + (size_t)m0 * 5))[tid];
  else if (tid < 240) ((float4*)XW)[tid] = ((const float4*)ew0)[tid - 80];
  else {
    int k = tid - 240;
    ((float4*)XW)[240 + k] = ((const float4*)eb0)[k];
    ((float4*)XW)[256 + k] = ((const float4*)eb0)[16 + k];
  }
  __syncthreads();

  #pragma unroll
  for (int i = 0; i < 4; i++) {
    int c = tid + i * 256;
    int row = c >> 4, kg = c & 15;
    float xr[5];
    #pragma unroll
    for (int d = 0; d < 5; d++) xr[d] = XW[row * 5 + d];
    float v[8];
    #pragma unroll
    for (int e = 0; e < 8; e++) {
      int col = kg * 8 + e;
      float a = XW[960 + col];
      #pragma unroll
      for (int d = 0; d < 5; d++) a += xr[d] * XW[320 + d * 128 + col];
      v[e] = fmaxf(a, 0.f);
    }
    short8 hv, lv;
    cvt8(make_float4(v[0],v[1],v[2],v[3]), make_float4(v[4],v[5],v[6],v[7]), hv, lv);
    int idx = (((row >> 4) * 4 + (kg >> 2)) * 64 + ((row & 15) | ((kg & 3) << 4))) * 8;
    *(short8*)&Ahi[idx] = hv;
    *(short8*)&Alo[idx] = lv;
  }

  f32x4 acc[4];
  f32x4 z = {0.f, 0.f, 0.f, 0.f};
  #pragma unroll
  for (int ct = 0; ct < 4; ct++) acc[ct] = z;
  unit_mfma_h(acc, wf, ct0, Ahi, Alo, Bhi, Blo, tid, lane, wid);

  const int rbase = m0 + wid * 16 + ((lane >> 4) << 2);
  const int cb = lane & 15;
  #pragma unroll
  for (int ct = 0; ct < 4; ct++) {
    int n = (ct0 + ct) * 16 + cb;
    float bv = eb1[n];
    #pragma unroll
    for (int r = 0; r < 4; r++)
      hOut[(size_t)(rbase + r) * HID + n] = fmaxf(acc[ct][r] + bv, 0.f);
  }
}

// ---------------- g1 (N-split): out = [relu](A@W + bias), grid (256,2) -----
template<int RELU>
__global__ __launch_bounds__(256, 4) void g1_kernel(
    const float* __restrict__ A, const ushort_t* __restrict__ wf,
    const float* __restrict__ bias, float* __restrict__ out) {
  __shared__ ushort_t Ahi[8192], Alo[8192], Bhi[4096], Blo[4096];
  const int tid = threadIdx.x, lane = tid & 63, wid = tid >> 6;
  const int m0 = blockIdx.x * 64, ct0 = blockIdx.y * 4;
  stage_A_convert(Ahi, Alo, A, m0, tid);
  f32x4 acc[4];
  f32x4 z = {0.f, 0.f, 0.f, 0.f};
  #pragma unroll
  for (int ct = 0; ct < 4; ct++) acc[ct] = z;
  unit_mfma_h(acc, wf, ct0, Ahi, Alo, Bhi, Blo, tid, lane, wid);

  const int rbase = m0 + wid * 16 + ((lane >> 4) << 2);
  const int cb = lane & 15;
  #pragma unroll
  for (int ct = 0; ct < 4; ct++) {
    int n = (ct0 + ct) * 16 + cb;
    float bv = bias ? bias[n] : 0.f;
    #pragma unroll
    for (int r = 0; r < 4; r++) {
      float v = acc[ct][r] + bv;
      if (RELU) v = fmaxf(v, 0.f);
      out[(size_t)(rbase + r) * HID + n] = v;
    }
  }
}

// ---------------- msg pair (full-N, grid (256,2) y=top/bot), bf16 out ------
__global__ __launch_bounds__(256, 4) void msg_kernel(
    const float* __restrict__ h, const ushort_t* __restrict__ wfT,
    const ushort_t* __restrict__ wfB, const float* __restrict__ mb,
    ushort_t* __restrict__ bufA, ushort_t* __restrict__ bufB) {
  __shared__ ushort_t Ahi[8192], Alo[8192], Bhi[8192], Blo[8192];
  const int tid = threadIdx.x, lane = tid & 63, wid = tid >> 6;
  const int m0 = blockIdx.x * 64;
  const int y = blockIdx.y;
  stage_A_convert(Ahi, Alo, h, m0, tid);
  f32x4 acc[8];
  f32x4 z = {0.f, 0.f, 0.f, 0.f};
  #pragma unroll
  for (int ct = 0; ct < 8; ct++) acc[ct] = z;
  unit_mfma(acc, y ? wfB : wfT, Ahi, Alo, Bhi, Blo, tid, lane, wid);

  ushort_t* out = y ? bufB : bufA;
  const float* bias = y ? mb : nullptr;
  const int rbase = m0 + wid * 16 + ((lane >> 4) << 2);
  const int cb = lane & 15;
  #pragma unroll
  for (int ct = 0; ct < 8; ct++) {
    int n = ct * 16 + cb;
    float bv = bias ? bias[n] : 0.f;
    #pragma unroll
    for (int r = 0; r < 4; r++)
      out[(size_t)(rbase + r) * HID + n] = bf16_rne(acc[ct][r] + bv);
  }
}

// ---------------- upd (N-split): h' = h + relu(h@Wt + agg@Wb + ub) ---------
__global__ __launch_bounds__(256, 4) void upd_kernel(
    const float* __restrict__ h, const ushort_t* __restrict__ wuT,
    const float* __restrict__ aggF, const ushort_t* __restrict__ wuB,
    const float* __restrict__ ub, float* __restrict__ out) {
  __shared__ ushort_t Ahi[8192], Alo[8192], Bhi[4096], Blo[4096];
  const int tid = threadIdx.x, lane = tid & 63, wid = tid >> 6;
  const int m0 = blockIdx.x * 64, ct0 = blockIdx.y * 4;
  stage_A_convert(Ahi, Alo, h, m0, tid);
  f32x4 acc[4];
  f32x4 z = {0.f, 0.f, 0.f, 0.f};
  #pragma unroll
  for (int ct = 0; ct < 4; ct++) acc[ct] = z;
  unit_mfma_h(acc, wuT, ct0, Ahi, Alo, Bhi, Blo, tid, lane, wid);
  __syncthreads();                         // phase-1 A reads done
  stage_A_convert(Ahi, Alo, aggF, m0, tid);
  unit_mfma_h(acc, wuB, ct0, Ahi, Alo, Bhi, Blo, tid, lane, wid);

  const int rbase = m0 + wid * 16 + ((lane >> 4) << 2);
  const int cb = lane & 15;
  #pragma unroll
  for (int ct = 0; ct < 4; ct++) {
    int n = (ct0 + ct) * 16 + cb;
    float bv = ub[n];
    #pragma unroll
    for (int r = 0; r < 4; r++) {
      float v = fmaxf(acc[ct][r] + bv, 0.f)
              + h[(size_t)(rbase + r) * HID + n];
      out[(size_t)(rbase + r) * HID + n] = v;
    }
  }
}

// ---------------- proj1 (full-N, grid (256,2) y=col-block) -------
__global__ __launch_bounds__(256, 4) void proj1_kernel(
    const float* __restrict__ A, const ushort_t* __restrict__ wf01,
    const float* __restrict__ pb1, float* __restrict__ zout) {
  __shared__ ushort_t Ahi[8192], Alo[8192], Bhi[8192], Blo[8192];
  const int tid = threadIdx.x, lane = tid & 63, wid = tid >> 6;
  const int m0 = blockIdx.x * 64;
  const int y = blockIdx.y;
  stage_A_convert(Ahi, Alo, A, m0, tid);
  f32x4 acc[8];
  f32x4 z = {0.f, 0.f, 0.f, 0.f};
  #pragma unroll
  for (int ct = 0; ct < 8; ct++) acc[ct] = z;
  unit_mfma(acc, wf01 + (size_t)y * 32768, Ahi, Alo, Bhi, Blo, tid, lane, wid);

  const int rbase = m0 + wid * 16 + ((lane >> 4) << 2);
  const int cb = lane & 15;
  #pragma unroll
  for (int ct = 0; ct < 8; ct++) {
    int n = y * 128 + ct * 16 + cb;
    float bv = pb1[n];
    #pragma unroll
    for (int r = 0; r < 4; r++)
      zout[(size_t)(rbase + r) * PROJ_D + n] = acc[ct][r] + bv;
  }
}

// ---------------- mean-aggregation over bf16 messages (2 nodes/block) -----
__global__ __launch_bounds__(256) void agg_kernel(const ushort_t* __restrict__ Abuf,
                                                  const ushort_t* __restrict__ Bbuf,
                                                  const int* __restrict__ row_ptr,
                                                  const int* __restrict__ col,
                                                  float* __restrict__ agg) {
  int j = blockIdx.x * 2 + (threadIdx.x >> 7);
  int c = threadIdx.x & 127;
  float bj = bf16_to_f(Bbuf[(size_t)j * HID + c]);
  int s = row_ptr[j], e = row_ptr[j + 1];
  float acc = 0.f;
  int p = s;
  for (; p + 4 <= e; p += 4) {
    int i0 = col[p], i1 = col[p+1], i2 = col[p+2], i3 = col[p+3];
    float v0 = bf16_to_f(Abuf[(size_t)i0 * HID + c]);
    float v1 = bf16_to_f(Abuf[(size_t)i1 * HID + c]);
    float v2 = bf16_to_f(Abuf[(size_t)i2 * HID + c]);
    float v3 = bf16_to_f(Abuf[(size_t)i3 * HID + c]);
    acc += fmaxf(v0 + bj, 0.f) + fmaxf(v1 + bj, 0.f)
         + fmaxf(v2 + bj, 0.f) + fmaxf(v3 + bj, 0.f);
  }
  for (; p < e; p++) {
    int i = col[p];
    acc += fmaxf(bf16_to_f(Abuf[(size_t)i * HID + c]) + bj, 0.f);
  }
  float deg = (float)(e - s);
  float inv = 1.0f / fmaxf(deg, 1.0f);
  agg[(size_t)j * HID + c] = acc * inv;
}

extern "C" void kernel_launch(void* const* d_in, const int* in_sizes, int n_in,
                              void* d_out, int out_size, void* d_ws, size_t ws_size,
                              hipStream_t stream) {
  (void)in_sizes; (void)n_in; (void)out_size; (void)ws_size;
  const float* x       = (const float*)d_in[0];
  const float* pos     = (const float*)d_in[1];
  const float* enc_w0  = (const float*)d_in[3];
  const float* enc_b0  = (const float*)d_in[4];
  const float* enc_w1  = (const float*)d_in[5];
  const float* enc_b1  = (const float*)d_in[6];
  const float* msg_w   = (const float*)d_in[7];
  const float* msg_b   = (const float*)d_in[8];
  const float* upd_w   = (const float*)d_in[9];
  const float* upd_b   = (const float*)d_in[10];
  const float* proj_w0 = (const float*)d_in[11];
  const float* proj_b0 = (const float*)d_in[12];
  const float* proj_w1 = (const float*)d_in[13];
  const float* proj_b1 = (const float*)d_in[14];

  char* ws = (char*)d_ws;
  size_t off = 0;
  auto alloc = [&](size_t bytes) -> void* {
    void* p = ws + off;
    off += (bytes + 255) & ~(size_t)255;
    return p;
  };
  int*      nbr     = (int*)alloc((size_t)EE * 4);
  int*      cnt     = (int*)alloc((size_t)BN * 4);
  int*      fill    = (int*)alloc((size_t)BN * 4);
  int*      row_ptr = (int*)alloc((size_t)(BN + 1) * 4);
  int*      col     = (int*)alloc((size_t)EE * 4);
  float*    h_a     = (float*)alloc((size_t)BN * HID * 4);
  float*    h_b     = (float*)alloc((size_t)BN * HID * 4);
  ushort_t* bufA    = (ushort_t*)alloc((size_t)BN * HID * 2);
  ushort_t* bufB    = (ushort_t*)alloc((size_t)BN * HID * 2);
  float*    bufAgg  = (float*)alloc((size_t)BN * HID * 4);
  ushort_t* wfrag   = (ushort_t*)alloc((size_t)16 * 32768 * 2);
  float4*   spos    = (float4*)alloc((size_t)BN * 16);
  int*      cptr    = (int*)alloc((size_t)BB * (NCELL + 1) * 4);
  float*    out     = (float*)d_out;
  float*    hOut    = out + (size_t)BN * PROJ_D;

  // setup: blocks 0-7 cellsort (+ zero cnt/fill), blocks 8-135 prep_w
  setup_kernel<<<136, 256, 0, stream>>>(pos, spos, cptr, (int4*)cnt,
                                        enc_w1, msg_w, upd_w, proj_w0, proj_w1,
                                        wfrag);
  knn_kernel<<<BN / QPB, 1024, 0, stream>>>(spos, cptr, nbr, cnt);
  scan_kernel<<<1, 256, 0, stream>>>(cnt, row_ptr);
  fill_kernel<<<EE / 256, 256, 0, stream>>>(nbr, row_ptr, fill, col);

  encg1_kernel<<<dim3(BN / 64, 2), 256, 0, stream>>>(
      x, enc_w0, enc_b0, wfrag + 0 * 32768, enc_b1, h_a);

  float* hc = h_a;
  float* hn = h_b;
  for (int i = 0; i < 3; i++) {
    msg_kernel<<<dim3(BN / 64, 2), 256, 0, stream>>>(
        hc, wfrag + (size_t)(1 + 2 * i) * 32768,
        wfrag + (size_t)(2 + 2 * i) * 32768, msg_b + (size_t)i * HID,
        bufA, bufB);
    agg_kernel<<<BN / 2, 256, 0, stream>>>(bufA, bufB, row_ptr, col, bufAgg);
    float* target = (i == 2) ? hOut : hn;
    upd_kernel<<<dim3(BN / 64, 2), 256, 0, stream>>>(
        hc, wfrag + (size_t)(7 + 2 * i) * 32768, bufAgg,
        wfrag + (size_t)(8 + 2 * i) * 32768, upd_b + (size_t)i * HID, target);
    hn = hc; hc = target;
  }

  g1_kernel<1><<<dim3(BN / 64, 2), 256, 0, stream>>>(hc, wfrag + 13 * 32768,
                                                     proj_b0, h_b);
  proj1_kernel<<<dim3(BN / 64, 2), 256, 0, stream>>>(
      h_b, wfrag + 14 * 32768, proj_b1, out);
}